// Round 11
// baseline (1280.683 us; speedup 1.0000x reference)
//
#include <hip/hip_runtime.h>
#include <math.h>

// PaiNN energy + analytic coord-gradient.
// R11: msg kernels are latency-bound on the per-edge dependent gather chain
//      (VALUBusy 36%, occ 20% uncapped). Software-pipeline: process edge PAIRS,
//      issuing both edges' loads (incl. the 2KB dst-atom gathers) before any
//      compute -> 2x memory-level parallelism per wave. Structure otherwise R10.

#define NA 8192
#define NE 131072
#define FD 128
#define FD3 384
#define NBASE 20
#define HD 64
#define RCUT 5.0f
#define PIF 3.14159265358979f

typedef short bf16x8 __attribute__((ext_vector_type(8)));
typedef float f32x4 __attribute__((ext_vector_type(4)));
typedef _Float16 f16x2 __attribute__((ext_vector_type(2)));

static __device__ __forceinline__ float silu_f(float x) {
    return x / (1.f + expf(-x));
}
static __device__ __forceinline__ float dsilu_f(float x) {
    float s = 1.f / (1.f + expf(-x));
    return s * (1.f + x * (1.f - s));
}
static __device__ __forceinline__ short f2bf(float x) {
    union { float f; unsigned int i; } c; c.f = x;
    unsigned int r = c.i + 0x7fffu + ((c.i >> 16) & 1u);
    return (short)(r >> 16);
}
static __device__ __forceinline__ float bf2f(short u) {
    union { unsigned int i; float f; } c; c.i = ((unsigned int)(unsigned short)u) << 16; return c.f;
}
static __device__ __forceinline__ float dot2f(f16x2 a, f16x2 b, float c) {
#if __has_builtin(__builtin_amdgcn_fdot2)
    return __builtin_amdgcn_fdot2(a, b, c, false);
#else
    return c + (float)a.x * (float)b.x + (float)a.y * (float)b.y;
#endif
}

// ---------------- split-precision bf16 MFMA GEMM ----------------
// C = [silu?](A) @ W (+bias) (*dsilu(pre)) (+addbuf); A [M,K] f32 row-major.
// wtrans=0: W is [K,N] row-major. wtrans=1: W is [N,K] row-major (used as Worig^T).
// Tile 128x64, 4 waves, wave = 32 rows. hi/lo split for ~fp19 effective precision.
__global__ __launch_bounds__(256) void mfma_gemm_kernel(
    const float* __restrict__ A, const float* __restrict__ W,
    const float* __restrict__ bias, const float* __restrict__ dsil,
    const float* __restrict__ addbuf, float* __restrict__ C,
    int M, int N, int K, int asilu, int acc, int wtrans)
{
    __shared__ short AsH[128][40];   // [m][k] bf16 hi, K-tile 32 padded to 40
    __shared__ short AsL[128][40];   // bf16 lo
    __shared__ short WsH[64][40];    // [n][k] bf16 hi
    __shared__ short WsL[64][40];
    int tid = threadIdx.x;
    int row0 = blockIdx.y * 128, col0 = blockIdx.x * 64;
    int wv = tid >> 6, lane = tid & 63;
    int quad = lane >> 4, l16 = lane & 15;

    f32x4 accv[2][4];
    #pragma unroll
    for (int i = 0; i < 2; ++i)
        #pragma unroll
        for (int j = 0; j < 4; ++j) { f32x4 z = {0.f, 0.f, 0.f, 0.f}; accv[i][j] = z; }

    int am = tid >> 1;                 // 0..127
    int ak = (tid & 1) * 16;           // 0 or 16
    const float* abase = A + (size_t)(row0 + am) * K + ak;
    int wn = tid & 63, wk0 = tid >> 6;   // non-trans: k = wk0 + 4p
    int wk2 = tid & 31, wn2 = tid >> 5;  // trans: n = wn2 + 8p

    for (int k0 = 0; k0 < K; k0 += 32) {
        // stage A tile (128x32) with optional silu, f32 -> bf16 hi+lo
        {
            const float* ap = abase + k0;
            #pragma unroll
            for (int i = 0; i < 4; ++i) {
                float4 v = *(const float4*)(ap + 4 * i);
                if (asilu) {
                    v.x = silu_f(v.x); v.y = silu_f(v.y);
                    v.z = silu_f(v.z); v.w = silu_f(v.w);
                }
                float vv[4] = {v.x, v.y, v.z, v.w};
                #pragma unroll
                for (int q = 0; q < 4; ++q) {
                    short h = f2bf(vv[q]);
                    AsH[am][ak + 4 * i + q] = h;
                    AsL[am][ak + 4 * i + q] = f2bf(vv[q] - bf2f(h));
                }
            }
        }
        // stage W tile -> Ws[n][k], hi+lo
        if (!wtrans) {
            #pragma unroll
            for (int p = 0; p < 8; ++p) {
                int k = wk0 + p * 4;
                float v = W[(size_t)(k0 + k) * N + col0 + wn];
                short h = f2bf(v);
                WsH[wn][k] = h;
                WsL[wn][k] = f2bf(v - bf2f(h));
            }
        } else {
            #pragma unroll
            for (int p = 0; p < 8; ++p) {
                int n2 = wn2 + p * 8;
                float v = W[(size_t)(col0 + n2) * K + k0 + wk2];
                short h = f2bf(v);
                WsH[n2][wk2] = h;
                WsL[n2][wk2] = f2bf(v - bf2f(h));
            }
        }
        __syncthreads();
        bf16x8 afH[2], afL[2], bfH[4], bfL[4];
        #pragma unroll
        for (int rt = 0; rt < 2; ++rt) {
            afH[rt] = *(const bf16x8*)&AsH[wv * 32 + rt * 16 + l16][quad * 8];
            afL[rt] = *(const bf16x8*)&AsL[wv * 32 + rt * 16 + l16][quad * 8];
        }
        #pragma unroll
        for (int ct = 0; ct < 4; ++ct) {
            bfH[ct] = *(const bf16x8*)&WsH[ct * 16 + l16][quad * 8];
            bfL[ct] = *(const bf16x8*)&WsL[ct * 16 + l16][quad * 8];
        }
        #pragma unroll
        for (int rt = 0; rt < 2; ++rt)
            #pragma unroll
            for (int ct = 0; ct < 4; ++ct) {
                accv[rt][ct] = __builtin_amdgcn_mfma_f32_16x16x32_bf16(
                    afL[rt], bfH[ct], accv[rt][ct], 0, 0, 0);
                accv[rt][ct] = __builtin_amdgcn_mfma_f32_16x16x32_bf16(
                    afH[rt], bfL[ct], accv[rt][ct], 0, 0, 0);
                accv[rt][ct] = __builtin_amdgcn_mfma_f32_16x16x32_bf16(
                    afH[rt], bfH[ct], accv[rt][ct], 0, 0, 0);
            }
        __syncthreads();
    }
    // epilogue: D[row][col], col = l16, row = quad*4 + r
    #pragma unroll
    for (int rt = 0; rt < 2; ++rt) {
        #pragma unroll
        for (int ct = 0; ct < 4; ++ct) {
            int colv = col0 + ct * 16 + l16;
            float bv = bias ? bias[colv] : 0.f;
            #pragma unroll
            for (int r = 0; r < 4; ++r) {
                int rowv = row0 + wv * 32 + rt * 16 + quad * 4 + r;
                float v = accv[rt][ct][r] + bv;
                size_t idx = (size_t)rowv * N + colv;
                if (dsil) { float pz = dsil[idx]; float s = 1.f / (1.f + expf(-pz)); v *= s * (1.f + pz * (1.f - s)); }
                if (addbuf) v += addbuf[idx];
                if (acc) C[idx] += v; else C[idx] = v;
            }
        }
    }
}

// ---------------- small helpers ----------------
__global__ void embed_kernel(const int* at_no, const float* emb, float* x) {
    int i = blockIdx.x * blockDim.x + threadIdx.x;   // NA*FD threads
    int n = i >> 7, f = i & 127;
    x[i] = emb[(size_t)at_no[n] * FD + f];
}

// builds UVcomb [128][256] = [u | v] and Tcomb [256][128] = [u^T ; v^T]
__global__ void combo_prep_kernel(const float* u, const float* v, float* UVcomb, float* Tcomb) {
    int i = blockIdx.x * blockDim.x + threadIdx.x;   // 32768 threads
    {
        int k = i >> 8, j = i & 255;
        UVcomb[i] = (j < 128) ? u[k * 128 + j] : v[k * 128 + (j - 128)];
    }
    {
        int k = i >> 7, j = i & 127;
        Tcomb[i] = (k < 128) ? u[j * 128 + k] : v[j * 128 + (k - 128)];
    }
}

// ---------------- edge geometry forward (+ CSR histogram fused) ----------------
__global__ void geom_fwd_kernel(const float* coord, const int* ei,
    float* d_e, float* unit_e, float* rbf_e, float* drbf_e, float* fcut_e, float* dfc_e,
    int* cnt_dst, int* cnt_src)
{
    int e = blockIdx.x * blockDim.x + threadIdx.x;
    if (e >= NE) return;
    int s = ei[e], t = ei[NE + e];
    atomicAdd(&cnt_src[s], 1);
    atomicAdd(&cnt_dst[t], 1);
    float rx = coord[t * 3 + 0] - coord[s * 3 + 0];
    float ry = coord[t * 3 + 1] - coord[s * 3 + 1];
    float rz = coord[t * 3 + 2] - coord[s * 3 + 2];
    float r2 = rx * rx + ry * ry + rz * rz;
    float dd = sqrtf(r2 + 1e-12f);
    float inv = 1.f / dd;
    d_e[e] = dd;
    unit_e[e * 3 + 0] = rx * inv; unit_e[e * 3 + 1] = ry * inv; unit_e[e * 3 + 2] = rz * inv;
    const float c0 = 0.6324555320336759f;   // sqrt(2/5)
    for (int k = 0; k < NBASE; ++k) {
        float nk = (k + 1) * (PIF / RCUT);
        float sn, cs; sincosf(nk * dd, &sn, &cs);
        rbf_e[(size_t)e * NBASE + k] = c0 * sn * inv;
        drbf_e[(size_t)e * NBASE + k] = c0 * (nk * cs * inv - sn * inv * inv);
    }
    if (dd < RCUT) {
        float sn, cs; sincosf(PIF * dd / RCUT, &sn, &cs);
        fcut_e[e] = 0.5f * (cs + 1.f);
        dfc_e[e] = -0.5f * (PIF / RCUT) * sn;
    } else { fcut_e[e] = 0.f; dfc_e[e] = 0.f; }
}

// ---------------- CSR build ----------------
__global__ __launch_bounds__(1024) void scan_kernel(
    const int* cnt_dst, const int* cnt_src,
    int* off_dst, int* off_src, int* cur_dst, int* cur_src)
{
    __shared__ int part[1024];
    const int* cnt = (blockIdx.x == 0) ? cnt_dst : cnt_src;
    int* off = (blockIdx.x == 0) ? off_dst : off_src;
    int* cur = (blockIdx.x == 0) ? cur_dst : cur_src;
    int t = threadIdx.x;
    int base = t * 8;
    int loc[8]; int s = 0;
    #pragma unroll
    for (int i = 0; i < 8; ++i) { loc[i] = s; s += cnt[base + i]; }
    part[t] = s;
    __syncthreads();
    for (int d = 1; d < 1024; d <<= 1) {
        int v = part[t];
        int w = (t >= d) ? part[t - d] : 0;
        __syncthreads();
        part[t] = v + w;
        __syncthreads();
    }
    int pre = (t == 0) ? 0 : part[t - 1];
    #pragma unroll
    for (int i = 0; i < 8; ++i) { int o = pre + loc[i]; off[base + i] = o; cur[base + i] = o; }
    if (t == 1023) off[NA] = part[1023];
}

__global__ void scatter_kernel(const int* ei, int* cur_dst, int* cur_src,
                               int* perm_dst, int* perm_src, int* srcp, int* dstp) {
    int e = blockIdx.x * blockDim.x + threadIdx.x;
    if (e >= NE) return;
    int s = ei[e], t = ei[NE + e];
    int pd = atomicAdd(&cur_dst[t], 1); perm_dst[pd] = e; srcp[pd] = s;
    int ps = atomicAdd(&cur_src[s], 1); perm_src[ps] = e; dstp[ps] = t;
}

// ---------------- message forward (per-dst-atom, 2 atoms/block, pipelined pairs) -----
__global__ __launch_bounds__(256) void msg_fwd_kernel(
    const int* __restrict__ row_off_dst, const int* __restrict__ perm_dst, const int* __restrict__ srcp,
    const float* __restrict__ rbf_e, const float* __restrict__ fcut_e, const float* __restrict__ unit_e,
    const float* __restrict__ phi, const float* __restrict__ Wr, const float* __restrict__ br,
    const float* __restrict__ x_in, const float* __restrict__ v_in,   // v_in may be null (block 0)
    float* __restrict__ x_mid, float* __restrict__ v_mid)
{
    int tid = threadIdx.x;
    int n = blockIdx.x * 2 + (tid >> 7);
    int f = tid & 127;
    float w0[NBASE], w1[NBASE], w2[NBASE];
    #pragma unroll
    for (int k = 0; k < NBASE; ++k) {
        w0[k] = Wr[k * FD3 + f];
        w1[k] = Wr[k * FD3 + FD + f];
        w2[k] = Wr[k * FD3 + 2 * FD + f];
    }
    float b0 = br[f], b1 = br[FD + f], b2 = br[2 * FD + f];
    float xa = 0.f, va0 = 0.f, va1 = 0.f, va2 = 0.f;
    int e0 = row_off_dst[n], e1 = row_off_dst[n + 1];

    struct FwdEdge {
        float fc, u0, u1, u2;
        float rb[NBASE];
        float ph0, ph1, ph2, vs0, vs1, vs2;
    };
    auto loadE = [&](int ii, FwdEdge& E) {
        int e = perm_dst[ii], s = srcp[ii];
        E.fc = fcut_e[e];
        E.u0 = unit_e[e * 3]; E.u1 = unit_e[e * 3 + 1]; E.u2 = unit_e[e * 3 + 2];
        const float* rp = rbf_e + (size_t)e * NBASE;
        #pragma unroll
        for (int k = 0; k < NBASE; ++k) E.rb[k] = rp[k];
        const float* ph = phi + (size_t)s * FD3;
        E.ph0 = ph[f]; E.ph1 = ph[FD + f]; E.ph2 = ph[2 * FD + f];
        if (v_in) {
            const float* vp = v_in + (size_t)s * 3 * FD;
            E.vs0 = vp[f]; E.vs1 = vp[FD + f]; E.vs2 = vp[2 * FD + f];
        } else { E.vs0 = 0.f; E.vs1 = 0.f; E.vs2 = 0.f; }
    };
    auto compE = [&](FwdEdge& E) {
        float raw0 = b0, raw1 = b1, raw2 = b2;
        #pragma unroll
        for (int k = 0; k < NBASE; ++k) {
            float r = E.rb[k];
            raw0 = fmaf(r, w0[k], raw0);
            raw1 = fmaf(r, w1[k], raw1);
            raw2 = fmaf(r, w2[k], raw2);
        }
        float f0 = raw0 * E.fc, f1 = raw1 * E.fc, f2 = raw2 * E.fc;
        float m0 = E.ph0 * f0, m1 = E.ph1 * f1, m2 = E.ph2 * f2;
        xa += m0;
        va0 += m1 * E.vs0 + m2 * E.u0;
        va1 += m1 * E.vs1 + m2 * E.u1;
        va2 += m1 * E.vs2 + m2 * E.u2;
    };

    for (int ii = e0; ii < e1; ii += 2) {
        FwdEdge A, B;
        loadE(ii, A);
        bool hasB = (ii + 1 < e1);
        if (hasB) loadE(ii + 1, B);
        compE(A);
        if (hasB) compE(B);
    }
    size_t xb = (size_t)n * FD + f;
    x_mid[xb] = x_in[xb] + xa;
    size_t vb = (size_t)n * 3 * FD + f;
    float p0 = 0.f, p1 = 0.f, p2 = 0.f;
    if (v_in) { p0 = v_in[vb]; p1 = v_in[vb + FD]; p2 = v_in[vb + 2 * FD]; }
    v_mid[vb] = p0 + va0; v_mid[vb + FD] = p1 + va1; v_mid[vb + 2 * FD] = p2 + va2;
}

// ---------------- update-block pointwise kernels (uvvv interleaved layout) ------------
// uvvv rows: row = n*3+i, cols 0..127 = uv, 128..255 = vv.
__global__ void vnorm_cat_kernel(const float* xmid, const float* uvvv, float* vnorm, float* cat) {
    int i = blockIdx.x * blockDim.x + threadIdx.x;  // NA*FD
    int n = i >> 7, g = i & 127;
    size_t ub = (size_t)n * 3 * 256 + 128 + g;
    float a = uvvv[ub], b = uvvv[ub + 256], c = uvvv[ub + 512];
    float vn = sqrtf(a * a + b * b + c * c + 1e-12f);
    vnorm[i] = vn;
    cat[(size_t)n * 2 * FD + g] = xmid[i];
    cat[(size_t)n * 2 * FD + FD + g] = vn;
}

__global__ void combine_kernel(const float* xmid, const float* vmid,
    const float* uvvv, const float* a_,
    float* x_out, float* v_out /* nullable */)
{
    int i = blockIdx.x * blockDim.x + threadIdx.x;  // NA*FD
    int n = i >> 7, g = i & 127;
    size_t vb = (size_t)n * 3 * FD + g;
    size_t ub = (size_t)n * 3 * 256 + g;
    float uv0 = uvvv[ub], uv1 = uvvv[ub + 256], uv2 = uvvv[ub + 512];
    float vv0 = uvvv[ub + 128], vv1 = uvvv[ub + 384], vv2 = uvvv[ub + 640];
    float S = uv0 * vv0 + uv1 * vv1 + uv2 * vv2;
    const float* ar = a_ + (size_t)n * FD3;
    x_out[i] = xmid[i] + ar[FD + g] * S + ar[2 * FD + g];
    if (v_out) {
        float avv = ar[g];
        v_out[vb] = vmid[vb] + avv * uv0;
        v_out[vb + FD] = vmid[vb + FD] + avv * uv1;
        v_out[vb + 2 * FD] = vmid[vb + 2 * FD] + avv * uv2;
    }
}

// ---------------- output head ----------------
__global__ __launch_bounds__(256) void energy_kernel(
    const float* tout, const float* ow2, const float* ob2,
    const float* atom_sp, const int* at_no, float* out)
{
    int n = blockIdx.x * 256 + threadIdx.x;   // NA exact
    float e = ob2[0] + atom_sp[at_no[n]];
    for (int h = 0; h < HD; ++h) {
        float t = tout[(size_t)n * HD + h];
        e = fmaf(silu_f(t), ow2[h], e);
    }
    #pragma unroll
    for (int off = 32; off > 0; off >>= 1) e += __shfl_down(e, off);
    __shared__ float s[4];
    int lane = threadIdx.x & 63, wv = threadIdx.x >> 6;
    if (lane == 0) s[wv] = e;
    __syncthreads();
    if (threadIdx.x == 0) atomicAdd(out, s[0] + s[1] + s[2] + s[3]);
}

__global__ __launch_bounds__(128) void head_bwd_kernel(
    const float* tout, const float* ow1, const float* ow2, float* gx)
{
    __shared__ float sh[HD];
    int n = blockIdx.x, f = threadIdx.x;
    if (f < HD) {
        float p = tout[(size_t)n * HD + f];
        sh[f] = dsilu_f(p) * ow2[f];
    }
    __syncthreads();
    float g = 0.f;
    #pragma unroll
    for (int h = 0; h < HD; ++h) g = fmaf(sh[h], ow1[f * HD + h], g);
    gx[(size_t)n * FD + f] = g;
}

// ---------------- update-block backward pointwise ----------------
__global__ void ubwd1_kernel(const float* gx, const float* gv,
    const float* uvvv, float* g_a)
{
    int i = blockIdx.x * blockDim.x + threadIdx.x;  // NA*FD
    int n = i >> 7, g = i & 127;
    size_t vb = (size_t)n * 3 * FD + g;
    size_t ub = (size_t)n * 3 * 256 + g;
    float uv0 = uvvv[ub], uv1 = uvvv[ub + 256], uv2 = uvvv[ub + 512];
    float vv0 = uvvv[ub + 128], vv1 = uvvv[ub + 384], vv2 = uvvv[ub + 640];
    float gv0 = gv[vb], gv1 = gv[vb + FD], gv2 = gv[vb + 2 * FD];
    float gxv = gx[i];
    float S = uv0 * vv0 + uv1 * vv1 + uv2 * vv2;
    size_t ab = (size_t)n * FD3;
    g_a[ab + g]           = gv0 * uv0 + gv1 * uv1 + gv2 * uv2;   // g w.r.t. a_vv
    g_a[ab + FD + g]      = gxv * S;                              // g w.r.t. a_sv
    g_a[ab + 2 * FD + g]  = gxv;                                  // g w.r.t. a_ss
}

// NOTE: uvvv is read then overwritten in place (g_uv/g_vv); no __restrict__ on it.
__global__ void ubwd2_kernel(const float* gx_in, const float* gv_in,
    const float* a_, const float* vnorm, const float* g_cat,
    float* uvvv, float* gx_mid, float* gv_tmp)
{
    int i = blockIdx.x * blockDim.x + threadIdx.x;  // NA*FD
    int n = i >> 7, g = i & 127;
    size_t vb = (size_t)n * 3 * FD + g, ab = (size_t)n * FD3;
    size_t ub = (size_t)n * 3 * 256 + g;
    float gxv = gx_in[i];
    float gS = gxv * a_[ab + FD + g];
    float avv = a_[ab + g];
    float gvn = g_cat[(size_t)n * 2 * FD + FD + g];
    float c = gvn / vnorm[i];
    float uv0 = uvvv[ub], uv1 = uvvv[ub + 256], uv2 = uvvv[ub + 512];
    float vv0 = uvvv[ub + 128], vv1 = uvvv[ub + 384], vv2 = uvvv[ub + 640];
    float gv0 = gv_in[vb], gv1 = gv_in[vb + FD], gv2 = gv_in[vb + 2 * FD];
    uvvv[ub]       = gv0 * avv + gS * vv0;
    uvvv[ub + 256] = gv1 * avv + gS * vv1;
    uvvv[ub + 512] = gv2 * avv + gS * vv2;
    uvvv[ub + 128] = gS * uv0 + c * vv0;
    uvvv[ub + 384] = gS * uv1 + c * vv1;
    uvvv[ub + 640] = gS * uv2 + c * vv2;
    gv_tmp[vb] = gv0; gv_tmp[vb + FD] = gv1; gv_tmp[vb + 2 * FD] = gv2;
    gx_mid[i] = gxv + g_cat[(size_t)n * 2 * FD + g];
}

// ---------------- merged message backward: one BLOCK (4 waves) per src atom --------
// Wave wv processes edge pairs (ii, ii+4), ii stepping by 8 (unique ownership).
// Both edges' loads (incl. 2KB dst-atom gathers) are issued before compute.
__global__ __launch_bounds__(256) void msg_bwd_merged_kernel(
    const int* __restrict__ row_off_src, const int* __restrict__ perm_src, const int* __restrict__ dstp,
    const float* __restrict__ rbf_e, const float* __restrict__ drbf_e,
    const float* __restrict__ fcut_e, const float* __restrict__ dfc_e,
    const float* __restrict__ unit_e,
    const float* phi, const float* __restrict__ Wr, const float* __restrict__ br,
    const float* __restrict__ v_in,              // nullable (block 0)
    const float* __restrict__ gx_mid, const float* __restrict__ gv_mid,
    float* gphi_out,                // aliases phi (own-atom read-then-write, barrier-protected)
    float* __restrict__ gv_out,
    float* __restrict__ gd_e, float* __restrict__ gu_e)
{
    __shared__ float red[12][4][64];
    int tid = threadIdx.x;
    int wv = tid >> 6, lane = tid & 63;
    int n = blockIdx.x;
    // weights for both feature halves, packed f16 pairs along k
    f16x2 w[2][3][10];
    float brv[2][3], ph[2][3], vs[2][3];
    #pragma unroll
    for (int h = 0; h < 2; ++h) {
        int f = lane + h * 64;
        #pragma unroll
        for (int s = 0; s < 3; ++s) {
            #pragma unroll
            for (int k2 = 0; k2 < 10; ++k2) {
                f16x2 t;
                t.x = (_Float16)Wr[(2 * k2) * FD3 + s * FD + f];
                t.y = (_Float16)Wr[(2 * k2 + 1) * FD3 + s * FD + f];
                w[h][s][k2] = t;
            }
            brv[h][s] = br[s * FD + f];
            ph[h][s] = phi[(size_t)n * FD3 + s * FD + f];
            vs[h][s] = v_in ? v_in[(size_t)n * 3 * FD + s * FD + f] : 0.f;
        }
    }
    float gp[2][3] = {{0.f, 0.f, 0.f}, {0.f, 0.f, 0.f}};
    float ga[2][3] = {{0.f, 0.f, 0.f}, {0.f, 0.f, 0.f}};
    int e0 = row_off_src[n], e1 = row_off_src[n + 1];

    struct BwdEdge {
        int e;
        float fc, dfc, u0, u1, u2;
        f16x2 rb2[10], db2[10];
        float gds[2];
        float gd[2][3];
    };
    auto loadE = [&](int ii, BwdEdge& E) {
        int e = perm_src[ii]; E.e = e;
        int dd = dstp[ii];
        E.fc = fcut_e[e]; E.dfc = dfc_e[e];
        E.u0 = unit_e[e * 3]; E.u1 = unit_e[e * 3 + 1]; E.u2 = unit_e[e * 3 + 2];
        const float* rp = rbf_e + (size_t)e * NBASE;
        const float* dp = drbf_e + (size_t)e * NBASE;
        #pragma unroll
        for (int k2 = 0; k2 < 10; ++k2) {
            f16x2 a, b;
            a.x = (_Float16)rp[2 * k2]; a.y = (_Float16)rp[2 * k2 + 1];
            b.x = (_Float16)dp[2 * k2]; b.y = (_Float16)dp[2 * k2 + 1];
            E.rb2[k2] = a; E.db2[k2] = b;
        }
        #pragma unroll
        for (int h = 0; h < 2; ++h) {
            int f = lane + h * 64;
            E.gds[h] = gx_mid[(size_t)dd * FD + f];
            const float* gvp = gv_mid + (size_t)dd * 3 * FD;
            E.gd[h][0] = gvp[f]; E.gd[h][1] = gvp[FD + f]; E.gd[h][2] = gvp[2 * FD + f];
        }
    };
    auto compE = [&](BwdEdge& E) {
        float r0 = 0.f, r1 = 0.f, r2 = 0.f, r3 = 0.f;
        #pragma unroll
        for (int h = 0; h < 2; ++h) {
            float raw0 = brv[h][0], raw1 = brv[h][1], raw2 = brv[h][2];
            float A0 = 0.f, A1 = 0.f, A2 = 0.f;
            #pragma unroll
            for (int k2 = 0; k2 < 10; ++k2) {
                raw0 = dot2f(E.rb2[k2], w[h][0][k2], raw0);
                raw1 = dot2f(E.rb2[k2], w[h][1][k2], raw1);
                raw2 = dot2f(E.rb2[k2], w[h][2][k2], raw2);
                A0 = dot2f(E.db2[k2], w[h][0][k2], A0);
                A1 = dot2f(E.db2[k2], w[h][1][k2], A1);
                A2 = dot2f(E.db2[k2], w[h][2][k2], A2);
            }
            float f0 = raw0 * E.fc, f1 = raw1 * E.fc, f2 = raw2 * E.fc;
            float gds = E.gds[h];
            float gd0 = E.gd[h][0], gd1 = E.gd[h][1], gd2 = E.gd[h][2];
            float gdv1 = gd0 * vs[h][0] + gd1 * vs[h][1] + gd2 * vs[h][2];
            float gdv2 = gd0 * E.u0 + gd1 * E.u1 + gd2 * E.u2;
            float dv1 = ph[h][1] * f1;
            ga[h][0] += gd0 * dv1; ga[h][1] += gd1 * dv1; ga[h][2] += gd2 * dv1;
            gp[h][0] += gds * f0; gp[h][1] += gdv1 * f1; gp[h][2] += gdv2 * f2;
            float dv2 = ph[h][2] * f2;
            r1 += gd0 * dv2; r2 += gd1 * dv2; r3 += gd2 * dv2;
            float gf0 = gds * ph[h][0], gf1 = gdv1 * ph[h][1], gf2 = gdv2 * ph[h][2];
            r0 += E.fc * (gf0 * A0 + gf1 * A1 + gf2 * A2)
                + E.dfc * (gf0 * raw0 + gf1 * raw1 + gf2 * raw2);
        }
        #pragma unroll
        for (int off = 32; off > 0; off >>= 1) {
            r0 += __shfl_down(r0, off);
            r1 += __shfl_down(r1, off);
            r2 += __shfl_down(r2, off);
            r3 += __shfl_down(r3, off);
        }
        if (lane == 0) {
            gd_e[E.e] += r0;
            gu_e[E.e * 3]     += r1;
            gu_e[E.e * 3 + 1] += r2;
            gu_e[E.e * 3 + 2] += r3;
        }
    };

    for (int ii = e0 + wv; ii < e1; ii += 8) {
        BwdEdge A, B;
        loadE(ii, A);
        bool hasB = (ii + 4 < e1);
        if (hasB) loadE(ii + 4, B);
        compE(A);
        if (hasB) compE(B);
    }
    // block reduce of gp/ga across the 4 waves
    #pragma unroll
    for (int h = 0; h < 2; ++h)
        #pragma unroll
        for (int s = 0; s < 3; ++s) {
            red[h * 3 + s][wv][lane] = gp[h][s];
            red[6 + h * 3 + s][wv][lane] = ga[h][s];
        }
    __syncthreads();
    int j0 = tid >> 6;   // 0..3
    #pragma unroll
    for (int rep = 0; rep < 3; ++rep) {
        int j = j0 + rep * 4;
        float v = red[j][0][lane] + red[j][1][lane] + red[j][2][lane] + red[j][3][lane];
        int jj = (j < 6) ? j : j - 6;
        int h = jj / 3, s = jj - 3 * h;
        int f = h * 64 + lane;
        if (j < 6) {
            gphi_out[(size_t)n * FD3 + s * FD + f] = v;
        } else {
            size_t vb = (size_t)n * 3 * FD + s * FD + f;
            gv_out[vb] = gv_mid[vb] + v;
        }
    }
}

// ---------------- geometry backward: per-edge grad vector (no atomics) ----------------
// NOTE: gvec aliases gu_e (same-thread read-then-write) — no __restrict__.
__global__ void edge_vec_kernel(const float* coord, const int* ei,
    const float* d_e, const float* gd_e, const float* gu_e, float* gvec)
{
    int e = blockIdx.x * blockDim.x + threadIdx.x;
    if (e >= NE) return;
    int s = ei[e], t = ei[NE + e];
    float rx = coord[t * 3 + 0] - coord[s * 3 + 0];
    float ry = coord[t * 3 + 1] - coord[s * 3 + 1];
    float rz = coord[t * 3 + 2] - coord[s * 3 + 2];
    float dd = d_e[e];
    float inv = 1.f / dd;
    float gu0 = gu_e[e * 3], gu1 = gu_e[e * 3 + 1], gu2 = gu_e[e * 3 + 2];
    float gd = gd_e[e];
    float dot = gu0 * rx + gu1 * ry + gu2 * rz;
    float coef = gd * inv - dot * inv * inv * inv;
    gvec[e * 3 + 0] = gu0 * inv + coef * rx;
    gvec[e * 3 + 1] = gu1 * inv + coef * ry;
    gvec[e * 3 + 2] = gu2 * inv + coef * rz;
}

// one wave per atom: gcoord[n] = sum_{dst edges} gvec - sum_{src edges} gvec
__global__ __launch_bounds__(256) void coord_gather_kernel(
    const int* __restrict__ off_dst, const int* __restrict__ perm_dst,
    const int* __restrict__ off_src, const int* __restrict__ perm_src,
    const float* __restrict__ gvec, float* __restrict__ gcoord)
{
    int n = blockIdx.x * 4 + (threadIdx.x >> 6);
    int lane = threadIdx.x & 63;
    float a0 = 0.f, a1 = 0.f, a2 = 0.f;
    int d0 = off_dst[n], d1 = off_dst[n + 1];
    for (int ii = d0 + lane; ii < d1; ii += 64) {
        int e = perm_dst[ii];
        a0 += gvec[e * 3]; a1 += gvec[e * 3 + 1]; a2 += gvec[e * 3 + 2];
    }
    int s0 = off_src[n], s1 = off_src[n + 1];
    for (int ii = s0 + lane; ii < s1; ii += 64) {
        int e = perm_src[ii];
        a0 -= gvec[e * 3]; a1 -= gvec[e * 3 + 1]; a2 -= gvec[e * 3 + 2];
    }
    #pragma unroll
    for (int off = 32; off > 0; off >>= 1) {
        a0 += __shfl_down(a0, off);
        a1 += __shfl_down(a1, off);
        a2 += __shfl_down(a2, off);
    }
    if (lane == 0) {
        gcoord[n * 3 + 0] = a0; gcoord[n * 3 + 1] = a1; gcoord[n * 3 + 2] = a2;
    }
}

// ======================================================================
extern "C" void kernel_launch(void* const* d_in, const int* in_sizes, int n_in,
                              void* d_out, int out_size, void* d_ws, size_t ws_size,
                              hipStream_t stream)
{
    (void)in_sizes; (void)n_in; (void)out_size; (void)ws_size;
    const int*   at_no   = (const int*)  d_in[0];
    const float* coord   = (const float*)d_in[1];
    const int*   eidx    = (const int*)  d_in[2];
    const float* emb     = (const float*)d_in[5];
    const float* atom_sp = (const float*)d_in[6];
    const float* msg_w1  = (const float*)d_in[7];
    const float* msg_b1  = (const float*)d_in[8];
    const float* msg_w2  = (const float*)d_in[9];
    const float* msg_b2  = (const float*)d_in[10];
    const float* msg_wr  = (const float*)d_in[11];
    const float* msg_br  = (const float*)d_in[12];
    const float* upd_u   = (const float*)d_in[13];
    const float* upd_v   = (const float*)d_in[14];
    const float* upd_w1  = (const float*)d_in[15];
    const float* upd_b1  = (const float*)d_in[16];
    const float* upd_w2  = (const float*)d_in[17];
    const float* upd_b2  = (const float*)d_in[18];
    const float* out_w1  = (const float*)d_in[19];
    const float* out_b1  = (const float*)d_in[20];
    const float* out_w2  = (const float*)d_in[21];
    const float* out_b2  = (const float*)d_in[22];
    float* out = (float*)d_out;
    float* gcoord = out + 1;

    char* wp = (char*)d_ws;
    auto alloc = [&](size_t nelem) -> float* {
        float* r = (float*)wp; wp += ((nelem * 4 + 255) & ~(size_t)255); return r;
    };
    auto alloci = [&](size_t nelem) -> int* {
        int* r = (int*)wp; wp += ((nelem * 4 + 255) & ~(size_t)255); return r;
    };
    const size_t NF = (size_t)NA * FD;

    float* d_e    = alloc(NE);
    float* unit_e = alloc(3 * (size_t)NE);
    float* rbf_e  = alloc((size_t)NBASE * NE);
    float* drbf_e = alloc((size_t)NBASE * NE);
    float* fcut_e = alloc(NE);
    float* dfc_e  = alloc(NE);
    float* gd_e   = alloc(NE);
    float* gu_e   = alloc(3 * (size_t)NE);
    int* cnt_dst = alloci(NA); int* cnt_src = alloci(NA);
    int* off_dst = alloci(NA + 1); int* off_src = alloci(NA + 1);
    int* cur_dst = alloci(NA); int* cur_src = alloci(NA);
    int* perm_dst = alloci(NE); int* perm_src = alloci(NE);
    int* srcp = alloci(NE); int* dstp = alloci(NE);
    float* xin_all = alloc(3 * NF);
    float* xin0 = xin_all; float* xin1 = xin_all + NF; float* xfin = xin_all + 2 * NF;
    float* vout0 = alloc(3 * NF);
    float* xmid = alloc(NF);
    float* vmid = alloc(3 * NF);            // reused as gv_tmp in backward
    float* catb = alloc(2 * NF);
    float* toutb = alloc((size_t)NA * HD);
    float *s1b[2], *phib[2], *uvvv[2], *vnb[2], *t1b[2], *ab[2];
    for (int b = 0; b < 2; ++b) {
        s1b[b] = alloc(NF); phib[b] = alloc(3 * NF); uvvv[b] = alloc(6 * NF);
        vnb[b] = alloc(NF); t1b[b] = alloc(NF); ab[b] = alloc(3 * NF);
    }
    float* gxA = alloc(NF); float* gxB = alloc(NF);
    float* gvA = alloc(3 * NF);
    // backward aliases of dead forward buffers:
    float* g_a   = xin_all;   // 3*NF
    float* g_cat = catb;      // 2*NF
    float* g_t1  = xmid;      // NF
    float* g_s1  = s1b[0];    // NF (only used in b==1 path)
    float* gvec_e = gu_e;     // in-place transform in edge_vec
    float *UVcomb[2], *Tcomb[2];
    for (int b = 0; b < 2; ++b) { UVcomb[b] = alloc(FD * 256); Tcomb[b] = alloc(256 * FD); }

    // zero-init (harness poisons d_out/d_ws with 0xAA before every call)
    hipMemsetAsync(d_out, 0, (size_t)(1 + NA * 3) * 4, stream);
    hipMemsetAsync(cnt_dst, 0, (size_t)NA * 4, stream);
    hipMemsetAsync(cnt_src, 0, (size_t)NA * 4, stream);
    hipMemsetAsync(gd_e, 0, (size_t)NE * 4, stream);
    hipMemsetAsync(gu_e, 0, 3ull * NE * 4, stream);
    hipMemsetAsync(gvA, 0, 3 * NF * 4, stream);

    geom_fwd_kernel<<<NE / 256, 256, 0, stream>>>(coord, eidx, d_e, unit_e, rbf_e, drbf_e,
                                                  fcut_e, dfc_e, cnt_dst, cnt_src);
    scan_kernel<<<2, 1024, 0, stream>>>(cnt_dst, cnt_src, off_dst, off_src, cur_dst, cur_src);
    scatter_kernel<<<NE / 256, 256, 0, stream>>>(eidx, cur_dst, cur_src, perm_dst, perm_src, srcp, dstp);
    embed_kernel<<<NF / 256, 256, 0, stream>>>(at_no, emb, xin0);
    for (int b = 0; b < 2; ++b)
        combo_prep_kernel<<<128, 256, 0, stream>>>(upd_u + (size_t)b * FD * FD,
                                                   upd_v + (size_t)b * FD * FD, UVcomb[b], Tcomb[b]);

    auto gemm = [&](const float* A, const float* W, const float* bias, const float* dsil,
                    const float* addb, float* C, int M, int Nn, int K, int asilu, int acc, int wtrans) {
        dim3 g(Nn / 64, M / 128);
        mfma_gemm_kernel<<<g, 256, 0, stream>>>(A, W, bias, dsil, addb, C, M, Nn, K, asilu, acc, wtrans);
    };

    // ---------------- forward ----------------
    for (int b = 0; b < 2; ++b) {
        const float* xinb = b ? xin1 : xin0;
        const float* vin  = b ? vout0 : nullptr;
        gemm(xinb, msg_w1 + (size_t)b * FD * FD, msg_b1 + b * FD, nullptr, nullptr, s1b[b], NA, FD, FD, 0, 0, 0);
        gemm(s1b[b], msg_w2 + (size_t)b * FD * FD3, msg_b2 + b * FD3, nullptr, nullptr, phib[b], NA, FD3, FD, 1, 0, 0);
        msg_fwd_kernel<<<NA / 2, 256, 0, stream>>>(off_dst, perm_dst, srcp, rbf_e, fcut_e, unit_e,
                                              phib[b], msg_wr + (size_t)b * NBASE * FD3, msg_br + b * FD3,
                                              xinb, vin, xmid, vmid);
        gemm(vmid, UVcomb[b], nullptr, nullptr, nullptr, uvvv[b], 3 * NA, 256, FD, 0, 0, 0);
        vnorm_cat_kernel<<<NF / 256, 256, 0, stream>>>(xmid, uvvv[b], vnb[b], catb);
        gemm(catb, upd_w1 + (size_t)b * 2 * FD * FD, upd_b1 + b * FD, nullptr, nullptr, t1b[b], NA, FD, 2 * FD, 0, 0, 0);
        gemm(t1b[b], upd_w2 + (size_t)b * FD * FD3, upd_b2 + b * FD3, nullptr, nullptr, ab[b], NA, FD3, FD, 1, 0, 0);
        combine_kernel<<<NF / 256, 256, 0, stream>>>(xmid, vmid, uvvv[b], ab[b],
                                                     b ? xfin : xin1, b ? nullptr : vout0);
    }
    gemm(xfin, out_w1, out_b1, nullptr, nullptr, toutb, NA, HD, FD, 0, 0, 0);
    energy_kernel<<<NA / 256, 256, 0, stream>>>(toutb, out_w2, out_b2, atom_sp, at_no, out);

    // ---------------- backward ----------------
    head_bwd_kernel<<<NA, FD, 0, stream>>>(toutb, out_w1, out_w2, gxA);
    for (int b = 1; b >= 0; --b) {
        ubwd1_kernel<<<NF / 256, 256, 0, stream>>>(gxA, gvA, uvvv[b], g_a);
        gemm(g_a, upd_w2 + (size_t)b * FD * FD3, nullptr, t1b[b], nullptr, g_t1, NA, FD, FD3, 0, 0, 1);
        gemm(g_t1, upd_w1 + (size_t)b * 2 * FD * FD, nullptr, nullptr, nullptr, g_cat, NA, 2 * FD, FD, 0, 0, 1);
        ubwd2_kernel<<<NF / 256, 256, 0, stream>>>(gxA, gvA, ab[b], vnb[b], g_cat,
                                                   uvvv[b], gxB, vmid);
        gemm(uvvv[b], Tcomb[b], nullptr, nullptr, nullptr, vmid, 3 * NA, FD, 256, 0, 1, 0);
        msg_bwd_merged_kernel<<<NA, 256, 0, stream>>>(off_src, perm_src, dstp,
                                              rbf_e, drbf_e, fcut_e, dfc_e, unit_e,
                                              phib[b], msg_wr + (size_t)b * NBASE * FD3, msg_br + b * FD3,
                                              b ? vout0 : nullptr, gxB, vmid,
                                              phib[b], gvA, gd_e, gu_e);
        if (b == 1) {
            gemm(phib[b], msg_w2 + (size_t)b * FD * FD3, nullptr, s1b[b], nullptr, g_s1, NA, FD, FD3, 0, 0, 1);
            gemm(g_s1, msg_w1 + (size_t)b * FD * FD, nullptr, nullptr, gxB, gxA, NA, FD, FD, 0, 0, 1);
        }
    }
    edge_vec_kernel<<<NE / 256, 256, 0, stream>>>(coord, eidx, d_e, gd_e, gu_e, gvec_e);
    coord_gather_kernel<<<NA / 4, 256, 0, stream>>>(off_dst, perm_dst, off_src, perm_src, gvec_e, gcoord);
}

// Round 12
// 1279.580 us; speedup vs baseline: 1.0009x; 1.0009x over previous
//
#include <hip/hip_runtime.h>
#include <math.h>

// PaiNN energy + analytic coord-gradient.
// R12: R11's load-pairing regressed (VGPR 96->124, compiler already overlapped).
//      msg_bwd reverted to exact R10 block-per-atom form (194us known-best).
//      msg_fwd now gets the same treatment: block-per-atom, 512 threads =
//      4 edge-subsets x 128 feature-threads (serial chain 16 -> ~4, 2x blocks),
//      one 8KB LDS reduce per atom.

#define NA 8192
#define NE 131072
#define FD 128
#define FD3 384
#define NBASE 20
#define HD 64
#define RCUT 5.0f
#define PIF 3.14159265358979f

typedef short bf16x8 __attribute__((ext_vector_type(8)));
typedef float f32x4 __attribute__((ext_vector_type(4)));
typedef _Float16 f16x2 __attribute__((ext_vector_type(2)));

static __device__ __forceinline__ float silu_f(float x) {
    return x / (1.f + expf(-x));
}
static __device__ __forceinline__ float dsilu_f(float x) {
    float s = 1.f / (1.f + expf(-x));
    return s * (1.f + x * (1.f - s));
}
static __device__ __forceinline__ short f2bf(float x) {
    union { float f; unsigned int i; } c; c.f = x;
    unsigned int r = c.i + 0x7fffu + ((c.i >> 16) & 1u);
    return (short)(r >> 16);
}
static __device__ __forceinline__ float bf2f(short u) {
    union { unsigned int i; float f; } c; c.i = ((unsigned int)(unsigned short)u) << 16; return c.f;
}
static __device__ __forceinline__ float dot2f(f16x2 a, f16x2 b, float c) {
#if __has_builtin(__builtin_amdgcn_fdot2)
    return __builtin_amdgcn_fdot2(a, b, c, false);
#else
    return c + (float)a.x * (float)b.x + (float)a.y * (float)b.y;
#endif
}

// ---------------- split-precision bf16 MFMA GEMM ----------------
// C = [silu?](A) @ W (+bias) (*dsilu(pre)) (+addbuf); A [M,K] f32 row-major.
// wtrans=0: W is [K,N] row-major. wtrans=1: W is [N,K] row-major (used as Worig^T).
// Tile 128x64, 4 waves, wave = 32 rows. hi/lo split for ~fp19 effective precision.
__global__ __launch_bounds__(256) void mfma_gemm_kernel(
    const float* __restrict__ A, const float* __restrict__ W,
    const float* __restrict__ bias, const float* __restrict__ dsil,
    const float* __restrict__ addbuf, float* __restrict__ C,
    int M, int N, int K, int asilu, int acc, int wtrans)
{
    __shared__ short AsH[128][40];   // [m][k] bf16 hi, K-tile 32 padded to 40
    __shared__ short AsL[128][40];   // bf16 lo
    __shared__ short WsH[64][40];    // [n][k] bf16 hi
    __shared__ short WsL[64][40];
    int tid = threadIdx.x;
    int row0 = blockIdx.y * 128, col0 = blockIdx.x * 64;
    int wv = tid >> 6, lane = tid & 63;
    int quad = lane >> 4, l16 = lane & 15;

    f32x4 accv[2][4];
    #pragma unroll
    for (int i = 0; i < 2; ++i)
        #pragma unroll
        for (int j = 0; j < 4; ++j) { f32x4 z = {0.f, 0.f, 0.f, 0.f}; accv[i][j] = z; }

    int am = tid >> 1;                 // 0..127
    int ak = (tid & 1) * 16;           // 0 or 16
    const float* abase = A + (size_t)(row0 + am) * K + ak;
    int wn = tid & 63, wk0 = tid >> 6;   // non-trans: k = wk0 + 4p
    int wk2 = tid & 31, wn2 = tid >> 5;  // trans: n = wn2 + 8p

    for (int k0 = 0; k0 < K; k0 += 32) {
        // stage A tile (128x32) with optional silu, f32 -> bf16 hi+lo
        {
            const float* ap = abase + k0;
            #pragma unroll
            for (int i = 0; i < 4; ++i) {
                float4 v = *(const float4*)(ap + 4 * i);
                if (asilu) {
                    v.x = silu_f(v.x); v.y = silu_f(v.y);
                    v.z = silu_f(v.z); v.w = silu_f(v.w);
                }
                float vv[4] = {v.x, v.y, v.z, v.w};
                #pragma unroll
                for (int q = 0; q < 4; ++q) {
                    short h = f2bf(vv[q]);
                    AsH[am][ak + 4 * i + q] = h;
                    AsL[am][ak + 4 * i + q] = f2bf(vv[q] - bf2f(h));
                }
            }
        }
        // stage W tile -> Ws[n][k], hi+lo
        if (!wtrans) {
            #pragma unroll
            for (int p = 0; p < 8; ++p) {
                int k = wk0 + p * 4;
                float v = W[(size_t)(k0 + k) * N + col0 + wn];
                short h = f2bf(v);
                WsH[wn][k] = h;
                WsL[wn][k] = f2bf(v - bf2f(h));
            }
        } else {
            #pragma unroll
            for (int p = 0; p < 8; ++p) {
                int n2 = wn2 + p * 8;
                float v = W[(size_t)(col0 + n2) * K + k0 + wk2];
                short h = f2bf(v);
                WsH[n2][wk2] = h;
                WsL[n2][wk2] = f2bf(v - bf2f(h));
            }
        }
        __syncthreads();
        bf16x8 afH[2], afL[2], bfH[4], bfL[4];
        #pragma unroll
        for (int rt = 0; rt < 2; ++rt) {
            afH[rt] = *(const bf16x8*)&AsH[wv * 32 + rt * 16 + l16][quad * 8];
            afL[rt] = *(const bf16x8*)&AsL[wv * 32 + rt * 16 + l16][quad * 8];
        }
        #pragma unroll
        for (int ct = 0; ct < 4; ++ct) {
            bfH[ct] = *(const bf16x8*)&WsH[ct * 16 + l16][quad * 8];
            bfL[ct] = *(const bf16x8*)&WsL[ct * 16 + l16][quad * 8];
        }
        #pragma unroll
        for (int rt = 0; rt < 2; ++rt)
            #pragma unroll
            for (int ct = 0; ct < 4; ++ct) {
                accv[rt][ct] = __builtin_amdgcn_mfma_f32_16x16x32_bf16(
                    afL[rt], bfH[ct], accv[rt][ct], 0, 0, 0);
                accv[rt][ct] = __builtin_amdgcn_mfma_f32_16x16x32_bf16(
                    afH[rt], bfL[ct], accv[rt][ct], 0, 0, 0);
                accv[rt][ct] = __builtin_amdgcn_mfma_f32_16x16x32_bf16(
                    afH[rt], bfH[ct], accv[rt][ct], 0, 0, 0);
            }
        __syncthreads();
    }
    // epilogue: D[row][col], col = l16, row = quad*4 + r
    #pragma unroll
    for (int rt = 0; rt < 2; ++rt) {
        #pragma unroll
        for (int ct = 0; ct < 4; ++ct) {
            int colv = col0 + ct * 16 + l16;
            float bv = bias ? bias[colv] : 0.f;
            #pragma unroll
            for (int r = 0; r < 4; ++r) {
                int rowv = row0 + wv * 32 + rt * 16 + quad * 4 + r;
                float v = accv[rt][ct][r] + bv;
                size_t idx = (size_t)rowv * N + colv;
                if (dsil) { float pz = dsil[idx]; float s = 1.f / (1.f + expf(-pz)); v *= s * (1.f + pz * (1.f - s)); }
                if (addbuf) v += addbuf[idx];
                if (acc) C[idx] += v; else C[idx] = v;
            }
        }
    }
}

// ---------------- small helpers ----------------
__global__ void embed_kernel(const int* at_no, const float* emb, float* x) {
    int i = blockIdx.x * blockDim.x + threadIdx.x;   // NA*FD threads
    int n = i >> 7, f = i & 127;
    x[i] = emb[(size_t)at_no[n] * FD + f];
}

// builds UVcomb [128][256] = [u | v] and Tcomb [256][128] = [u^T ; v^T]
__global__ void combo_prep_kernel(const float* u, const float* v, float* UVcomb, float* Tcomb) {
    int i = blockIdx.x * blockDim.x + threadIdx.x;   // 32768 threads
    {
        int k = i >> 8, j = i & 255;
        UVcomb[i] = (j < 128) ? u[k * 128 + j] : v[k * 128 + (j - 128)];
    }
    {
        int k = i >> 7, j = i & 127;
        Tcomb[i] = (k < 128) ? u[j * 128 + k] : v[j * 128 + (k - 128)];
    }
}

// ---------------- edge geometry forward (+ CSR histogram fused) ----------------
__global__ void geom_fwd_kernel(const float* coord, const int* ei,
    float* d_e, float* unit_e, float* rbf_e, float* drbf_e, float* fcut_e, float* dfc_e,
    int* cnt_dst, int* cnt_src)
{
    int e = blockIdx.x * blockDim.x + threadIdx.x;
    if (e >= NE) return;
    int s = ei[e], t = ei[NE + e];
    atomicAdd(&cnt_src[s], 1);
    atomicAdd(&cnt_dst[t], 1);
    float rx = coord[t * 3 + 0] - coord[s * 3 + 0];
    float ry = coord[t * 3 + 1] - coord[s * 3 + 1];
    float rz = coord[t * 3 + 2] - coord[s * 3 + 2];
    float r2 = rx * rx + ry * ry + rz * rz;
    float dd = sqrtf(r2 + 1e-12f);
    float inv = 1.f / dd;
    d_e[e] = dd;
    unit_e[e * 3 + 0] = rx * inv; unit_e[e * 3 + 1] = ry * inv; unit_e[e * 3 + 2] = rz * inv;
    const float c0 = 0.6324555320336759f;   // sqrt(2/5)
    for (int k = 0; k < NBASE; ++k) {
        float nk = (k + 1) * (PIF / RCUT);
        float sn, cs; sincosf(nk * dd, &sn, &cs);
        rbf_e[(size_t)e * NBASE + k] = c0 * sn * inv;
        drbf_e[(size_t)e * NBASE + k] = c0 * (nk * cs * inv - sn * inv * inv);
    }
    if (dd < RCUT) {
        float sn, cs; sincosf(PIF * dd / RCUT, &sn, &cs);
        fcut_e[e] = 0.5f * (cs + 1.f);
        dfc_e[e] = -0.5f * (PIF / RCUT) * sn;
    } else { fcut_e[e] = 0.f; dfc_e[e] = 0.f; }
}

// ---------------- CSR build ----------------
__global__ __launch_bounds__(1024) void scan_kernel(
    const int* cnt_dst, const int* cnt_src,
    int* off_dst, int* off_src, int* cur_dst, int* cur_src)
{
    __shared__ int part[1024];
    const int* cnt = (blockIdx.x == 0) ? cnt_dst : cnt_src;
    int* off = (blockIdx.x == 0) ? off_dst : off_src;
    int* cur = (blockIdx.x == 0) ? cur_dst : cur_src;
    int t = threadIdx.x;
    int base = t * 8;
    int loc[8]; int s = 0;
    #pragma unroll
    for (int i = 0; i < 8; ++i) { loc[i] = s; s += cnt[base + i]; }
    part[t] = s;
    __syncthreads();
    for (int d = 1; d < 1024; d <<= 1) {
        int v = part[t];
        int w = (t >= d) ? part[t - d] : 0;
        __syncthreads();
        part[t] = v + w;
        __syncthreads();
    }
    int pre = (t == 0) ? 0 : part[t - 1];
    #pragma unroll
    for (int i = 0; i < 8; ++i) { int o = pre + loc[i]; off[base + i] = o; cur[base + i] = o; }
    if (t == 1023) off[NA] = part[1023];
}

__global__ void scatter_kernel(const int* ei, int* cur_dst, int* cur_src,
                               int* perm_dst, int* perm_src, int* srcp, int* dstp) {
    int e = blockIdx.x * blockDim.x + threadIdx.x;
    if (e >= NE) return;
    int s = ei[e], t = ei[NE + e];
    int pd = atomicAdd(&cur_dst[t], 1); perm_dst[pd] = e; srcp[pd] = s;
    int ps = atomicAdd(&cur_src[s], 1); perm_src[ps] = e; dstp[ps] = t;
}

// ---------------- message forward: one BLOCK (512 thr) per dst atom ----------------
// 4 edge-subsets x 128 feature-threads; subset sub handles edges e0+sub, +4.
// Partials combined via 8KB LDS; write duty split by subset.
__global__ __launch_bounds__(512) void msg_fwd_kernel(
    const int* __restrict__ row_off_dst, const int* __restrict__ perm_dst, const int* __restrict__ srcp,
    const float* __restrict__ rbf_e, const float* __restrict__ fcut_e, const float* __restrict__ unit_e,
    const float* __restrict__ phi, const float* __restrict__ Wr, const float* __restrict__ br,
    const float* __restrict__ x_in, const float* __restrict__ v_in,   // v_in may be null (block 0)
    float* __restrict__ x_mid, float* __restrict__ v_mid)
{
    __shared__ float red[4][4][FD];   // [quantity][subset][feature]
    int tid = threadIdx.x;
    int sub = tid >> 7;     // 0..3
    int f = tid & 127;
    int n = blockIdx.x;
    float w0[NBASE], w1[NBASE], w2[NBASE];
    #pragma unroll
    for (int k = 0; k < NBASE; ++k) {
        w0[k] = Wr[k * FD3 + f];
        w1[k] = Wr[k * FD3 + FD + f];
        w2[k] = Wr[k * FD3 + 2 * FD + f];
    }
    float b0 = br[f], b1 = br[FD + f], b2 = br[2 * FD + f];
    float xa = 0.f, va0 = 0.f, va1 = 0.f, va2 = 0.f;
    int e0 = row_off_dst[n], e1 = row_off_dst[n + 1];
    for (int ii = e0 + sub; ii < e1; ii += 4) {
        int e = perm_dst[ii];
        int s = srcp[ii];
        float fc = fcut_e[e];
        const float* rp = rbf_e + (size_t)e * NBASE;
        float raw0 = b0, raw1 = b1, raw2 = b2;
        #pragma unroll
        for (int k = 0; k < NBASE; ++k) {
            float r = rp[k];
            raw0 = fmaf(r, w0[k], raw0);
            raw1 = fmaf(r, w1[k], raw1);
            raw2 = fmaf(r, w2[k], raw2);
        }
        float f0 = raw0 * fc, f1 = raw1 * fc, f2 = raw2 * fc;
        const float* ph = phi + (size_t)s * FD3;
        float m0 = ph[f] * f0, m1 = ph[FD + f] * f1, m2 = ph[2 * FD + f] * f2;
        xa += m0;
        float u0 = unit_e[e * 3], u1 = unit_e[e * 3 + 1], u2 = unit_e[e * 3 + 2];
        float vs0 = 0.f, vs1 = 0.f, vs2 = 0.f;
        if (v_in) {
            const float* vp = v_in + (size_t)s * 3 * FD;
            vs0 = vp[f]; vs1 = vp[FD + f]; vs2 = vp[2 * FD + f];
        }
        va0 += m1 * vs0 + m2 * u0;
        va1 += m1 * vs1 + m2 * u1;
        va2 += m1 * vs2 + m2 * u2;
    }
    red[0][sub][f] = xa; red[1][sub][f] = va0; red[2][sub][f] = va1; red[3][sub][f] = va2;
    __syncthreads();
    // subset q combines + writes quantity q
    float v = red[sub][0][f] + red[sub][1][f] + red[sub][2][f] + red[sub][3][f];
    if (sub == 0) {
        size_t xb = (size_t)n * FD + f;
        x_mid[xb] = x_in[xb] + v;
    } else {
        size_t vb = (size_t)n * 3 * FD + (sub - 1) * FD + f;
        float p = v_in ? v_in[vb] : 0.f;
        v_mid[vb] = p + v;
    }
}

// ---------------- update-block pointwise kernels (uvvv interleaved layout) ------------
// uvvv rows: row = n*3+i, cols 0..127 = uv, 128..255 = vv.
__global__ void vnorm_cat_kernel(const float* xmid, const float* uvvv, float* vnorm, float* cat) {
    int i = blockIdx.x * blockDim.x + threadIdx.x;  // NA*FD
    int n = i >> 7, g = i & 127;
    size_t ub = (size_t)n * 3 * 256 + 128 + g;
    float a = uvvv[ub], b = uvvv[ub + 256], c = uvvv[ub + 512];
    float vn = sqrtf(a * a + b * b + c * c + 1e-12f);
    vnorm[i] = vn;
    cat[(size_t)n * 2 * FD + g] = xmid[i];
    cat[(size_t)n * 2 * FD + FD + g] = vn;
}

__global__ void combine_kernel(const float* xmid, const float* vmid,
    const float* uvvv, const float* a_,
    float* x_out, float* v_out /* nullable */)
{
    int i = blockIdx.x * blockDim.x + threadIdx.x;  // NA*FD
    int n = i >> 7, g = i & 127;
    size_t vb = (size_t)n * 3 * FD + g;
    size_t ub = (size_t)n * 3 * 256 + g;
    float uv0 = uvvv[ub], uv1 = uvvv[ub + 256], uv2 = uvvv[ub + 512];
    float vv0 = uvvv[ub + 128], vv1 = uvvv[ub + 384], vv2 = uvvv[ub + 640];
    float S = uv0 * vv0 + uv1 * vv1 + uv2 * vv2;
    const float* ar = a_ + (size_t)n * FD3;
    x_out[i] = xmid[i] + ar[FD + g] * S + ar[2 * FD + g];
    if (v_out) {
        float avv = ar[g];
        v_out[vb] = vmid[vb] + avv * uv0;
        v_out[vb + FD] = vmid[vb + FD] + avv * uv1;
        v_out[vb + 2 * FD] = vmid[vb + 2 * FD] + avv * uv2;
    }
}

// ---------------- output head ----------------
__global__ __launch_bounds__(256) void energy_kernel(
    const float* tout, const float* ow2, const float* ob2,
    const float* atom_sp, const int* at_no, float* out)
{
    int n = blockIdx.x * 256 + threadIdx.x;   // NA exact
    float e = ob2[0] + atom_sp[at_no[n]];
    for (int h = 0; h < HD; ++h) {
        float t = tout[(size_t)n * HD + h];
        e = fmaf(silu_f(t), ow2[h], e);
    }
    #pragma unroll
    for (int off = 32; off > 0; off >>= 1) e += __shfl_down(e, off);
    __shared__ float s[4];
    int lane = threadIdx.x & 63, wv = threadIdx.x >> 6;
    if (lane == 0) s[wv] = e;
    __syncthreads();
    if (threadIdx.x == 0) atomicAdd(out, s[0] + s[1] + s[2] + s[3]);
}

__global__ __launch_bounds__(128) void head_bwd_kernel(
    const float* tout, const float* ow1, const float* ow2, float* gx)
{
    __shared__ float sh[HD];
    int n = blockIdx.x, f = threadIdx.x;
    if (f < HD) {
        float p = tout[(size_t)n * HD + f];
        sh[f] = dsilu_f(p) * ow2[f];
    }
    __syncthreads();
    float g = 0.f;
    #pragma unroll
    for (int h = 0; h < HD; ++h) g = fmaf(sh[h], ow1[f * HD + h], g);
    gx[(size_t)n * FD + f] = g;
}

// ---------------- update-block backward pointwise ----------------
__global__ void ubwd1_kernel(const float* gx, const float* gv,
    const float* uvvv, float* g_a)
{
    int i = blockIdx.x * blockDim.x + threadIdx.x;  // NA*FD
    int n = i >> 7, g = i & 127;
    size_t vb = (size_t)n * 3 * FD + g;
    size_t ub = (size_t)n * 3 * 256 + g;
    float uv0 = uvvv[ub], uv1 = uvvv[ub + 256], uv2 = uvvv[ub + 512];
    float vv0 = uvvv[ub + 128], vv1 = uvvv[ub + 384], vv2 = uvvv[ub + 640];
    float gv0 = gv[vb], gv1 = gv[vb + FD], gv2 = gv[vb + 2 * FD];
    float gxv = gx[i];
    float S = uv0 * vv0 + uv1 * vv1 + uv2 * vv2;
    size_t ab = (size_t)n * FD3;
    g_a[ab + g]           = gv0 * uv0 + gv1 * uv1 + gv2 * uv2;   // g w.r.t. a_vv
    g_a[ab + FD + g]      = gxv * S;                              // g w.r.t. a_sv
    g_a[ab + 2 * FD + g]  = gxv;                                  // g w.r.t. a_ss
}

// NOTE: uvvv is read then overwritten in place (g_uv/g_vv); no __restrict__ on it.
__global__ void ubwd2_kernel(const float* gx_in, const float* gv_in,
    const float* a_, const float* vnorm, const float* g_cat,
    float* uvvv, float* gx_mid, float* gv_tmp)
{
    int i = blockIdx.x * blockDim.x + threadIdx.x;  // NA*FD
    int n = i >> 7, g = i & 127;
    size_t vb = (size_t)n * 3 * FD + g, ab = (size_t)n * FD3;
    size_t ub = (size_t)n * 3 * 256 + g;
    float gxv = gx_in[i];
    float gS = gxv * a_[ab + FD + g];
    float avv = a_[ab + g];
    float gvn = g_cat[(size_t)n * 2 * FD + FD + g];
    float c = gvn / vnorm[i];
    float uv0 = uvvv[ub], uv1 = uvvv[ub + 256], uv2 = uvvv[ub + 512];
    float vv0 = uvvv[ub + 128], vv1 = uvvv[ub + 384], vv2 = uvvv[ub + 640];
    float gv0 = gv_in[vb], gv1 = gv_in[vb + FD], gv2 = gv_in[vb + 2 * FD];
    uvvv[ub]       = gv0 * avv + gS * vv0;
    uvvv[ub + 256] = gv1 * avv + gS * vv1;
    uvvv[ub + 512] = gv2 * avv + gS * vv2;
    uvvv[ub + 128] = gS * uv0 + c * vv0;
    uvvv[ub + 384] = gS * uv1 + c * vv1;
    uvvv[ub + 640] = gS * uv2 + c * vv2;
    gv_tmp[vb] = gv0; gv_tmp[vb + FD] = gv1; gv_tmp[vb + 2 * FD] = gv2;
    gx_mid[i] = gxv + g_cat[(size_t)n * 2 * FD + g];
}

// ---------------- merged message backward: one BLOCK (4 waves) per src atom --------
// Wave wv processes edges ii = e0+wv, e0+wv+4, ... (unique ownership, no atomics).
// Per-edge body: register-f16 Wr + dot2 (no LDS in loop). Per-lane gp/ga partials
// are block-reduced through 12KB LDS once at the end.  [exact R10 version]
__global__ __launch_bounds__(256) void msg_bwd_merged_kernel(
    const int* __restrict__ row_off_src, const int* __restrict__ perm_src, const int* __restrict__ dstp,
    const float* __restrict__ rbf_e, const float* __restrict__ drbf_e,
    const float* __restrict__ fcut_e, const float* __restrict__ dfc_e,
    const float* __restrict__ unit_e,
    const float* phi, const float* __restrict__ Wr, const float* __restrict__ br,
    const float* __restrict__ v_in,              // nullable (block 0)
    const float* __restrict__ gx_mid, const float* __restrict__ gv_mid,
    float* gphi_out,                // aliases phi (own-atom read-then-write, barrier-protected)
    float* __restrict__ gv_out,
    float* __restrict__ gd_e, float* __restrict__ gu_e)
{
    __shared__ float red[12][4][64];
    int tid = threadIdx.x;
    int wv = tid >> 6, lane = tid & 63;
    int n = blockIdx.x;
    // weights for both feature halves, packed f16 pairs along k
    f16x2 w[2][3][10];
    float brv[2][3], ph[2][3], vs[2][3];
    #pragma unroll
    for (int h = 0; h < 2; ++h) {
        int f = lane + h * 64;
        #pragma unroll
        for (int s = 0; s < 3; ++s) {
            #pragma unroll
            for (int k2 = 0; k2 < 10; ++k2) {
                f16x2 t;
                t.x = (_Float16)Wr[(2 * k2) * FD3 + s * FD + f];
                t.y = (_Float16)Wr[(2 * k2 + 1) * FD3 + s * FD + f];
                w[h][s][k2] = t;
            }
            brv[h][s] = br[s * FD + f];
            ph[h][s] = phi[(size_t)n * FD3 + s * FD + f];
            vs[h][s] = v_in ? v_in[(size_t)n * 3 * FD + s * FD + f] : 0.f;
        }
    }
    float gp[2][3] = {{0.f, 0.f, 0.f}, {0.f, 0.f, 0.f}};
    float ga[2][3] = {{0.f, 0.f, 0.f}, {0.f, 0.f, 0.f}};
    int e0 = row_off_src[n], e1 = row_off_src[n + 1];
    for (int ii = e0 + wv; ii < e1; ii += 4) {
        int e = perm_src[ii], dd = dstp[ii];
        float fc = fcut_e[e], dfc = dfc_e[e];
        float u0 = unit_e[e * 3], u1 = unit_e[e * 3 + 1], u2 = unit_e[e * 3 + 2];
        const float* rp = rbf_e + (size_t)e * NBASE;
        const float* dp = drbf_e + (size_t)e * NBASE;
        f16x2 rb2[10], db2[10];
        #pragma unroll
        for (int k2 = 0; k2 < 10; ++k2) {
            f16x2 a, b;
            a.x = (_Float16)rp[2 * k2]; a.y = (_Float16)rp[2 * k2 + 1];
            b.x = (_Float16)dp[2 * k2]; b.y = (_Float16)dp[2 * k2 + 1];
            rb2[k2] = a; db2[k2] = b;
        }
        float r0 = 0.f, r1 = 0.f, r2 = 0.f, r3 = 0.f;
        #pragma unroll
        for (int h = 0; h < 2; ++h) {
            int f = lane + h * 64;
            float raw0 = brv[h][0], raw1 = brv[h][1], raw2 = brv[h][2];
            float A0 = 0.f, A1 = 0.f, A2 = 0.f;
            #pragma unroll
            for (int k2 = 0; k2 < 10; ++k2) {
                raw0 = dot2f(rb2[k2], w[h][0][k2], raw0);
                raw1 = dot2f(rb2[k2], w[h][1][k2], raw1);
                raw2 = dot2f(rb2[k2], w[h][2][k2], raw2);
                A0 = dot2f(db2[k2], w[h][0][k2], A0);
                A1 = dot2f(db2[k2], w[h][1][k2], A1);
                A2 = dot2f(db2[k2], w[h][2][k2], A2);
            }
            float f0 = raw0 * fc, f1 = raw1 * fc, f2 = raw2 * fc;
            float gds = gx_mid[(size_t)dd * FD + f];
            const float* gvp = gv_mid + (size_t)dd * 3 * FD;
            float gd0 = gvp[f], gd1 = gvp[FD + f], gd2 = gvp[2 * FD + f];
            float gdv1 = gd0 * vs[h][0] + gd1 * vs[h][1] + gd2 * vs[h][2];
            float gdv2 = gd0 * u0 + gd1 * u1 + gd2 * u2;
            float dv1 = ph[h][1] * f1;
            ga[h][0] += gd0 * dv1; ga[h][1] += gd1 * dv1; ga[h][2] += gd2 * dv1;
            gp[h][0] += gds * f0; gp[h][1] += gdv1 * f1; gp[h][2] += gdv2 * f2;
            float dv2 = ph[h][2] * f2;
            r1 += gd0 * dv2; r2 += gd1 * dv2; r3 += gd2 * dv2;
            float gf0 = gds * ph[h][0], gf1 = gdv1 * ph[h][1], gf2 = gdv2 * ph[h][2];
            r0 += fc * (gf0 * A0 + gf1 * A1 + gf2 * A2)
                + dfc * (gf0 * raw0 + gf1 * raw1 + gf2 * raw2);
        }
        #pragma unroll
        for (int off = 32; off > 0; off >>= 1) {
            r0 += __shfl_down(r0, off);
            r1 += __shfl_down(r1, off);
            r2 += __shfl_down(r2, off);
            r3 += __shfl_down(r3, off);
        }
        if (lane == 0) {
            gd_e[e] += r0;
            gu_e[e * 3]     += r1;
            gu_e[e * 3 + 1] += r2;
            gu_e[e * 3 + 2] += r3;
        }
    }
    // block reduce of gp/ga across the 4 waves
    #pragma unroll
    for (int h = 0; h < 2; ++h)
        #pragma unroll
        for (int s = 0; s < 3; ++s) {
            red[h * 3 + s][wv][lane] = gp[h][s];
            red[6 + h * 3 + s][wv][lane] = ga[h][s];
        }
    __syncthreads();
    int j0 = tid >> 6;   // 0..3
    #pragma unroll
    for (int rep = 0; rep < 3; ++rep) {
        int j = j0 + rep * 4;
        float v = red[j][0][lane] + red[j][1][lane] + red[j][2][lane] + red[j][3][lane];
        int jj = (j < 6) ? j : j - 6;
        int h = jj / 3, s = jj - 3 * h;
        int f = h * 64 + lane;
        if (j < 6) {
            gphi_out[(size_t)n * FD3 + s * FD + f] = v;
        } else {
            size_t vb = (size_t)n * 3 * FD + s * FD + f;
            gv_out[vb] = gv_mid[vb] + v;
        }
    }
}

// ---------------- geometry backward: per-edge grad vector (no atomics) ----------------
// NOTE: gvec aliases gu_e (same-thread read-then-write) — no __restrict__.
__global__ void edge_vec_kernel(const float* coord, const int* ei,
    const float* d_e, const float* gd_e, const float* gu_e, float* gvec)
{
    int e = blockIdx.x * blockDim.x + threadIdx.x;
    if (e >= NE) return;
    int s = ei[e], t = ei[NE + e];
    float rx = coord[t * 3 + 0] - coord[s * 3 + 0];
    float ry = coord[t * 3 + 1] - coord[s * 3 + 1];
    float rz = coord[t * 3 + 2] - coord[s * 3 + 2];
    float dd = d_e[e];
    float inv = 1.f / dd;
    float gu0 = gu_e[e * 3], gu1 = gu_e[e * 3 + 1], gu2 = gu_e[e * 3 + 2];
    float gd = gd_e[e];
    float dot = gu0 * rx + gu1 * ry + gu2 * rz;
    float coef = gd * inv - dot * inv * inv * inv;
    gvec[e * 3 + 0] = gu0 * inv + coef * rx;
    gvec[e * 3 + 1] = gu1 * inv + coef * ry;
    gvec[e * 3 + 2] = gu2 * inv + coef * rz;
}

// one wave per atom: gcoord[n] = sum_{dst edges} gvec - sum_{src edges} gvec
__global__ __launch_bounds__(256) void coord_gather_kernel(
    const int* __restrict__ off_dst, const int* __restrict__ perm_dst,
    const int* __restrict__ off_src, const int* __restrict__ perm_src,
    const float* __restrict__ gvec, float* __restrict__ gcoord)
{
    int n = blockIdx.x * 4 + (threadIdx.x >> 6);
    int lane = threadIdx.x & 63;
    float a0 = 0.f, a1 = 0.f, a2 = 0.f;
    int d0 = off_dst[n], d1 = off_dst[n + 1];
    for (int ii = d0 + lane; ii < d1; ii += 64) {
        int e = perm_dst[ii];
        a0 += gvec[e * 3]; a1 += gvec[e * 3 + 1]; a2 += gvec[e * 3 + 2];
    }
    int s0 = off_src[n], s1 = off_src[n + 1];
    for (int ii = s0 + lane; ii < s1; ii += 64) {
        int e = perm_src[ii];
        a0 -= gvec[e * 3]; a1 -= gvec[e * 3 + 1]; a2 -= gvec[e * 3 + 2];
    }
    #pragma unroll
    for (int off = 32; off > 0; off >>= 1) {
        a0 += __shfl_down(a0, off);
        a1 += __shfl_down(a1, off);
        a2 += __shfl_down(a2, off);
    }
    if (lane == 0) {
        gcoord[n * 3 + 0] = a0; gcoord[n * 3 + 1] = a1; gcoord[n * 3 + 2] = a2;
    }
}

// ======================================================================
extern "C" void kernel_launch(void* const* d_in, const int* in_sizes, int n_in,
                              void* d_out, int out_size, void* d_ws, size_t ws_size,
                              hipStream_t stream)
{
    (void)in_sizes; (void)n_in; (void)out_size; (void)ws_size;
    const int*   at_no   = (const int*)  d_in[0];
    const float* coord   = (const float*)d_in[1];
    const int*   eidx    = (const int*)  d_in[2];
    const float* emb     = (const float*)d_in[5];
    const float* atom_sp = (const float*)d_in[6];
    const float* msg_w1  = (const float*)d_in[7];
    const float* msg_b1  = (const float*)d_in[8];
    const float* msg_w2  = (const float*)d_in[9];
    const float* msg_b2  = (const float*)d_in[10];
    const float* msg_wr  = (const float*)d_in[11];
    const float* msg_br  = (const float*)d_in[12];
    const float* upd_u   = (const float*)d_in[13];
    const float* upd_v   = (const float*)d_in[14];
    const float* upd_w1  = (const float*)d_in[15];
    const float* upd_b1  = (const float*)d_in[16];
    const float* upd_w2  = (const float*)d_in[17];
    const float* upd_b2  = (const float*)d_in[18];
    const float* out_w1  = (const float*)d_in[19];
    const float* out_b1  = (const float*)d_in[20];
    const float* out_w2  = (const float*)d_in[21];
    const float* out_b2  = (const float*)d_in[22];
    float* out = (float*)d_out;
    float* gcoord = out + 1;

    char* wp = (char*)d_ws;
    auto alloc = [&](size_t nelem) -> float* {
        float* r = (float*)wp; wp += ((nelem * 4 + 255) & ~(size_t)255); return r;
    };
    auto alloci = [&](size_t nelem) -> int* {
        int* r = (int*)wp; wp += ((nelem * 4 + 255) & ~(size_t)255); return r;
    };
    const size_t NF = (size_t)NA * FD;

    float* d_e    = alloc(NE);
    float* unit_e = alloc(3 * (size_t)NE);
    float* rbf_e  = alloc((size_t)NBASE * NE);
    float* drbf_e = alloc((size_t)NBASE * NE);
    float* fcut_e = alloc(NE);
    float* dfc_e  = alloc(NE);
    float* gd_e   = alloc(NE);
    float* gu_e   = alloc(3 * (size_t)NE);
    int* cnt_dst = alloci(NA); int* cnt_src = alloci(NA);
    int* off_dst = alloci(NA + 1); int* off_src = alloci(NA + 1);
    int* cur_dst = alloci(NA); int* cur_src = alloci(NA);
    int* perm_dst = alloci(NE); int* perm_src = alloci(NE);
    int* srcp = alloci(NE); int* dstp = alloci(NE);
    float* xin_all = alloc(3 * NF);
    float* xin0 = xin_all; float* xin1 = xin_all + NF; float* xfin = xin_all + 2 * NF;
    float* vout0 = alloc(3 * NF);
    float* xmid = alloc(NF);
    float* vmid = alloc(3 * NF);            // reused as gv_tmp in backward
    float* catb = alloc(2 * NF);
    float* toutb = alloc((size_t)NA * HD);
    float *s1b[2], *phib[2], *uvvv[2], *vnb[2], *t1b[2], *ab[2];
    for (int b = 0; b < 2; ++b) {
        s1b[b] = alloc(NF); phib[b] = alloc(3 * NF); uvvv[b] = alloc(6 * NF);
        vnb[b] = alloc(NF); t1b[b] = alloc(NF); ab[b] = alloc(3 * NF);
    }
    float* gxA = alloc(NF); float* gxB = alloc(NF);
    float* gvA = alloc(3 * NF);
    // backward aliases of dead forward buffers:
    float* g_a   = xin_all;   // 3*NF
    float* g_cat = catb;      // 2*NF
    float* g_t1  = xmid;      // NF
    float* g_s1  = s1b[0];    // NF (only used in b==1 path)
    float* gvec_e = gu_e;     // in-place transform in edge_vec
    float *UVcomb[2], *Tcomb[2];
    for (int b = 0; b < 2; ++b) { UVcomb[b] = alloc(FD * 256); Tcomb[b] = alloc(256 * FD); }

    // zero-init (harness poisons d_out/d_ws with 0xAA before every call)
    hipMemsetAsync(d_out, 0, (size_t)(1 + NA * 3) * 4, stream);
    hipMemsetAsync(cnt_dst, 0, (size_t)NA * 4, stream);
    hipMemsetAsync(cnt_src, 0, (size_t)NA * 4, stream);
    hipMemsetAsync(gd_e, 0, (size_t)NE * 4, stream);
    hipMemsetAsync(gu_e, 0, 3ull * NE * 4, stream);
    hipMemsetAsync(gvA, 0, 3 * NF * 4, stream);

    geom_fwd_kernel<<<NE / 256, 256, 0, stream>>>(coord, eidx, d_e, unit_e, rbf_e, drbf_e,
                                                  fcut_e, dfc_e, cnt_dst, cnt_src);
    scan_kernel<<<2, 1024, 0, stream>>>(cnt_dst, cnt_src, off_dst, off_src, cur_dst, cur_src);
    scatter_kernel<<<NE / 256, 256, 0, stream>>>(eidx, cur_dst, cur_src, perm_dst, perm_src, srcp, dstp);
    embed_kernel<<<NF / 256, 256, 0, stream>>>(at_no, emb, xin0);
    for (int b = 0; b < 2; ++b)
        combo_prep_kernel<<<128, 256, 0, stream>>>(upd_u + (size_t)b * FD * FD,
                                                   upd_v + (size_t)b * FD * FD, UVcomb[b], Tcomb[b]);

    auto gemm = [&](const float* A, const float* W, const float* bias, const float* dsil,
                    const float* addb, float* C, int M, int Nn, int K, int asilu, int acc, int wtrans) {
        dim3 g(Nn / 64, M / 128);
        mfma_gemm_kernel<<<g, 256, 0, stream>>>(A, W, bias, dsil, addb, C, M, Nn, K, asilu, acc, wtrans);
    };

    // ---------------- forward ----------------
    for (int b = 0; b < 2; ++b) {
        const float* xinb = b ? xin1 : xin0;
        const float* vin  = b ? vout0 : nullptr;
        gemm(xinb, msg_w1 + (size_t)b * FD * FD, msg_b1 + b * FD, nullptr, nullptr, s1b[b], NA, FD, FD, 0, 0, 0);
        gemm(s1b[b], msg_w2 + (size_t)b * FD * FD3, msg_b2 + b * FD3, nullptr, nullptr, phib[b], NA, FD3, FD, 1, 0, 0);
        msg_fwd_kernel<<<NA, 512, 0, stream>>>(off_dst, perm_dst, srcp, rbf_e, fcut_e, unit_e,
                                              phib[b], msg_wr + (size_t)b * NBASE * FD3, msg_br + b * FD3,
                                              xinb, vin, xmid, vmid);
        gemm(vmid, UVcomb[b], nullptr, nullptr, nullptr, uvvv[b], 3 * NA, 256, FD, 0, 0, 0);
        vnorm_cat_kernel<<<NF / 256, 256, 0, stream>>>(xmid, uvvv[b], vnb[b], catb);
        gemm(catb, upd_w1 + (size_t)b * 2 * FD * FD, upd_b1 + b * FD, nullptr, nullptr, t1b[b], NA, FD, 2 * FD, 0, 0, 0);
        gemm(t1b[b], upd_w2 + (size_t)b * FD * FD3, upd_b2 + b * FD3, nullptr, nullptr, ab[b], NA, FD3, FD, 1, 0, 0);
        combine_kernel<<<NF / 256, 256, 0, stream>>>(xmid, vmid, uvvv[b], ab[b],
                                                     b ? xfin : xin1, b ? nullptr : vout0);
    }
    gemm(xfin, out_w1, out_b1, nullptr, nullptr, toutb, NA, HD, FD, 0, 0, 0);
    energy_kernel<<<NA / 256, 256, 0, stream>>>(toutb, out_w2, out_b2, atom_sp, at_no, out);

    // ---------------- backward ----------------
    head_bwd_kernel<<<NA, FD, 0, stream>>>(toutb, out_w1, out_w2, gxA);
    for (int b = 1; b >= 0; --b) {
        ubwd1_kernel<<<NF / 256, 256, 0, stream>>>(gxA, gvA, uvvv[b], g_a);
        gemm(g_a, upd_w2 + (size_t)b * FD * FD3, nullptr, t1b[b], nullptr, g_t1, NA, FD, FD3, 0, 0, 1);
        gemm(g_t1, upd_w1 + (size_t)b * 2 * FD * FD, nullptr, nullptr, nullptr, g_cat, NA, 2 * FD, FD, 0, 0, 1);
        ubwd2_kernel<<<NF / 256, 256, 0, stream>>>(gxA, gvA, ab[b], vnb[b], g_cat,
                                                   uvvv[b], gxB, vmid);
        gemm(uvvv[b], Tcomb[b], nullptr, nullptr, nullptr, vmid, 3 * NA, FD, 256, 0, 1, 0);
        msg_bwd_merged_kernel<<<NA, 256, 0, stream>>>(off_src, perm_src, dstp,
                                              rbf_e, drbf_e, fcut_e, dfc_e, unit_e,
                                              phib[b], msg_wr + (size_t)b * NBASE * FD3, msg_br + b * FD3,
                                              b ? vout0 : nullptr, gxB, vmid,
                                              phib[b], gvA, gd_e, gu_e);
        if (b == 1) {
            gemm(phib[b], msg_w2 + (size_t)b * FD * FD3, nullptr, s1b[b], nullptr, g_s1, NA, FD, FD3, 0, 0, 1);
            gemm(g_s1, msg_w1 + (size_t)b * FD * FD, nullptr, nullptr, gxB, gxA, NA, FD, FD, 0, 0, 1);
        }
    }
    edge_vec_kernel<<<NE / 256, 256, 0, stream>>>(coord, eidx, d_e, gd_e, gu_e, gvec_e);
    coord_gather_kernel<<<NA / 4, 256, 0, stream>>>(off_dst, perm_dst, off_src, perm_src, gvec_e, gcoord);
}

// Round 13
// 1207.756 us; speedup vs baseline: 1.0604x; 1.0595x over previous
//
#include <hip/hip_runtime.h>
#include <math.h>

// PaiNN energy + analytic coord-gradient.
// R13: exact R10 structure (best known, 1226us). Two load-reducing tweaks in
//      msg_bwd's serial chain: (1) rbf/drbf pre-packed as f16 pairs in geom_fwd
//      (40 f32 loads+cvt/edge -> 20 dword loads); (2) Wr pre-packed f16
//      (preamble 120 f32 loads -> 60 dword loads). No structural changes.

#define NA 8192
#define NE 131072
#define FD 128
#define FD3 384
#define NBASE 20
#define HD 64
#define RCUT 5.0f
#define PIF 3.14159265358979f

typedef short bf16x8 __attribute__((ext_vector_type(8)));
typedef float f32x4 __attribute__((ext_vector_type(4)));
typedef _Float16 f16x2 __attribute__((ext_vector_type(2)));

static __device__ __forceinline__ float silu_f(float x) {
    return x / (1.f + expf(-x));
}
static __device__ __forceinline__ float dsilu_f(float x) {
    float s = 1.f / (1.f + expf(-x));
    return s * (1.f + x * (1.f - s));
}
static __device__ __forceinline__ short f2bf(float x) {
    union { float f; unsigned int i; } c; c.f = x;
    unsigned int r = c.i + 0x7fffu + ((c.i >> 16) & 1u);
    return (short)(r >> 16);
}
static __device__ __forceinline__ float bf2f(short u) {
    union { unsigned int i; float f; } c; c.i = ((unsigned int)(unsigned short)u) << 16; return c.f;
}
static __device__ __forceinline__ float dot2f(f16x2 a, f16x2 b, float c) {
#if __has_builtin(__builtin_amdgcn_fdot2)
    return __builtin_amdgcn_fdot2(a, b, c, false);
#else
    return c + (float)a.x * (float)b.x + (float)a.y * (float)b.y;
#endif
}
static __device__ __forceinline__ unsigned int packf16(float a, float b) {
    union { _Float16 h[2]; unsigned int u; } c;
    c.h[0] = (_Float16)a; c.h[1] = (_Float16)b;
    return c.u;
}

// ---------------- split-precision bf16 MFMA GEMM ----------------
// C = [silu?](A) @ W (+bias) (*dsilu(pre)) (+addbuf); A [M,K] f32 row-major.
// wtrans=0: W is [K,N] row-major. wtrans=1: W is [N,K] row-major (used as Worig^T).
// Tile 128x64, 4 waves, wave = 32 rows. hi/lo split for ~fp19 effective precision.
__global__ __launch_bounds__(256) void mfma_gemm_kernel(
    const float* __restrict__ A, const float* __restrict__ W,
    const float* __restrict__ bias, const float* __restrict__ dsil,
    const float* __restrict__ addbuf, float* __restrict__ C,
    int M, int N, int K, int asilu, int acc, int wtrans)
{
    __shared__ short AsH[128][40];   // [m][k] bf16 hi, K-tile 32 padded to 40
    __shared__ short AsL[128][40];   // bf16 lo
    __shared__ short WsH[64][40];    // [n][k] bf16 hi
    __shared__ short WsL[64][40];
    int tid = threadIdx.x;
    int row0 = blockIdx.y * 128, col0 = blockIdx.x * 64;
    int wv = tid >> 6, lane = tid & 63;
    int quad = lane >> 4, l16 = lane & 15;

    f32x4 accv[2][4];
    #pragma unroll
    for (int i = 0; i < 2; ++i)
        #pragma unroll
        for (int j = 0; j < 4; ++j) { f32x4 z = {0.f, 0.f, 0.f, 0.f}; accv[i][j] = z; }

    int am = tid >> 1;                 // 0..127
    int ak = (tid & 1) * 16;           // 0 or 16
    const float* abase = A + (size_t)(row0 + am) * K + ak;
    int wn = tid & 63, wk0 = tid >> 6;   // non-trans: k = wk0 + 4p
    int wk2 = tid & 31, wn2 = tid >> 5;  // trans: n = wn2 + 8p

    for (int k0 = 0; k0 < K; k0 += 32) {
        // stage A tile (128x32) with optional silu, f32 -> bf16 hi+lo
        {
            const float* ap = abase + k0;
            #pragma unroll
            for (int i = 0; i < 4; ++i) {
                float4 v = *(const float4*)(ap + 4 * i);
                if (asilu) {
                    v.x = silu_f(v.x); v.y = silu_f(v.y);
                    v.z = silu_f(v.z); v.w = silu_f(v.w);
                }
                float vv[4] = {v.x, v.y, v.z, v.w};
                #pragma unroll
                for (int q = 0; q < 4; ++q) {
                    short h = f2bf(vv[q]);
                    AsH[am][ak + 4 * i + q] = h;
                    AsL[am][ak + 4 * i + q] = f2bf(vv[q] - bf2f(h));
                }
            }
        }
        // stage W tile -> Ws[n][k], hi+lo
        if (!wtrans) {
            #pragma unroll
            for (int p = 0; p < 8; ++p) {
                int k = wk0 + p * 4;
                float v = W[(size_t)(k0 + k) * N + col0 + wn];
                short h = f2bf(v);
                WsH[wn][k] = h;
                WsL[wn][k] = f2bf(v - bf2f(h));
            }
        } else {
            #pragma unroll
            for (int p = 0; p < 8; ++p) {
                int n2 = wn2 + p * 8;
                float v = W[(size_t)(col0 + n2) * K + k0 + wk2];
                short h = f2bf(v);
                WsH[n2][wk2] = h;
                WsL[n2][wk2] = f2bf(v - bf2f(h));
            }
        }
        __syncthreads();
        bf16x8 afH[2], afL[2], bfH[4], bfL[4];
        #pragma unroll
        for (int rt = 0; rt < 2; ++rt) {
            afH[rt] = *(const bf16x8*)&AsH[wv * 32 + rt * 16 + l16][quad * 8];
            afL[rt] = *(const bf16x8*)&AsL[wv * 32 + rt * 16 + l16][quad * 8];
        }
        #pragma unroll
        for (int ct = 0; ct < 4; ++ct) {
            bfH[ct] = *(const bf16x8*)&WsH[ct * 16 + l16][quad * 8];
            bfL[ct] = *(const bf16x8*)&WsL[ct * 16 + l16][quad * 8];
        }
        #pragma unroll
        for (int rt = 0; rt < 2; ++rt)
            #pragma unroll
            for (int ct = 0; ct < 4; ++ct) {
                accv[rt][ct] = __builtin_amdgcn_mfma_f32_16x16x32_bf16(
                    afL[rt], bfH[ct], accv[rt][ct], 0, 0, 0);
                accv[rt][ct] = __builtin_amdgcn_mfma_f32_16x16x32_bf16(
                    afH[rt], bfL[ct], accv[rt][ct], 0, 0, 0);
                accv[rt][ct] = __builtin_amdgcn_mfma_f32_16x16x32_bf16(
                    afH[rt], bfH[ct], accv[rt][ct], 0, 0, 0);
            }
        __syncthreads();
    }
    // epilogue: D[row][col], col = l16, row = quad*4 + r
    #pragma unroll
    for (int rt = 0; rt < 2; ++rt) {
        #pragma unroll
        for (int ct = 0; ct < 4; ++ct) {
            int colv = col0 + ct * 16 + l16;
            float bv = bias ? bias[colv] : 0.f;
            #pragma unroll
            for (int r = 0; r < 4; ++r) {
                int rowv = row0 + wv * 32 + rt * 16 + quad * 4 + r;
                float v = accv[rt][ct][r] + bv;
                size_t idx = (size_t)rowv * N + colv;
                if (dsil) { float pz = dsil[idx]; float s = 1.f / (1.f + expf(-pz)); v *= s * (1.f + pz * (1.f - s)); }
                if (addbuf) v += addbuf[idx];
                if (acc) C[idx] += v; else C[idx] = v;
            }
        }
    }
}

// ---------------- small helpers ----------------
__global__ void embed_kernel(const int* at_no, const float* emb, float* x) {
    int i = blockIdx.x * blockDim.x + threadIdx.x;   // NA*FD threads
    int n = i >> 7, f = i & 127;
    x[i] = emb[(size_t)at_no[n] * FD + f];
}

// builds UVcomb [128][256] = [u | v] and Tcomb [256][128] = [u^T ; v^T]
__global__ void combo_prep_kernel(const float* u, const float* v, float* UVcomb, float* Tcomb) {
    int i = blockIdx.x * blockDim.x + threadIdx.x;   // 32768 threads
    {
        int k = i >> 8, j = i & 255;
        UVcomb[i] = (j < 128) ? u[k * 128 + j] : v[k * 128 + (j - 128)];
    }
    {
        int k = i >> 7, j = i & 127;
        Tcomb[i] = (k < 128) ? u[j * 128 + k] : v[j * 128 + (k - 128)];
    }
}

// packs Wr (NBASE x FD3 f32) into f16 pairs along k: out[k2*384 + s*128 + f]
__global__ void wpack_kernel(const float* __restrict__ Wr, unsigned int* __restrict__ out) {
    int i = blockIdx.x * blockDim.x + threadIdx.x;   // 3840 threads
    if (i >= 3840) return;
    int k2 = i / 384, r = i - k2 * 384;
    out[i] = packf16(Wr[(2 * k2) * FD3 + r], Wr[(2 * k2 + 1) * FD3 + r]);
}

// ---------------- edge geometry forward (+ CSR histogram + f16 rbf packing) ---------
__global__ void geom_fwd_kernel(const float* coord, const int* ei,
    float* d_e, float* unit_e, float* rbf_e, float* drbf_e, float* fcut_e, float* dfc_e,
    unsigned int* rbfh_e, unsigned int* drbfh_e,
    int* cnt_dst, int* cnt_src)
{
    int e = blockIdx.x * blockDim.x + threadIdx.x;
    if (e >= NE) return;
    int s = ei[e], t = ei[NE + e];
    atomicAdd(&cnt_src[s], 1);
    atomicAdd(&cnt_dst[t], 1);
    float rx = coord[t * 3 + 0] - coord[s * 3 + 0];
    float ry = coord[t * 3 + 1] - coord[s * 3 + 1];
    float rz = coord[t * 3 + 2] - coord[s * 3 + 2];
    float r2 = rx * rx + ry * ry + rz * rz;
    float dd = sqrtf(r2 + 1e-12f);
    float inv = 1.f / dd;
    d_e[e] = dd;
    unit_e[e * 3 + 0] = rx * inv; unit_e[e * 3 + 1] = ry * inv; unit_e[e * 3 + 2] = rz * inv;
    const float c0 = 0.6324555320336759f;   // sqrt(2/5)
    float rb[NBASE], db[NBASE];
    for (int k = 0; k < NBASE; ++k) {
        float nk = (k + 1) * (PIF / RCUT);
        float sn, cs; sincosf(nk * dd, &sn, &cs);
        rb[k] = c0 * sn * inv;
        db[k] = c0 * (nk * cs * inv - sn * inv * inv);
        rbf_e[(size_t)e * NBASE + k] = rb[k];
        drbf_e[(size_t)e * NBASE + k] = db[k];
    }
    #pragma unroll
    for (int k2 = 0; k2 < 10; ++k2) {
        rbfh_e[(size_t)e * 10 + k2] = packf16(rb[2 * k2], rb[2 * k2 + 1]);
        drbfh_e[(size_t)e * 10 + k2] = packf16(db[2 * k2], db[2 * k2 + 1]);
    }
    if (dd < RCUT) {
        float sn, cs; sincosf(PIF * dd / RCUT, &sn, &cs);
        fcut_e[e] = 0.5f * (cs + 1.f);
        dfc_e[e] = -0.5f * (PIF / RCUT) * sn;
    } else { fcut_e[e] = 0.f; dfc_e[e] = 0.f; }
}

// ---------------- CSR build ----------------
__global__ __launch_bounds__(1024) void scan_kernel(
    const int* cnt_dst, const int* cnt_src,
    int* off_dst, int* off_src, int* cur_dst, int* cur_src)
{
    __shared__ int part[1024];
    const int* cnt = (blockIdx.x == 0) ? cnt_dst : cnt_src;
    int* off = (blockIdx.x == 0) ? off_dst : off_src;
    int* cur = (blockIdx.x == 0) ? cur_dst : cur_src;
    int t = threadIdx.x;
    int base = t * 8;
    int loc[8]; int s = 0;
    #pragma unroll
    for (int i = 0; i < 8; ++i) { loc[i] = s; s += cnt[base + i]; }
    part[t] = s;
    __syncthreads();
    for (int d = 1; d < 1024; d <<= 1) {
        int v = part[t];
        int w = (t >= d) ? part[t - d] : 0;
        __syncthreads();
        part[t] = v + w;
        __syncthreads();
    }
    int pre = (t == 0) ? 0 : part[t - 1];
    #pragma unroll
    for (int i = 0; i < 8; ++i) { int o = pre + loc[i]; off[base + i] = o; cur[base + i] = o; }
    if (t == 1023) off[NA] = part[1023];
}

__global__ void scatter_kernel(const int* ei, int* cur_dst, int* cur_src,
                               int* perm_dst, int* perm_src, int* srcp, int* dstp) {
    int e = blockIdx.x * blockDim.x + threadIdx.x;
    if (e >= NE) return;
    int s = ei[e], t = ei[NE + e];
    int pd = atomicAdd(&cur_dst[t], 1); perm_dst[pd] = e; srcp[pd] = s;
    int ps = atomicAdd(&cur_src[s], 1); perm_src[ps] = e; dstp[ps] = t;
}

// ---------------- message forward (per-dst-atom, 2 atoms/block, Wr in registers) -----
// [exact R10 version]
__global__ __launch_bounds__(256) void msg_fwd_kernel(
    const int* __restrict__ row_off_dst, const int* __restrict__ perm_dst, const int* __restrict__ srcp,
    const float* __restrict__ rbf_e, const float* __restrict__ fcut_e, const float* __restrict__ unit_e,
    const float* __restrict__ phi, const float* __restrict__ Wr, const float* __restrict__ br,
    const float* __restrict__ x_in, const float* __restrict__ v_in,   // v_in may be null (block 0)
    float* __restrict__ x_mid, float* __restrict__ v_mid)
{
    int tid = threadIdx.x;
    int n = blockIdx.x * 2 + (tid >> 7);
    int f = tid & 127;
    float w0[NBASE], w1[NBASE], w2[NBASE];
    #pragma unroll
    for (int k = 0; k < NBASE; ++k) {
        w0[k] = Wr[k * FD3 + f];
        w1[k] = Wr[k * FD3 + FD + f];
        w2[k] = Wr[k * FD3 + 2 * FD + f];
    }
    float b0 = br[f], b1 = br[FD + f], b2 = br[2 * FD + f];
    float xa = 0.f, va0 = 0.f, va1 = 0.f, va2 = 0.f;
    int e0 = row_off_dst[n], e1 = row_off_dst[n + 1];
    for (int ii = e0; ii < e1; ++ii) {
        int e = perm_dst[ii];
        int s = srcp[ii];
        float fc = fcut_e[e];
        const float* rp = rbf_e + (size_t)e * NBASE;
        float raw0 = b0, raw1 = b1, raw2 = b2;
        #pragma unroll
        for (int k = 0; k < NBASE; ++k) {
            float r = rp[k];
            raw0 = fmaf(r, w0[k], raw0);
            raw1 = fmaf(r, w1[k], raw1);
            raw2 = fmaf(r, w2[k], raw2);
        }
        float f0 = raw0 * fc, f1 = raw1 * fc, f2 = raw2 * fc;
        const float* ph = phi + (size_t)s * FD3;
        float m0 = ph[f] * f0, m1 = ph[FD + f] * f1, m2 = ph[2 * FD + f] * f2;
        xa += m0;
        float u0 = unit_e[e * 3], u1 = unit_e[e * 3 + 1], u2 = unit_e[e * 3 + 2];
        float vs0 = 0.f, vs1 = 0.f, vs2 = 0.f;
        if (v_in) {
            const float* vp = v_in + (size_t)s * 3 * FD;
            vs0 = vp[f]; vs1 = vp[FD + f]; vs2 = vp[2 * FD + f];
        }
        va0 += m1 * vs0 + m2 * u0;
        va1 += m1 * vs1 + m2 * u1;
        va2 += m1 * vs2 + m2 * u2;
    }
    size_t xb = (size_t)n * FD + f;
    x_mid[xb] = x_in[xb] + xa;
    size_t vb = (size_t)n * 3 * FD + f;
    float p0 = 0.f, p1 = 0.f, p2 = 0.f;
    if (v_in) { p0 = v_in[vb]; p1 = v_in[vb + FD]; p2 = v_in[vb + 2 * FD]; }
    v_mid[vb] = p0 + va0; v_mid[vb + FD] = p1 + va1; v_mid[vb + 2 * FD] = p2 + va2;
}

// ---------------- update-block pointwise kernels (uvvv interleaved layout) ------------
// uvvv rows: row = n*3+i, cols 0..127 = uv, 128..255 = vv.
__global__ void vnorm_cat_kernel(const float* xmid, const float* uvvv, float* vnorm, float* cat) {
    int i = blockIdx.x * blockDim.x + threadIdx.x;  // NA*FD
    int n = i >> 7, g = i & 127;
    size_t ub = (size_t)n * 3 * 256 + 128 + g;
    float a = uvvv[ub], b = uvvv[ub + 256], c = uvvv[ub + 512];
    float vn = sqrtf(a * a + b * b + c * c + 1e-12f);
    vnorm[i] = vn;
    cat[(size_t)n * 2 * FD + g] = xmid[i];
    cat[(size_t)n * 2 * FD + FD + g] = vn;
}

__global__ void combine_kernel(const float* xmid, const float* vmid,
    const float* uvvv, const float* a_,
    float* x_out, float* v_out /* nullable */)
{
    int i = blockIdx.x * blockDim.x + threadIdx.x;  // NA*FD
    int n = i >> 7, g = i & 127;
    size_t vb = (size_t)n * 3 * FD + g;
    size_t ub = (size_t)n * 3 * 256 + g;
    float uv0 = uvvv[ub], uv1 = uvvv[ub + 256], uv2 = uvvv[ub + 512];
    float vv0 = uvvv[ub + 128], vv1 = uvvv[ub + 384], vv2 = uvvv[ub + 640];
    float S = uv0 * vv0 + uv1 * vv1 + uv2 * vv2;
    const float* ar = a_ + (size_t)n * FD3;
    x_out[i] = xmid[i] + ar[FD + g] * S + ar[2 * FD + g];
    if (v_out) {
        float avv = ar[g];
        v_out[vb] = vmid[vb] + avv * uv0;
        v_out[vb + FD] = vmid[vb + FD] + avv * uv1;
        v_out[vb + 2 * FD] = vmid[vb + 2 * FD] + avv * uv2;
    }
}

// ---------------- output head ----------------
__global__ __launch_bounds__(256) void energy_kernel(
    const float* tout, const float* ow2, const float* ob2,
    const float* atom_sp, const int* at_no, float* out)
{
    int n = blockIdx.x * 256 + threadIdx.x;   // NA exact
    float e = ob2[0] + atom_sp[at_no[n]];
    for (int h = 0; h < HD; ++h) {
        float t = tout[(size_t)n * HD + h];
        e = fmaf(silu_f(t), ow2[h], e);
    }
    #pragma unroll
    for (int off = 32; off > 0; off >>= 1) e += __shfl_down(e, off);
    __shared__ float s[4];
    int lane = threadIdx.x & 63, wv = threadIdx.x >> 6;
    if (lane == 0) s[wv] = e;
    __syncthreads();
    if (threadIdx.x == 0) atomicAdd(out, s[0] + s[1] + s[2] + s[3]);
}

__global__ __launch_bounds__(128) void head_bwd_kernel(
    const float* tout, const float* ow1, const float* ow2, float* gx)
{
    __shared__ float sh[HD];
    int n = blockIdx.x, f = threadIdx.x;
    if (f < HD) {
        float p = tout[(size_t)n * HD + f];
        sh[f] = dsilu_f(p) * ow2[f];
    }
    __syncthreads();
    float g = 0.f;
    #pragma unroll
    for (int h = 0; h < HD; ++h) g = fmaf(sh[h], ow1[f * HD + h], g);
    gx[(size_t)n * FD + f] = g;
}

// ---------------- update-block backward pointwise ----------------
__global__ void ubwd1_kernel(const float* gx, const float* gv,
    const float* uvvv, float* g_a)
{
    int i = blockIdx.x * blockDim.x + threadIdx.x;  // NA*FD
    int n = i >> 7, g = i & 127;
    size_t vb = (size_t)n * 3 * FD + g;
    size_t ub = (size_t)n * 3 * 256 + g;
    float uv0 = uvvv[ub], uv1 = uvvv[ub + 256], uv2 = uvvv[ub + 512];
    float vv0 = uvvv[ub + 128], vv1 = uvvv[ub + 384], vv2 = uvvv[ub + 640];
    float gv0 = gv[vb], gv1 = gv[vb + FD], gv2 = gv[vb + 2 * FD];
    float gxv = gx[i];
    float S = uv0 * vv0 + uv1 * vv1 + uv2 * vv2;
    size_t ab = (size_t)n * FD3;
    g_a[ab + g]           = gv0 * uv0 + gv1 * uv1 + gv2 * uv2;   // g w.r.t. a_vv
    g_a[ab + FD + g]      = gxv * S;                              // g w.r.t. a_sv
    g_a[ab + 2 * FD + g]  = gxv;                                  // g w.r.t. a_ss
}

// NOTE: uvvv is read then overwritten in place (g_uv/g_vv); no __restrict__ on it.
__global__ void ubwd2_kernel(const float* gx_in, const float* gv_in,
    const float* a_, const float* vnorm, const float* g_cat,
    float* uvvv, float* gx_mid, float* gv_tmp)
{
    int i = blockIdx.x * blockDim.x + threadIdx.x;  // NA*FD
    int n = i >> 7, g = i & 127;
    size_t vb = (size_t)n * 3 * FD + g, ab = (size_t)n * FD3;
    size_t ub = (size_t)n * 3 * 256 + g;
    float gxv = gx_in[i];
    float gS = gxv * a_[ab + FD + g];
    float avv = a_[ab + g];
    float gvn = g_cat[(size_t)n * 2 * FD + FD + g];
    float c = gvn / vnorm[i];
    float uv0 = uvvv[ub], uv1 = uvvv[ub + 256], uv2 = uvvv[ub + 512];
    float vv0 = uvvv[ub + 128], vv1 = uvvv[ub + 384], vv2 = uvvv[ub + 640];
    float gv0 = gv_in[vb], gv1 = gv_in[vb + FD], gv2 = gv_in[vb + 2 * FD];
    uvvv[ub]       = gv0 * avv + gS * vv0;
    uvvv[ub + 256] = gv1 * avv + gS * vv1;
    uvvv[ub + 512] = gv2 * avv + gS * vv2;
    uvvv[ub + 128] = gS * uv0 + c * vv0;
    uvvv[ub + 384] = gS * uv1 + c * vv1;
    uvvv[ub + 640] = gS * uv2 + c * vv2;
    gv_tmp[vb] = gv0; gv_tmp[vb + FD] = gv1; gv_tmp[vb + 2 * FD] = gv2;
    gx_mid[i] = gxv + g_cat[(size_t)n * 2 * FD + g];
}

// ---------------- merged message backward: one BLOCK (4 waves) per src atom --------
// [R10 structure; loads use pre-packed f16 rbf/drbf + Wr]
__global__ __launch_bounds__(256) void msg_bwd_merged_kernel(
    const int* __restrict__ row_off_src, const int* __restrict__ perm_src, const int* __restrict__ dstp,
    const unsigned int* __restrict__ rbfh_e, const unsigned int* __restrict__ drbfh_e,
    const float* __restrict__ fcut_e, const float* __restrict__ dfc_e,
    const float* __restrict__ unit_e,
    const float* phi, const unsigned int* __restrict__ Wrp, const float* __restrict__ br,
    const float* __restrict__ v_in,              // nullable (block 0)
    const float* __restrict__ gx_mid, const float* __restrict__ gv_mid,
    float* gphi_out,                // aliases phi (own-atom read-then-write, barrier-protected)
    float* __restrict__ gv_out,
    float* __restrict__ gd_e, float* __restrict__ gu_e)
{
    __shared__ float red[12][4][64];
    int tid = threadIdx.x;
    int wv = tid >> 6, lane = tid & 63;
    int n = blockIdx.x;
    // weights for both feature halves, packed f16 pairs along k (pre-packed)
    f16x2 w[2][3][10];
    float brv[2][3], ph[2][3], vs[2][3];
    #pragma unroll
    for (int h = 0; h < 2; ++h) {
        int f = lane + h * 64;
        #pragma unroll
        for (int s = 0; s < 3; ++s) {
            #pragma unroll
            for (int k2 = 0; k2 < 10; ++k2) {
                unsigned int u = Wrp[k2 * 384 + s * 128 + f];
                w[h][s][k2] = *(const f16x2*)&u;
            }
            brv[h][s] = br[s * FD + f];
            ph[h][s] = phi[(size_t)n * FD3 + s * FD + f];
            vs[h][s] = v_in ? v_in[(size_t)n * 3 * FD + s * FD + f] : 0.f;
        }
    }
    float gp[2][3] = {{0.f, 0.f, 0.f}, {0.f, 0.f, 0.f}};
    float ga[2][3] = {{0.f, 0.f, 0.f}, {0.f, 0.f, 0.f}};
    int e0 = row_off_src[n], e1 = row_off_src[n + 1];
    for (int ii = e0 + wv; ii < e1; ii += 4) {
        int e = perm_src[ii], dd = dstp[ii];
        float fc = fcut_e[e], dfc = dfc_e[e];
        float u0 = unit_e[e * 3], u1 = unit_e[e * 3 + 1], u2 = unit_e[e * 3 + 2];
        f16x2 rb2[10], db2[10];
        #pragma unroll
        for (int k2 = 0; k2 < 10; ++k2) {
            unsigned int ra = rbfh_e[(size_t)e * 10 + k2];
            unsigned int db = drbfh_e[(size_t)e * 10 + k2];
            rb2[k2] = *(const f16x2*)&ra;
            db2[k2] = *(const f16x2*)&db;
        }
        float r0 = 0.f, r1 = 0.f, r2 = 0.f, r3 = 0.f;
        #pragma unroll
        for (int h = 0; h < 2; ++h) {
            int f = lane + h * 64;
            float raw0 = brv[h][0], raw1 = brv[h][1], raw2 = brv[h][2];
            float A0 = 0.f, A1 = 0.f, A2 = 0.f;
            #pragma unroll
            for (int k2 = 0; k2 < 10; ++k2) {
                raw0 = dot2f(rb2[k2], w[h][0][k2], raw0);
                raw1 = dot2f(rb2[k2], w[h][1][k2], raw1);
                raw2 = dot2f(rb2[k2], w[h][2][k2], raw2);
                A0 = dot2f(db2[k2], w[h][0][k2], A0);
                A1 = dot2f(db2[k2], w[h][1][k2], A1);
                A2 = dot2f(db2[k2], w[h][2][k2], A2);
            }
            float f0 = raw0 * fc, f1 = raw1 * fc, f2 = raw2 * fc;
            float gds = gx_mid[(size_t)dd * FD + f];
            const float* gvp = gv_mid + (size_t)dd * 3 * FD;
            float gd0 = gvp[f], gd1 = gvp[FD + f], gd2 = gvp[2 * FD + f];
            float gdv1 = gd0 * vs[h][0] + gd1 * vs[h][1] + gd2 * vs[h][2];
            float gdv2 = gd0 * u0 + gd1 * u1 + gd2 * u2;
            float dv1 = ph[h][1] * f1;
            ga[h][0] += gd0 * dv1; ga[h][1] += gd1 * dv1; ga[h][2] += gd2 * dv1;
            gp[h][0] += gds * f0; gp[h][1] += gdv1 * f1; gp[h][2] += gdv2 * f2;
            float dv2 = ph[h][2] * f2;
            r1 += gd0 * dv2; r2 += gd1 * dv2; r3 += gd2 * dv2;
            float gf0 = gds * ph[h][0], gf1 = gdv1 * ph[h][1], gf2 = gdv2 * ph[h][2];
            r0 += fc * (gf0 * A0 + gf1 * A1 + gf2 * A2)
                + dfc * (gf0 * raw0 + gf1 * raw1 + gf2 * raw2);
        }
        #pragma unroll
        for (int off = 32; off > 0; off >>= 1) {
            r0 += __shfl_down(r0, off);
            r1 += __shfl_down(r1, off);
            r2 += __shfl_down(r2, off);
            r3 += __shfl_down(r3, off);
        }
        if (lane == 0) {
            gd_e[e] += r0;
            gu_e[e * 3]     += r1;
            gu_e[e * 3 + 1] += r2;
            gu_e[e * 3 + 2] += r3;
        }
    }
    // block reduce of gp/ga across the 4 waves
    #pragma unroll
    for (int h = 0; h < 2; ++h)
        #pragma unroll
        for (int s = 0; s < 3; ++s) {
            red[h * 3 + s][wv][lane] = gp[h][s];
            red[6 + h * 3 + s][wv][lane] = ga[h][s];
        }
    __syncthreads();
    int j0 = tid >> 6;   // 0..3
    #pragma unroll
    for (int rep = 0; rep < 3; ++rep) {
        int j = j0 + rep * 4;
        float v = red[j][0][lane] + red[j][1][lane] + red[j][2][lane] + red[j][3][lane];
        int jj = (j < 6) ? j : j - 6;
        int h = jj / 3, s = jj - 3 * h;
        int f = h * 64 + lane;
        if (j < 6) {
            gphi_out[(size_t)n * FD3 + s * FD + f] = v;
        } else {
            size_t vb = (size_t)n * 3 * FD + s * FD + f;
            gv_out[vb] = gv_mid[vb] + v;
        }
    }
}

// ---------------- geometry backward: per-edge grad vector (no atomics) ----------------
// NOTE: gvec aliases gu_e (same-thread read-then-write) — no __restrict__.
__global__ void edge_vec_kernel(const float* coord, const int* ei,
    const float* d_e, const float* gd_e, const float* gu_e, float* gvec)
{
    int e = blockIdx.x * blockDim.x + threadIdx.x;
    if (e >= NE) return;
    int s = ei[e], t = ei[NE + e];
    float rx = coord[t * 3 + 0] - coord[s * 3 + 0];
    float ry = coord[t * 3 + 1] - coord[s * 3 + 1];
    float rz = coord[t * 3 + 2] - coord[s * 3 + 2];
    float dd = d_e[e];
    float inv = 1.f / dd;
    float gu0 = gu_e[e * 3], gu1 = gu_e[e * 3 + 1], gu2 = gu_e[e * 3 + 2];
    float gd = gd_e[e];
    float dot = gu0 * rx + gu1 * ry + gu2 * rz;
    float coef = gd * inv - dot * inv * inv * inv;
    gvec[e * 3 + 0] = gu0 * inv + coef * rx;
    gvec[e * 3 + 1] = gu1 * inv + coef * ry;
    gvec[e * 3 + 2] = gu2 * inv + coef * rz;
}

// one wave per atom: gcoord[n] = sum_{dst edges} gvec - sum_{src edges} gvec
__global__ __launch_bounds__(256) void coord_gather_kernel(
    const int* __restrict__ off_dst, const int* __restrict__ perm_dst,
    const int* __restrict__ off_src, const int* __restrict__ perm_src,
    const float* __restrict__ gvec, float* __restrict__ gcoord)
{
    int n = blockIdx.x * 4 + (threadIdx.x >> 6);
    int lane = threadIdx.x & 63;
    float a0 = 0.f, a1 = 0.f, a2 = 0.f;
    int d0 = off_dst[n], d1 = off_dst[n + 1];
    for (int ii = d0 + lane; ii < d1; ii += 64) {
        int e = perm_dst[ii];
        a0 += gvec[e * 3]; a1 += gvec[e * 3 + 1]; a2 += gvec[e * 3 + 2];
    }
    int s0 = off_src[n], s1 = off_src[n + 1];
    for (int ii = s0 + lane; ii < s1; ii += 64) {
        int e = perm_src[ii];
        a0 -= gvec[e * 3]; a1 -= gvec[e * 3 + 1]; a2 -= gvec[e * 3 + 2];
    }
    #pragma unroll
    for (int off = 32; off > 0; off >>= 1) {
        a0 += __shfl_down(a0, off);
        a1 += __shfl_down(a1, off);
        a2 += __shfl_down(a2, off);
    }
    if (lane == 0) {
        gcoord[n * 3 + 0] = a0; gcoord[n * 3 + 1] = a1; gcoord[n * 3 + 2] = a2;
    }
}

// ======================================================================
extern "C" void kernel_launch(void* const* d_in, const int* in_sizes, int n_in,
                              void* d_out, int out_size, void* d_ws, size_t ws_size,
                              hipStream_t stream)
{
    (void)in_sizes; (void)n_in; (void)out_size; (void)ws_size;
    const int*   at_no   = (const int*)  d_in[0];
    const float* coord   = (const float*)d_in[1];
    const int*   eidx    = (const int*)  d_in[2];
    const float* emb     = (const float*)d_in[5];
    const float* atom_sp = (const float*)d_in[6];
    const float* msg_w1  = (const float*)d_in[7];
    const float* msg_b1  = (const float*)d_in[8];
    const float* msg_w2  = (const float*)d_in[9];
    const float* msg_b2  = (const float*)d_in[10];
    const float* msg_wr  = (const float*)d_in[11];
    const float* msg_br  = (const float*)d_in[12];
    const float* upd_u   = (const float*)d_in[13];
    const float* upd_v   = (const float*)d_in[14];
    const float* upd_w1  = (const float*)d_in[15];
    const float* upd_b1  = (const float*)d_in[16];
    const float* upd_w2  = (const float*)d_in[17];
    const float* upd_b2  = (const float*)d_in[18];
    const float* out_w1  = (const float*)d_in[19];
    const float* out_b1  = (const float*)d_in[20];
    const float* out_w2  = (const float*)d_in[21];
    const float* out_b2  = (const float*)d_in[22];
    float* out = (float*)d_out;
    float* gcoord = out + 1;

    char* wp = (char*)d_ws;
    auto alloc = [&](size_t nelem) -> float* {
        float* r = (float*)wp; wp += ((nelem * 4 + 255) & ~(size_t)255); return r;
    };
    auto alloci = [&](size_t nelem) -> int* {
        int* r = (int*)wp; wp += ((nelem * 4 + 255) & ~(size_t)255); return r;
    };
    auto allocu = [&](size_t nelem) -> unsigned int* {
        unsigned int* r = (unsigned int*)wp; wp += ((nelem * 4 + 255) & ~(size_t)255); return r;
    };
    const size_t NF = (size_t)NA * FD;

    float* d_e    = alloc(NE);
    float* unit_e = alloc(3 * (size_t)NE);
    float* rbf_e  = alloc((size_t)NBASE * NE);
    float* drbf_e = alloc((size_t)NBASE * NE);
    float* fcut_e = alloc(NE);
    float* dfc_e  = alloc(NE);
    float* gd_e   = alloc(NE);
    float* gu_e   = alloc(3 * (size_t)NE);
    unsigned int* rbfh_e  = allocu((size_t)10 * NE);
    unsigned int* drbfh_e = allocu((size_t)10 * NE);
    int* cnt_dst = alloci(NA); int* cnt_src = alloci(NA);
    int* off_dst = alloci(NA + 1); int* off_src = alloci(NA + 1);
    int* cur_dst = alloci(NA); int* cur_src = alloci(NA);
    int* perm_dst = alloci(NE); int* perm_src = alloci(NE);
    int* srcp = alloci(NE); int* dstp = alloci(NE);
    float* xin_all = alloc(3 * NF);
    float* xin0 = xin_all; float* xin1 = xin_all + NF; float* xfin = xin_all + 2 * NF;
    float* vout0 = alloc(3 * NF);
    float* xmid = alloc(NF);
    float* vmid = alloc(3 * NF);            // reused as gv_tmp in backward
    float* catb = alloc(2 * NF);
    float* toutb = alloc((size_t)NA * HD);
    float *s1b[2], *phib[2], *uvvv[2], *vnb[2], *t1b[2], *ab[2];
    for (int b = 0; b < 2; ++b) {
        s1b[b] = alloc(NF); phib[b] = alloc(3 * NF); uvvv[b] = alloc(6 * NF);
        vnb[b] = alloc(NF); t1b[b] = alloc(NF); ab[b] = alloc(3 * NF);
    }
    float* gxA = alloc(NF); float* gxB = alloc(NF);
    float* gvA = alloc(3 * NF);
    // backward aliases of dead forward buffers:
    float* g_a   = xin_all;   // 3*NF
    float* g_cat = catb;      // 2*NF
    float* g_t1  = xmid;      // NF
    float* g_s1  = s1b[0];    // NF (only used in b==1 path)
    float* gvec_e = gu_e;     // in-place transform in edge_vec
    float *UVcomb[2], *Tcomb[2];
    for (int b = 0; b < 2; ++b) { UVcomb[b] = alloc(FD * 256); Tcomb[b] = alloc(256 * FD); }
    unsigned int* Wrp[2];
    for (int b = 0; b < 2; ++b) Wrp[b] = allocu(3840);

    // zero-init (harness poisons d_out/d_ws with 0xAA before every call)
    hipMemsetAsync(d_out, 0, (size_t)(1 + NA * 3) * 4, stream);
    hipMemsetAsync(cnt_dst, 0, (size_t)NA * 4, stream);
    hipMemsetAsync(cnt_src, 0, (size_t)NA * 4, stream);
    hipMemsetAsync(gd_e, 0, (size_t)NE * 4, stream);
    hipMemsetAsync(gu_e, 0, 3ull * NE * 4, stream);
    hipMemsetAsync(gvA, 0, 3 * NF * 4, stream);

    geom_fwd_kernel<<<NE / 256, 256, 0, stream>>>(coord, eidx, d_e, unit_e, rbf_e, drbf_e,
                                                  fcut_e, dfc_e, rbfh_e, drbfh_e, cnt_dst, cnt_src);
    scan_kernel<<<2, 1024, 0, stream>>>(cnt_dst, cnt_src, off_dst, off_src, cur_dst, cur_src);
    scatter_kernel<<<NE / 256, 256, 0, stream>>>(eidx, cur_dst, cur_src, perm_dst, perm_src, srcp, dstp);
    embed_kernel<<<NF / 256, 256, 0, stream>>>(at_no, emb, xin0);
    for (int b = 0; b < 2; ++b) {
        combo_prep_kernel<<<128, 256, 0, stream>>>(upd_u + (size_t)b * FD * FD,
                                                   upd_v + (size_t)b * FD * FD, UVcomb[b], Tcomb[b]);
        wpack_kernel<<<15, 256, 0, stream>>>(msg_wr + (size_t)b * NBASE * FD3, Wrp[b]);
    }

    auto gemm = [&](const float* A, const float* W, const float* bias, const float* dsil,
                    const float* addb, float* C, int M, int Nn, int K, int asilu, int acc, int wtrans) {
        dim3 g(Nn / 64, M / 128);
        mfma_gemm_kernel<<<g, 256, 0, stream>>>(A, W, bias, dsil, addb, C, M, Nn, K, asilu, acc, wtrans);
    };

    // ---------------- forward ----------------
    for (int b = 0; b < 2; ++b) {
        const float* xinb = b ? xin1 : xin0;
        const float* vin  = b ? vout0 : nullptr;
        gemm(xinb, msg_w1 + (size_t)b * FD * FD, msg_b1 + b * FD, nullptr, nullptr, s1b[b], NA, FD, FD, 0, 0, 0);
        gemm(s1b[b], msg_w2 + (size_t)b * FD * FD3, msg_b2 + b * FD3, nullptr, nullptr, phib[b], NA, FD3, FD, 1, 0, 0);
        msg_fwd_kernel<<<NA / 2, 256, 0, stream>>>(off_dst, perm_dst, srcp, rbf_e, fcut_e, unit_e,
                                              phib[b], msg_wr + (size_t)b * NBASE * FD3, msg_br + b * FD3,
                                              xinb, vin, xmid, vmid);
        gemm(vmid, UVcomb[b], nullptr, nullptr, nullptr, uvvv[b], 3 * NA, 256, FD, 0, 0, 0);
        vnorm_cat_kernel<<<NF / 256, 256, 0, stream>>>(xmid, uvvv[b], vnb[b], catb);
        gemm(catb, upd_w1 + (size_t)b * 2 * FD * FD, upd_b1 + b * FD, nullptr, nullptr, t1b[b], NA, FD, 2 * FD, 0, 0, 0);
        gemm(t1b[b], upd_w2 + (size_t)b * FD * FD3, upd_b2 + b * FD3, nullptr, nullptr, ab[b], NA, FD3, FD, 1, 0, 0);
        combine_kernel<<<NF / 256, 256, 0, stream>>>(xmid, vmid, uvvv[b], ab[b],
                                                     b ? xfin : xin1, b ? nullptr : vout0);
    }
    gemm(xfin, out_w1, out_b1, nullptr, nullptr, toutb, NA, HD, FD, 0, 0, 0);
    energy_kernel<<<NA / 256, 256, 0, stream>>>(toutb, out_w2, out_b2, atom_sp, at_no, out);

    // ---------------- backward ----------------
    head_bwd_kernel<<<NA, FD, 0, stream>>>(toutb, out_w1, out_w2, gxA);
    for (int b = 1; b >= 0; --b) {
        ubwd1_kernel<<<NF / 256, 256, 0, stream>>>(gxA, gvA, uvvv[b], g_a);
        gemm(g_a, upd_w2 + (size_t)b * FD * FD3, nullptr, t1b[b], nullptr, g_t1, NA, FD, FD3, 0, 0, 1);
        gemm(g_t1, upd_w1 + (size_t)b * 2 * FD * FD, nullptr, nullptr, nullptr, g_cat, NA, 2 * FD, FD, 0, 0, 1);
        ubwd2_kernel<<<NF / 256, 256, 0, stream>>>(gxA, gvA, ab[b], vnb[b], g_cat,
                                                   uvvv[b], gxB, vmid);
        gemm(uvvv[b], Tcomb[b], nullptr, nullptr, nullptr, vmid, 3 * NA, FD, 256, 0, 1, 0);
        msg_bwd_merged_kernel<<<NA, 256, 0, stream>>>(off_src, perm_src, dstp,
                                              rbfh_e, drbfh_e, fcut_e, dfc_e, unit_e,
                                              phib[b], Wrp[b], msg_br + (size_t)b * FD3,
                                              b ? vout0 : nullptr, gxB, vmid,
                                              phib[b], gvA, gd_e, gu_e);
        if (b == 1) {
            gemm(phib[b], msg_w2 + (size_t)b * FD * FD3, nullptr, s1b[b], nullptr, g_s1, NA, FD, FD3, 0, 0, 1);
            gemm(g_s1, msg_w1 + (size_t)b * FD * FD, nullptr, nullptr, gxB, gxA, NA, FD, FD, 0, 0, 1);
        }
    }
    edge_vec_kernel<<<NE / 256, 256, 0, stream>>>(coord, eidx, d_e, gd_e, gu_e, gvec_e);
    coord_gather_kernel<<<NA / 4, 256, 0, stream>>>(off_dst, perm_dst, off_src, perm_src, gvec_e, gcoord);
}

// Round 14
// 1164.844 us; speedup vs baseline: 1.0994x; 1.0368x over previous
//
#include <hip/hip_runtime.h>
#include <math.h>

// PaiNN energy + analytic coord-gradient.
// R14: R13 confirmed (msg_bwd 195->175 via f16-packed loads on the serial
//      chain). Same medicine for msg_fwd: pre-packed rbfh_e + Wrp + dot2
//      (20 f32 loads+60 FMA/edge -> 10 dword loads+30 dot2; preamble 120->30
//      dword loads). No other changes from R13.

#define NA 8192
#define NE 131072
#define FD 128
#define FD3 384
#define NBASE 20
#define HD 64
#define RCUT 5.0f
#define PIF 3.14159265358979f

typedef short bf16x8 __attribute__((ext_vector_type(8)));
typedef float f32x4 __attribute__((ext_vector_type(4)));
typedef _Float16 f16x2 __attribute__((ext_vector_type(2)));

static __device__ __forceinline__ float silu_f(float x) {
    return x / (1.f + expf(-x));
}
static __device__ __forceinline__ float dsilu_f(float x) {
    float s = 1.f / (1.f + expf(-x));
    return s * (1.f + x * (1.f - s));
}
static __device__ __forceinline__ short f2bf(float x) {
    union { float f; unsigned int i; } c; c.f = x;
    unsigned int r = c.i + 0x7fffu + ((c.i >> 16) & 1u);
    return (short)(r >> 16);
}
static __device__ __forceinline__ float bf2f(short u) {
    union { unsigned int i; float f; } c; c.i = ((unsigned int)(unsigned short)u) << 16; return c.f;
}
static __device__ __forceinline__ float dot2f(f16x2 a, f16x2 b, float c) {
#if __has_builtin(__builtin_amdgcn_fdot2)
    return __builtin_amdgcn_fdot2(a, b, c, false);
#else
    return c + (float)a.x * (float)b.x + (float)a.y * (float)b.y;
#endif
}
static __device__ __forceinline__ unsigned int packf16(float a, float b) {
    union { _Float16 h[2]; unsigned int u; } c;
    c.h[0] = (_Float16)a; c.h[1] = (_Float16)b;
    return c.u;
}

// ---------------- split-precision bf16 MFMA GEMM ----------------
// C = [silu?](A) @ W (+bias) (*dsilu(pre)) (+addbuf); A [M,K] f32 row-major.
// wtrans=0: W is [K,N] row-major. wtrans=1: W is [N,K] row-major (used as Worig^T).
// Tile 128x64, 4 waves, wave = 32 rows. hi/lo split for ~fp19 effective precision.
__global__ __launch_bounds__(256) void mfma_gemm_kernel(
    const float* __restrict__ A, const float* __restrict__ W,
    const float* __restrict__ bias, const float* __restrict__ dsil,
    const float* __restrict__ addbuf, float* __restrict__ C,
    int M, int N, int K, int asilu, int acc, int wtrans)
{
    __shared__ short AsH[128][40];   // [m][k] bf16 hi, K-tile 32 padded to 40
    __shared__ short AsL[128][40];   // bf16 lo
    __shared__ short WsH[64][40];    // [n][k] bf16 hi
    __shared__ short WsL[64][40];
    int tid = threadIdx.x;
    int row0 = blockIdx.y * 128, col0 = blockIdx.x * 64;
    int wv = tid >> 6, lane = tid & 63;
    int quad = lane >> 4, l16 = lane & 15;

    f32x4 accv[2][4];
    #pragma unroll
    for (int i = 0; i < 2; ++i)
        #pragma unroll
        for (int j = 0; j < 4; ++j) { f32x4 z = {0.f, 0.f, 0.f, 0.f}; accv[i][j] = z; }

    int am = tid >> 1;                 // 0..127
    int ak = (tid & 1) * 16;           // 0 or 16
    const float* abase = A + (size_t)(row0 + am) * K + ak;
    int wn = tid & 63, wk0 = tid >> 6;   // non-trans: k = wk0 + 4p
    int wk2 = tid & 31, wn2 = tid >> 5;  // trans: n = wn2 + 8p

    for (int k0 = 0; k0 < K; k0 += 32) {
        // stage A tile (128x32) with optional silu, f32 -> bf16 hi+lo
        {
            const float* ap = abase + k0;
            #pragma unroll
            for (int i = 0; i < 4; ++i) {
                float4 v = *(const float4*)(ap + 4 * i);
                if (asilu) {
                    v.x = silu_f(v.x); v.y = silu_f(v.y);
                    v.z = silu_f(v.z); v.w = silu_f(v.w);
                }
                float vv[4] = {v.x, v.y, v.z, v.w};
                #pragma unroll
                for (int q = 0; q < 4; ++q) {
                    short h = f2bf(vv[q]);
                    AsH[am][ak + 4 * i + q] = h;
                    AsL[am][ak + 4 * i + q] = f2bf(vv[q] - bf2f(h));
                }
            }
        }
        // stage W tile -> Ws[n][k], hi+lo
        if (!wtrans) {
            #pragma unroll
            for (int p = 0; p < 8; ++p) {
                int k = wk0 + p * 4;
                float v = W[(size_t)(k0 + k) * N + col0 + wn];
                short h = f2bf(v);
                WsH[wn][k] = h;
                WsL[wn][k] = f2bf(v - bf2f(h));
            }
        } else {
            #pragma unroll
            for (int p = 0; p < 8; ++p) {
                int n2 = wn2 + p * 8;
                float v = W[(size_t)(col0 + n2) * K + k0 + wk2];
                short h = f2bf(v);
                WsH[n2][wk2] = h;
                WsL[n2][wk2] = f2bf(v - bf2f(h));
            }
        }
        __syncthreads();
        bf16x8 afH[2], afL[2], bfH[4], bfL[4];
        #pragma unroll
        for (int rt = 0; rt < 2; ++rt) {
            afH[rt] = *(const bf16x8*)&AsH[wv * 32 + rt * 16 + l16][quad * 8];
            afL[rt] = *(const bf16x8*)&AsL[wv * 32 + rt * 16 + l16][quad * 8];
        }
        #pragma unroll
        for (int ct = 0; ct < 4; ++ct) {
            bfH[ct] = *(const bf16x8*)&WsH[ct * 16 + l16][quad * 8];
            bfL[ct] = *(const bf16x8*)&WsL[ct * 16 + l16][quad * 8];
        }
        #pragma unroll
        for (int rt = 0; rt < 2; ++rt)
            #pragma unroll
            for (int ct = 0; ct < 4; ++ct) {
                accv[rt][ct] = __builtin_amdgcn_mfma_f32_16x16x32_bf16(
                    afL[rt], bfH[ct], accv[rt][ct], 0, 0, 0);
                accv[rt][ct] = __builtin_amdgcn_mfma_f32_16x16x32_bf16(
                    afH[rt], bfL[ct], accv[rt][ct], 0, 0, 0);
                accv[rt][ct] = __builtin_amdgcn_mfma_f32_16x16x32_bf16(
                    afH[rt], bfH[ct], accv[rt][ct], 0, 0, 0);
            }
        __syncthreads();
    }
    // epilogue: D[row][col], col = l16, row = quad*4 + r
    #pragma unroll
    for (int rt = 0; rt < 2; ++rt) {
        #pragma unroll
        for (int ct = 0; ct < 4; ++ct) {
            int colv = col0 + ct * 16 + l16;
            float bv = bias ? bias[colv] : 0.f;
            #pragma unroll
            for (int r = 0; r < 4; ++r) {
                int rowv = row0 + wv * 32 + rt * 16 + quad * 4 + r;
                float v = accv[rt][ct][r] + bv;
                size_t idx = (size_t)rowv * N + colv;
                if (dsil) { float pz = dsil[idx]; float s = 1.f / (1.f + expf(-pz)); v *= s * (1.f + pz * (1.f - s)); }
                if (addbuf) v += addbuf[idx];
                if (acc) C[idx] += v; else C[idx] = v;
            }
        }
    }
}

// ---------------- small helpers ----------------
__global__ void embed_kernel(const int* at_no, const float* emb, float* x) {
    int i = blockIdx.x * blockDim.x + threadIdx.x;   // NA*FD threads
    int n = i >> 7, f = i & 127;
    x[i] = emb[(size_t)at_no[n] * FD + f];
}

// builds UVcomb [128][256] = [u | v] and Tcomb [256][128] = [u^T ; v^T]
__global__ void combo_prep_kernel(const float* u, const float* v, float* UVcomb, float* Tcomb) {
    int i = blockIdx.x * blockDim.x + threadIdx.x;   // 32768 threads
    {
        int k = i >> 8, j = i & 255;
        UVcomb[i] = (j < 128) ? u[k * 128 + j] : v[k * 128 + (j - 128)];
    }
    {
        int k = i >> 7, j = i & 127;
        Tcomb[i] = (k < 128) ? u[j * 128 + k] : v[j * 128 + (k - 128)];
    }
}

// packs Wr (NBASE x FD3 f32) into f16 pairs along k: out[k2*384 + s*128 + f]
__global__ void wpack_kernel(const float* __restrict__ Wr, unsigned int* __restrict__ out) {
    int i = blockIdx.x * blockDim.x + threadIdx.x;   // 3840 threads
    if (i >= 3840) return;
    int k2 = i / 384, r = i - k2 * 384;
    out[i] = packf16(Wr[(2 * k2) * FD3 + r], Wr[(2 * k2 + 1) * FD3 + r]);
}

// ---------------- edge geometry forward (+ CSR histogram + f16 rbf packing) ---------
__global__ void geom_fwd_kernel(const float* coord, const int* ei,
    float* d_e, float* unit_e, float* rbf_e, float* drbf_e, float* fcut_e, float* dfc_e,
    unsigned int* rbfh_e, unsigned int* drbfh_e,
    int* cnt_dst, int* cnt_src)
{
    int e = blockIdx.x * blockDim.x + threadIdx.x;
    if (e >= NE) return;
    int s = ei[e], t = ei[NE + e];
    atomicAdd(&cnt_src[s], 1);
    atomicAdd(&cnt_dst[t], 1);
    float rx = coord[t * 3 + 0] - coord[s * 3 + 0];
    float ry = coord[t * 3 + 1] - coord[s * 3 + 1];
    float rz = coord[t * 3 + 2] - coord[s * 3 + 2];
    float r2 = rx * rx + ry * ry + rz * rz;
    float dd = sqrtf(r2 + 1e-12f);
    float inv = 1.f / dd;
    d_e[e] = dd;
    unit_e[e * 3 + 0] = rx * inv; unit_e[e * 3 + 1] = ry * inv; unit_e[e * 3 + 2] = rz * inv;
    const float c0 = 0.6324555320336759f;   // sqrt(2/5)
    float rb[NBASE], db[NBASE];
    for (int k = 0; k < NBASE; ++k) {
        float nk = (k + 1) * (PIF / RCUT);
        float sn, cs; sincosf(nk * dd, &sn, &cs);
        rb[k] = c0 * sn * inv;
        db[k] = c0 * (nk * cs * inv - sn * inv * inv);
        rbf_e[(size_t)e * NBASE + k] = rb[k];
        drbf_e[(size_t)e * NBASE + k] = db[k];
    }
    #pragma unroll
    for (int k2 = 0; k2 < 10; ++k2) {
        rbfh_e[(size_t)e * 10 + k2] = packf16(rb[2 * k2], rb[2 * k2 + 1]);
        drbfh_e[(size_t)e * 10 + k2] = packf16(db[2 * k2], db[2 * k2 + 1]);
    }
    if (dd < RCUT) {
        float sn, cs; sincosf(PIF * dd / RCUT, &sn, &cs);
        fcut_e[e] = 0.5f * (cs + 1.f);
        dfc_e[e] = -0.5f * (PIF / RCUT) * sn;
    } else { fcut_e[e] = 0.f; dfc_e[e] = 0.f; }
}

// ---------------- CSR build ----------------
__global__ __launch_bounds__(1024) void scan_kernel(
    const int* cnt_dst, const int* cnt_src,
    int* off_dst, int* off_src, int* cur_dst, int* cur_src)
{
    __shared__ int part[1024];
    const int* cnt = (blockIdx.x == 0) ? cnt_dst : cnt_src;
    int* off = (blockIdx.x == 0) ? off_dst : off_src;
    int* cur = (blockIdx.x == 0) ? cur_dst : cur_src;
    int t = threadIdx.x;
    int base = t * 8;
    int loc[8]; int s = 0;
    #pragma unroll
    for (int i = 0; i < 8; ++i) { loc[i] = s; s += cnt[base + i]; }
    part[t] = s;
    __syncthreads();
    for (int d = 1; d < 1024; d <<= 1) {
        int v = part[t];
        int w = (t >= d) ? part[t - d] : 0;
        __syncthreads();
        part[t] = v + w;
        __syncthreads();
    }
    int pre = (t == 0) ? 0 : part[t - 1];
    #pragma unroll
    for (int i = 0; i < 8; ++i) { int o = pre + loc[i]; off[base + i] = o; cur[base + i] = o; }
    if (t == 1023) off[NA] = part[1023];
}

__global__ void scatter_kernel(const int* ei, int* cur_dst, int* cur_src,
                               int* perm_dst, int* perm_src, int* srcp, int* dstp) {
    int e = blockIdx.x * blockDim.x + threadIdx.x;
    if (e >= NE) return;
    int s = ei[e], t = ei[NE + e];
    int pd = atomicAdd(&cur_dst[t], 1); perm_dst[pd] = e; srcp[pd] = s;
    int ps = atomicAdd(&cur_src[s], 1); perm_src[ps] = e; dstp[ps] = t;
}

// ---------------- message forward (per-dst-atom, 2 atoms/block, packed f16 filter) ---
__global__ __launch_bounds__(256) void msg_fwd_kernel(
    const int* __restrict__ row_off_dst, const int* __restrict__ perm_dst, const int* __restrict__ srcp,
    const unsigned int* __restrict__ rbfh_e, const float* __restrict__ fcut_e, const float* __restrict__ unit_e,
    const float* __restrict__ phi, const unsigned int* __restrict__ Wrp, const float* __restrict__ br,
    const float* __restrict__ x_in, const float* __restrict__ v_in,   // v_in may be null (block 0)
    float* __restrict__ x_mid, float* __restrict__ v_mid)
{
    int tid = threadIdx.x;
    int n = blockIdx.x * 2 + (tid >> 7);
    int f = tid & 127;
    f16x2 w0[10], w1[10], w2[10];
    #pragma unroll
    for (int k2 = 0; k2 < 10; ++k2) {
        unsigned int a = Wrp[k2 * 384 + f];
        unsigned int b = Wrp[k2 * 384 + 128 + f];
        unsigned int c = Wrp[k2 * 384 + 256 + f];
        w0[k2] = *(const f16x2*)&a;
        w1[k2] = *(const f16x2*)&b;
        w2[k2] = *(const f16x2*)&c;
    }
    float b0 = br[f], b1 = br[FD + f], b2 = br[2 * FD + f];
    float xa = 0.f, va0 = 0.f, va1 = 0.f, va2 = 0.f;
    int e0 = row_off_dst[n], e1 = row_off_dst[n + 1];
    for (int ii = e0; ii < e1; ++ii) {
        int e = perm_dst[ii];
        int s = srcp[ii];
        float fc = fcut_e[e];
        float raw0 = b0, raw1 = b1, raw2 = b2;
        #pragma unroll
        for (int k2 = 0; k2 < 10; ++k2) {
            unsigned int ra = rbfh_e[(size_t)e * 10 + k2];
            f16x2 r = *(const f16x2*)&ra;
            raw0 = dot2f(r, w0[k2], raw0);
            raw1 = dot2f(r, w1[k2], raw1);
            raw2 = dot2f(r, w2[k2], raw2);
        }
        float f0 = raw0 * fc, f1 = raw1 * fc, f2 = raw2 * fc;
        const float* ph = phi + (size_t)s * FD3;
        float m0 = ph[f] * f0, m1 = ph[FD + f] * f1, m2 = ph[2 * FD + f] * f2;
        xa += m0;
        float u0 = unit_e[e * 3], u1 = unit_e[e * 3 + 1], u2 = unit_e[e * 3 + 2];
        float vs0 = 0.f, vs1 = 0.f, vs2 = 0.f;
        if (v_in) {
            const float* vp = v_in + (size_t)s * 3 * FD;
            vs0 = vp[f]; vs1 = vp[FD + f]; vs2 = vp[2 * FD + f];
        }
        va0 += m1 * vs0 + m2 * u0;
        va1 += m1 * vs1 + m2 * u1;
        va2 += m1 * vs2 + m2 * u2;
    }
    size_t xb = (size_t)n * FD + f;
    x_mid[xb] = x_in[xb] + xa;
    size_t vb = (size_t)n * 3 * FD + f;
    float p0 = 0.f, p1 = 0.f, p2 = 0.f;
    if (v_in) { p0 = v_in[vb]; p1 = v_in[vb + FD]; p2 = v_in[vb + 2 * FD]; }
    v_mid[vb] = p0 + va0; v_mid[vb + FD] = p1 + va1; v_mid[vb + 2 * FD] = p2 + va2;
}

// ---------------- update-block pointwise kernels (uvvv interleaved layout) ------------
// uvvv rows: row = n*3+i, cols 0..127 = uv, 128..255 = vv.
__global__ void vnorm_cat_kernel(const float* xmid, const float* uvvv, float* vnorm, float* cat) {
    int i = blockIdx.x * blockDim.x + threadIdx.x;  // NA*FD
    int n = i >> 7, g = i & 127;
    size_t ub = (size_t)n * 3 * 256 + 128 + g;
    float a = uvvv[ub], b = uvvv[ub + 256], c = uvvv[ub + 512];
    float vn = sqrtf(a * a + b * b + c * c + 1e-12f);
    vnorm[i] = vn;
    cat[(size_t)n * 2 * FD + g] = xmid[i];
    cat[(size_t)n * 2 * FD + FD + g] = vn;
}

__global__ void combine_kernel(const float* xmid, const float* vmid,
    const float* uvvv, const float* a_,
    float* x_out, float* v_out /* nullable */)
{
    int i = blockIdx.x * blockDim.x + threadIdx.x;  // NA*FD
    int n = i >> 7, g = i & 127;
    size_t vb = (size_t)n * 3 * FD + g;
    size_t ub = (size_t)n * 3 * 256 + g;
    float uv0 = uvvv[ub], uv1 = uvvv[ub + 256], uv2 = uvvv[ub + 512];
    float vv0 = uvvv[ub + 128], vv1 = uvvv[ub + 384], vv2 = uvvv[ub + 640];
    float S = uv0 * vv0 + uv1 * vv1 + uv2 * vv2;
    const float* ar = a_ + (size_t)n * FD3;
    x_out[i] = xmid[i] + ar[FD + g] * S + ar[2 * FD + g];
    if (v_out) {
        float avv = ar[g];
        v_out[vb] = vmid[vb] + avv * uv0;
        v_out[vb + FD] = vmid[vb + FD] + avv * uv1;
        v_out[vb + 2 * FD] = vmid[vb + 2 * FD] + avv * uv2;
    }
}

// ---------------- output head ----------------
__global__ __launch_bounds__(256) void energy_kernel(
    const float* tout, const float* ow2, const float* ob2,
    const float* atom_sp, const int* at_no, float* out)
{
    int n = blockIdx.x * 256 + threadIdx.x;   // NA exact
    float e = ob2[0] + atom_sp[at_no[n]];
    for (int h = 0; h < HD; ++h) {
        float t = tout[(size_t)n * HD + h];
        e = fmaf(silu_f(t), ow2[h], e);
    }
    #pragma unroll
    for (int off = 32; off > 0; off >>= 1) e += __shfl_down(e, off);
    __shared__ float s[4];
    int lane = threadIdx.x & 63, wv = threadIdx.x >> 6;
    if (lane == 0) s[wv] = e;
    __syncthreads();
    if (threadIdx.x == 0) atomicAdd(out, s[0] + s[1] + s[2] + s[3]);
}

__global__ __launch_bounds__(128) void head_bwd_kernel(
    const float* tout, const float* ow1, const float* ow2, float* gx)
{
    __shared__ float sh[HD];
    int n = blockIdx.x, f = threadIdx.x;
    if (f < HD) {
        float p = tout[(size_t)n * HD + f];
        sh[f] = dsilu_f(p) * ow2[f];
    }
    __syncthreads();
    float g = 0.f;
    #pragma unroll
    for (int h = 0; h < HD; ++h) g = fmaf(sh[h], ow1[f * HD + h], g);
    gx[(size_t)n * FD + f] = g;
}

// ---------------- update-block backward pointwise ----------------
__global__ void ubwd1_kernel(const float* gx, const float* gv,
    const float* uvvv, float* g_a)
{
    int i = blockIdx.x * blockDim.x + threadIdx.x;  // NA*FD
    int n = i >> 7, g = i & 127;
    size_t vb = (size_t)n * 3 * FD + g;
    size_t ub = (size_t)n * 3 * 256 + g;
    float uv0 = uvvv[ub], uv1 = uvvv[ub + 256], uv2 = uvvv[ub + 512];
    float vv0 = uvvv[ub + 128], vv1 = uvvv[ub + 384], vv2 = uvvv[ub + 640];
    float gv0 = gv[vb], gv1 = gv[vb + FD], gv2 = gv[vb + 2 * FD];
    float gxv = gx[i];
    float S = uv0 * vv0 + uv1 * vv1 + uv2 * vv2;
    size_t ab = (size_t)n * FD3;
    g_a[ab + g]           = gv0 * uv0 + gv1 * uv1 + gv2 * uv2;   // g w.r.t. a_vv
    g_a[ab + FD + g]      = gxv * S;                              // g w.r.t. a_sv
    g_a[ab + 2 * FD + g]  = gxv;                                  // g w.r.t. a_ss
}

// NOTE: uvvv is read then overwritten in place (g_uv/g_vv); no __restrict__ on it.
__global__ void ubwd2_kernel(const float* gx_in, const float* gv_in,
    const float* a_, const float* vnorm, const float* g_cat,
    float* uvvv, float* gx_mid, float* gv_tmp)
{
    int i = blockIdx.x * blockDim.x + threadIdx.x;  // NA*FD
    int n = i >> 7, g = i & 127;
    size_t vb = (size_t)n * 3 * FD + g, ab = (size_t)n * FD3;
    size_t ub = (size_t)n * 3 * 256 + g;
    float gxv = gx_in[i];
    float gS = gxv * a_[ab + FD + g];
    float avv = a_[ab + g];
    float gvn = g_cat[(size_t)n * 2 * FD + FD + g];
    float c = gvn / vnorm[i];
    float uv0 = uvvv[ub], uv1 = uvvv[ub + 256], uv2 = uvvv[ub + 512];
    float vv0 = uvvv[ub + 128], vv1 = uvvv[ub + 384], vv2 = uvvv[ub + 640];
    float gv0 = gv_in[vb], gv1 = gv_in[vb + FD], gv2 = gv_in[vb + 2 * FD];
    uvvv[ub]       = gv0 * avv + gS * vv0;
    uvvv[ub + 256] = gv1 * avv + gS * vv1;
    uvvv[ub + 512] = gv2 * avv + gS * vv2;
    uvvv[ub + 128] = gS * uv0 + c * vv0;
    uvvv[ub + 384] = gS * uv1 + c * vv1;
    uvvv[ub + 640] = gS * uv2 + c * vv2;
    gv_tmp[vb] = gv0; gv_tmp[vb + FD] = gv1; gv_tmp[vb + 2 * FD] = gv2;
    gx_mid[i] = gxv + g_cat[(size_t)n * 2 * FD + g];
}

// ---------------- merged message backward: one BLOCK (4 waves) per src atom --------
// [R13 version: R10 structure + pre-packed f16 rbf/drbf + Wr]
__global__ __launch_bounds__(256) void msg_bwd_merged_kernel(
    const int* __restrict__ row_off_src, const int* __restrict__ perm_src, const int* __restrict__ dstp,
    const unsigned int* __restrict__ rbfh_e, const unsigned int* __restrict__ drbfh_e,
    const float* __restrict__ fcut_e, const float* __restrict__ dfc_e,
    const float* __restrict__ unit_e,
    const float* phi, const unsigned int* __restrict__ Wrp, const float* __restrict__ br,
    const float* __restrict__ v_in,              // nullable (block 0)
    const float* __restrict__ gx_mid, const float* __restrict__ gv_mid,
    float* gphi_out,                // aliases phi (own-atom read-then-write, barrier-protected)
    float* __restrict__ gv_out,
    float* __restrict__ gd_e, float* __restrict__ gu_e)
{
    __shared__ float red[12][4][64];
    int tid = threadIdx.x;
    int wv = tid >> 6, lane = tid & 63;
    int n = blockIdx.x;
    // weights for both feature halves, packed f16 pairs along k (pre-packed)
    f16x2 w[2][3][10];
    float brv[2][3], ph[2][3], vs[2][3];
    #pragma unroll
    for (int h = 0; h < 2; ++h) {
        int f = lane + h * 64;
        #pragma unroll
        for (int s = 0; s < 3; ++s) {
            #pragma unroll
            for (int k2 = 0; k2 < 10; ++k2) {
                unsigned int u = Wrp[k2 * 384 + s * 128 + f];
                w[h][s][k2] = *(const f16x2*)&u;
            }
            brv[h][s] = br[s * FD + f];
            ph[h][s] = phi[(size_t)n * FD3 + s * FD + f];
            vs[h][s] = v_in ? v_in[(size_t)n * 3 * FD + s * FD + f] : 0.f;
        }
    }
    float gp[2][3] = {{0.f, 0.f, 0.f}, {0.f, 0.f, 0.f}};
    float ga[2][3] = {{0.f, 0.f, 0.f}, {0.f, 0.f, 0.f}};
    int e0 = row_off_src[n], e1 = row_off_src[n + 1];
    for (int ii = e0 + wv; ii < e1; ii += 4) {
        int e = perm_src[ii], dd = dstp[ii];
        float fc = fcut_e[e], dfc = dfc_e[e];
        float u0 = unit_e[e * 3], u1 = unit_e[e * 3 + 1], u2 = unit_e[e * 3 + 2];
        f16x2 rb2[10], db2[10];
        #pragma unroll
        for (int k2 = 0; k2 < 10; ++k2) {
            unsigned int ra = rbfh_e[(size_t)e * 10 + k2];
            unsigned int db = drbfh_e[(size_t)e * 10 + k2];
            rb2[k2] = *(const f16x2*)&ra;
            db2[k2] = *(const f16x2*)&db;
        }
        float r0 = 0.f, r1 = 0.f, r2 = 0.f, r3 = 0.f;
        #pragma unroll
        for (int h = 0; h < 2; ++h) {
            int f = lane + h * 64;
            float raw0 = brv[h][0], raw1 = brv[h][1], raw2 = brv[h][2];
            float A0 = 0.f, A1 = 0.f, A2 = 0.f;
            #pragma unroll
            for (int k2 = 0; k2 < 10; ++k2) {
                raw0 = dot2f(rb2[k2], w[h][0][k2], raw0);
                raw1 = dot2f(rb2[k2], w[h][1][k2], raw1);
                raw2 = dot2f(rb2[k2], w[h][2][k2], raw2);
                A0 = dot2f(db2[k2], w[h][0][k2], A0);
                A1 = dot2f(db2[k2], w[h][1][k2], A1);
                A2 = dot2f(db2[k2], w[h][2][k2], A2);
            }
            float f0 = raw0 * fc, f1 = raw1 * fc, f2 = raw2 * fc;
            float gds = gx_mid[(size_t)dd * FD + f];
            const float* gvp = gv_mid + (size_t)dd * 3 * FD;
            float gd0 = gvp[f], gd1 = gvp[FD + f], gd2 = gvp[2 * FD + f];
            float gdv1 = gd0 * vs[h][0] + gd1 * vs[h][1] + gd2 * vs[h][2];
            float gdv2 = gd0 * u0 + gd1 * u1 + gd2 * u2;
            float dv1 = ph[h][1] * f1;
            ga[h][0] += gd0 * dv1; ga[h][1] += gd1 * dv1; ga[h][2] += gd2 * dv1;
            gp[h][0] += gds * f0; gp[h][1] += gdv1 * f1; gp[h][2] += gdv2 * f2;
            float dv2 = ph[h][2] * f2;
            r1 += gd0 * dv2; r2 += gd1 * dv2; r3 += gd2 * dv2;
            float gf0 = gds * ph[h][0], gf1 = gdv1 * ph[h][1], gf2 = gdv2 * ph[h][2];
            r0 += fc * (gf0 * A0 + gf1 * A1 + gf2 * A2)
                + dfc * (gf0 * raw0 + gf1 * raw1 + gf2 * raw2);
        }
        #pragma unroll
        for (int off = 32; off > 0; off >>= 1) {
            r0 += __shfl_down(r0, off);
            r1 += __shfl_down(r1, off);
            r2 += __shfl_down(r2, off);
            r3 += __shfl_down(r3, off);
        }
        if (lane == 0) {
            gd_e[e] += r0;
            gu_e[e * 3]     += r1;
            gu_e[e * 3 + 1] += r2;
            gu_e[e * 3 + 2] += r3;
        }
    }
    // block reduce of gp/ga across the 4 waves
    #pragma unroll
    for (int h = 0; h < 2; ++h)
        #pragma unroll
        for (int s = 0; s < 3; ++s) {
            red[h * 3 + s][wv][lane] = gp[h][s];
            red[6 + h * 3 + s][wv][lane] = ga[h][s];
        }
    __syncthreads();
    int j0 = tid >> 6;   // 0..3
    #pragma unroll
    for (int rep = 0; rep < 3; ++rep) {
        int j = j0 + rep * 4;
        float v = red[j][0][lane] + red[j][1][lane] + red[j][2][lane] + red[j][3][lane];
        int jj = (j < 6) ? j : j - 6;
        int h = jj / 3, s = jj - 3 * h;
        int f = h * 64 + lane;
        if (j < 6) {
            gphi_out[(size_t)n * FD3 + s * FD + f] = v;
        } else {
            size_t vb = (size_t)n * 3 * FD + s * FD + f;
            gv_out[vb] = gv_mid[vb] + v;
        }
    }
}

// ---------------- geometry backward: per-edge grad vector (no atomics) ----------------
// NOTE: gvec aliases gu_e (same-thread read-then-write) — no __restrict__.
__global__ void edge_vec_kernel(const float* coord, const int* ei,
    const float* d_e, const float* gd_e, const float* gu_e, float* gvec)
{
    int e = blockIdx.x * blockDim.x + threadIdx.x;
    if (e >= NE) return;
    int s = ei[e], t = ei[NE + e];
    float rx = coord[t * 3 + 0] - coord[s * 3 + 0];
    float ry = coord[t * 3 + 1] - coord[s * 3 + 1];
    float rz = coord[t * 3 + 2] - coord[s * 3 + 2];
    float dd = d_e[e];
    float inv = 1.f / dd;
    float gu0 = gu_e[e * 3], gu1 = gu_e[e * 3 + 1], gu2 = gu_e[e * 3 + 2];
    float gd = gd_e[e];
    float dot = gu0 * rx + gu1 * ry + gu2 * rz;
    float coef = gd * inv - dot * inv * inv * inv;
    gvec[e * 3 + 0] = gu0 * inv + coef * rx;
    gvec[e * 3 + 1] = gu1 * inv + coef * ry;
    gvec[e * 3 + 2] = gu2 * inv + coef * rz;
}

// one wave per atom: gcoord[n] = sum_{dst edges} gvec - sum_{src edges} gvec
__global__ __launch_bounds__(256) void coord_gather_kernel(
    const int* __restrict__ off_dst, const int* __restrict__ perm_dst,
    const int* __restrict__ off_src, const int* __restrict__ perm_src,
    const float* __restrict__ gvec, float* __restrict__ gcoord)
{
    int n = blockIdx.x * 4 + (threadIdx.x >> 6);
    int lane = threadIdx.x & 63;
    float a0 = 0.f, a1 = 0.f, a2 = 0.f;
    int d0 = off_dst[n], d1 = off_dst[n + 1];
    for (int ii = d0 + lane; ii < d1; ii += 64) {
        int e = perm_dst[ii];
        a0 += gvec[e * 3]; a1 += gvec[e * 3 + 1]; a2 += gvec[e * 3 + 2];
    }
    int s0 = off_src[n], s1 = off_src[n + 1];
    for (int ii = s0 + lane; ii < s1; ii += 64) {
        int e = perm_src[ii];
        a0 -= gvec[e * 3]; a1 -= gvec[e * 3 + 1]; a2 -= gvec[e * 3 + 2];
    }
    #pragma unroll
    for (int off = 32; off > 0; off >>= 1) {
        a0 += __shfl_down(a0, off);
        a1 += __shfl_down(a1, off);
        a2 += __shfl_down(a2, off);
    }
    if (lane == 0) {
        gcoord[n * 3 + 0] = a0; gcoord[n * 3 + 1] = a1; gcoord[n * 3 + 2] = a2;
    }
}

// ======================================================================
extern "C" void kernel_launch(void* const* d_in, const int* in_sizes, int n_in,
                              void* d_out, int out_size, void* d_ws, size_t ws_size,
                              hipStream_t stream)
{
    (void)in_sizes; (void)n_in; (void)out_size; (void)ws_size;
    const int*   at_no   = (const int*)  d_in[0];
    const float* coord   = (const float*)d_in[1];
    const int*   eidx    = (const int*)  d_in[2];
    const float* emb     = (const float*)d_in[5];
    const float* atom_sp = (const float*)d_in[6];
    const float* msg_w1  = (const float*)d_in[7];
    const float* msg_b1  = (const float*)d_in[8];
    const float* msg_w2  = (const float*)d_in[9];
    const float* msg_b2  = (const float*)d_in[10];
    const float* msg_wr  = (const float*)d_in[11];
    const float* msg_br  = (const float*)d_in[12];
    const float* upd_u   = (const float*)d_in[13];
    const float* upd_v   = (const float*)d_in[14];
    const float* upd_w1  = (const float*)d_in[15];
    const float* upd_b1  = (const float*)d_in[16];
    const float* upd_w2  = (const float*)d_in[17];
    const float* upd_b2  = (const float*)d_in[18];
    const float* out_w1  = (const float*)d_in[19];
    const float* out_b1  = (const float*)d_in[20];
    const float* out_w2  = (const float*)d_in[21];
    const float* out_b2  = (const float*)d_in[22];
    float* out = (float*)d_out;
    float* gcoord = out + 1;

    char* wp = (char*)d_ws;
    auto alloc = [&](size_t nelem) -> float* {
        float* r = (float*)wp; wp += ((nelem * 4 + 255) & ~(size_t)255); return r;
    };
    auto alloci = [&](size_t nelem) -> int* {
        int* r = (int*)wp; wp += ((nelem * 4 + 255) & ~(size_t)255); return r;
    };
    auto allocu = [&](size_t nelem) -> unsigned int* {
        unsigned int* r = (unsigned int*)wp; wp += ((nelem * 4 + 255) & ~(size_t)255); return r;
    };
    const size_t NF = (size_t)NA * FD;

    float* d_e    = alloc(NE);
    float* unit_e = alloc(3 * (size_t)NE);
    float* rbf_e  = alloc((size_t)NBASE * NE);
    float* drbf_e = alloc((size_t)NBASE * NE);
    float* fcut_e = alloc(NE);
    float* dfc_e  = alloc(NE);
    float* gd_e   = alloc(NE);
    float* gu_e   = alloc(3 * (size_t)NE);
    unsigned int* rbfh_e  = allocu((size_t)10 * NE);
    unsigned int* drbfh_e = allocu((size_t)10 * NE);
    int* cnt_dst = alloci(NA); int* cnt_src = alloci(NA);
    int* off_dst = alloci(NA + 1); int* off_src = alloci(NA + 1);
    int* cur_dst = alloci(NA); int* cur_src = alloci(NA);
    int* perm_dst = alloci(NE); int* perm_src = alloci(NE);
    int* srcp = alloci(NE); int* dstp = alloci(NE);
    float* xin_all = alloc(3 * NF);
    float* xin0 = xin_all; float* xin1 = xin_all + NF; float* xfin = xin_all + 2 * NF;
    float* vout0 = alloc(3 * NF);
    float* xmid = alloc(NF);
    float* vmid = alloc(3 * NF);            // reused as gv_tmp in backward
    float* catb = alloc(2 * NF);
    float* toutb = alloc((size_t)NA * HD);
    float *s1b[2], *phib[2], *uvvv[2], *vnb[2], *t1b[2], *ab[2];
    for (int b = 0; b < 2; ++b) {
        s1b[b] = alloc(NF); phib[b] = alloc(3 * NF); uvvv[b] = alloc(6 * NF);
        vnb[b] = alloc(NF); t1b[b] = alloc(NF); ab[b] = alloc(3 * NF);
    }
    float* gxA = alloc(NF); float* gxB = alloc(NF);
    float* gvA = alloc(3 * NF);
    // backward aliases of dead forward buffers:
    float* g_a   = xin_all;   // 3*NF
    float* g_cat = catb;      // 2*NF
    float* g_t1  = xmid;      // NF
    float* g_s1  = s1b[0];    // NF (only used in b==1 path)
    float* gvec_e = gu_e;     // in-place transform in edge_vec
    float *UVcomb[2], *Tcomb[2];
    for (int b = 0; b < 2; ++b) { UVcomb[b] = alloc(FD * 256); Tcomb[b] = alloc(256 * FD); }
    unsigned int* Wrp[2];
    for (int b = 0; b < 2; ++b) Wrp[b] = allocu(3840);

    // zero-init (harness poisons d_out/d_ws with 0xAA before every call)
    hipMemsetAsync(d_out, 0, (size_t)(1 + NA * 3) * 4, stream);
    hipMemsetAsync(cnt_dst, 0, (size_t)NA * 4, stream);
    hipMemsetAsync(cnt_src, 0, (size_t)NA * 4, stream);
    hipMemsetAsync(gd_e, 0, (size_t)NE * 4, stream);
    hipMemsetAsync(gu_e, 0, 3ull * NE * 4, stream);
    hipMemsetAsync(gvA, 0, 3 * NF * 4, stream);

    geom_fwd_kernel<<<NE / 256, 256, 0, stream>>>(coord, eidx, d_e, unit_e, rbf_e, drbf_e,
                                                  fcut_e, dfc_e, rbfh_e, drbfh_e, cnt_dst, cnt_src);
    scan_kernel<<<2, 1024, 0, stream>>>(cnt_dst, cnt_src, off_dst, off_src, cur_dst, cur_src);
    scatter_kernel<<<NE / 256, 256, 0, stream>>>(eidx, cur_dst, cur_src, perm_dst, perm_src, srcp, dstp);
    embed_kernel<<<NF / 256, 256, 0, stream>>>(at_no, emb, xin0);
    for (int b = 0; b < 2; ++b) {
        combo_prep_kernel<<<128, 256, 0, stream>>>(upd_u + (size_t)b * FD * FD,
                                                   upd_v + (size_t)b * FD * FD, UVcomb[b], Tcomb[b]);
        wpack_kernel<<<15, 256, 0, stream>>>(msg_wr + (size_t)b * NBASE * FD3, Wrp[b]);
    }

    auto gemm = [&](const float* A, const float* W, const float* bias, const float* dsil,
                    const float* addb, float* C, int M, int Nn, int K, int asilu, int acc, int wtrans) {
        dim3 g(Nn / 64, M / 128);
        mfma_gemm_kernel<<<g, 256, 0, stream>>>(A, W, bias, dsil, addb, C, M, Nn, K, asilu, acc, wtrans);
    };

    // ---------------- forward ----------------
    for (int b = 0; b < 2; ++b) {
        const float* xinb = b ? xin1 : xin0;
        const float* vin  = b ? vout0 : nullptr;
        gemm(xinb, msg_w1 + (size_t)b * FD * FD, msg_b1 + b * FD, nullptr, nullptr, s1b[b], NA, FD, FD, 0, 0, 0);
        gemm(s1b[b], msg_w2 + (size_t)b * FD * FD3, msg_b2 + b * FD3, nullptr, nullptr, phib[b], NA, FD3, FD, 1, 0, 0);
        msg_fwd_kernel<<<NA / 2, 256, 0, stream>>>(off_dst, perm_dst, srcp, rbfh_e, fcut_e, unit_e,
                                              phib[b], Wrp[b], msg_br + (size_t)b * FD3,
                                              xinb, vin, xmid, vmid);
        gemm(vmid, UVcomb[b], nullptr, nullptr, nullptr, uvvv[b], 3 * NA, 256, FD, 0, 0, 0);
        vnorm_cat_kernel<<<NF / 256, 256, 0, stream>>>(xmid, uvvv[b], vnb[b], catb);
        gemm(catb, upd_w1 + (size_t)b * 2 * FD * FD, upd_b1 + b * FD, nullptr, nullptr, t1b[b], NA, FD, 2 * FD, 0, 0, 0);
        gemm(t1b[b], upd_w2 + (size_t)b * FD * FD3, upd_b2 + b * FD3, nullptr, nullptr, ab[b], NA, FD3, FD, 1, 0, 0);
        combine_kernel<<<NF / 256, 256, 0, stream>>>(xmid, vmid, uvvv[b], ab[b],
                                                     b ? xfin : xin1, b ? nullptr : vout0);
    }
    gemm(xfin, out_w1, out_b1, nullptr, nullptr, toutb, NA, HD, FD, 0, 0, 0);
    energy_kernel<<<NA / 256, 256, 0, stream>>>(toutb, out_w2, out_b2, atom_sp, at_no, out);

    // ---------------- backward ----------------
    head_bwd_kernel<<<NA, FD, 0, stream>>>(toutb, out_w1, out_w2, gxA);
    for (int b = 1; b >= 0; --b) {
        ubwd1_kernel<<<NF / 256, 256, 0, stream>>>(gxA, gvA, uvvv[b], g_a);
        gemm(g_a, upd_w2 + (size_t)b * FD * FD3, nullptr, t1b[b], nullptr, g_t1, NA, FD, FD3, 0, 0, 1);
        gemm(g_t1, upd_w1 + (size_t)b * 2 * FD * FD, nullptr, nullptr, nullptr, g_cat, NA, 2 * FD, FD, 0, 0, 1);
        ubwd2_kernel<<<NF / 256, 256, 0, stream>>>(gxA, gvA, ab[b], vnb[b], g_cat,
                                                   uvvv[b], gxB, vmid);
        gemm(uvvv[b], Tcomb[b], nullptr, nullptr, nullptr, vmid, 3 * NA, FD, 256, 0, 1, 0);
        msg_bwd_merged_kernel<<<NA, 256, 0, stream>>>(off_src, perm_src, dstp,
                                              rbfh_e, drbfh_e, fcut_e, dfc_e, unit_e,
                                              phib[b], Wrp[b], msg_br + (size_t)b * FD3,
                                              b ? vout0 : nullptr, gxB, vmid,
                                              phib[b], gvA, gd_e, gu_e);
        if (b == 1) {
            gemm(phib[b], msg_w2 + (size_t)b * FD * FD3, nullptr, s1b[b], nullptr, g_s1, NA, FD, FD3, 0, 0, 1);
            gemm(g_s1, msg_w1 + (size_t)b * FD * FD, nullptr, nullptr, gxB, gxA, NA, FD, FD, 0, 0, 1);
        }
    }
    edge_vec_kernel<<<NE / 256, 256, 0, stream>>>(coord, eidx, d_e, gd_e, gu_e, gvec_e);
    coord_gather_kernel<<<NA / 4, 256, 0, stream>>>(off_dst, perm_dst, off_src, perm_src, gvec_e, gcoord);
}

// Round 15
// 1009.828 us; speedup vs baseline: 1.2682x; 1.1535x over previous
//
#include <hip/hip_runtime.h>
#include <math.h>

// PaiNN energy + analytic coord-gradient.
// R15: (1) 64-row GEMM tile for M=8192/N<=128 GEMMs (grid 128->256 blocks,
//      was half-idle); (2) geometry packed as float4 (u0,u1,u2,fc) + dfc
//      (5 scalar loads -> 2 on the edge serial chain); geom_fwd stops writing
//      unused f32 rbf/drbf/unit/fcut buffers (-21MB writes).

#define NA 8192
#define NE 131072
#define FD 128
#define FD3 384
#define NBASE 20
#define HD 64
#define RCUT 5.0f
#define PIF 3.14159265358979f

typedef short bf16x8 __attribute__((ext_vector_type(8)));
typedef float f32x4 __attribute__((ext_vector_type(4)));
typedef _Float16 f16x2 __attribute__((ext_vector_type(2)));

static __device__ __forceinline__ float silu_f(float x) {
    return x / (1.f + expf(-x));
}
static __device__ __forceinline__ float dsilu_f(float x) {
    float s = 1.f / (1.f + expf(-x));
    return s * (1.f + x * (1.f - s));
}
static __device__ __forceinline__ short f2bf(float x) {
    union { float f; unsigned int i; } c; c.f = x;
    unsigned int r = c.i + 0x7fffu + ((c.i >> 16) & 1u);
    return (short)(r >> 16);
}
static __device__ __forceinline__ float bf2f(short u) {
    union { unsigned int i; float f; } c; c.i = ((unsigned int)(unsigned short)u) << 16; return c.f;
}
static __device__ __forceinline__ float dot2f(f16x2 a, f16x2 b, float c) {
#if __has_builtin(__builtin_amdgcn_fdot2)
    return __builtin_amdgcn_fdot2(a, b, c, false);
#else
    return c + (float)a.x * (float)b.x + (float)a.y * (float)b.y;
#endif
}
static __device__ __forceinline__ unsigned int packf16(float a, float b) {
    union { _Float16 h[2]; unsigned int u; } c;
    c.h[0] = (_Float16)a; c.h[1] = (_Float16)b;
    return c.u;
}

// ---------------- split-precision bf16 MFMA GEMM (128-row tile) ----------------
__global__ __launch_bounds__(256) void mfma_gemm_kernel(
    const float* __restrict__ A, const float* __restrict__ W,
    const float* __restrict__ bias, const float* __restrict__ dsil,
    const float* __restrict__ addbuf, float* __restrict__ C,
    int M, int N, int K, int asilu, int acc, int wtrans)
{
    __shared__ short AsH[128][40];
    __shared__ short AsL[128][40];
    __shared__ short WsH[64][40];
    __shared__ short WsL[64][40];
    int tid = threadIdx.x;
    int row0 = blockIdx.y * 128, col0 = blockIdx.x * 64;
    int wv = tid >> 6, lane = tid & 63;
    int quad = lane >> 4, l16 = lane & 15;

    f32x4 accv[2][4];
    #pragma unroll
    for (int i = 0; i < 2; ++i)
        #pragma unroll
        for (int j = 0; j < 4; ++j) { f32x4 z = {0.f, 0.f, 0.f, 0.f}; accv[i][j] = z; }

    int am = tid >> 1;
    int ak = (tid & 1) * 16;
    const float* abase = A + (size_t)(row0 + am) * K + ak;
    int wn = tid & 63, wk0 = tid >> 6;
    int wk2 = tid & 31, wn2 = tid >> 5;

    for (int k0 = 0; k0 < K; k0 += 32) {
        {
            const float* ap = abase + k0;
            #pragma unroll
            for (int i = 0; i < 4; ++i) {
                float4 v = *(const float4*)(ap + 4 * i);
                if (asilu) {
                    v.x = silu_f(v.x); v.y = silu_f(v.y);
                    v.z = silu_f(v.z); v.w = silu_f(v.w);
                }
                float vv[4] = {v.x, v.y, v.z, v.w};
                #pragma unroll
                for (int q = 0; q < 4; ++q) {
                    short h = f2bf(vv[q]);
                    AsH[am][ak + 4 * i + q] = h;
                    AsL[am][ak + 4 * i + q] = f2bf(vv[q] - bf2f(h));
                }
            }
        }
        if (!wtrans) {
            #pragma unroll
            for (int p = 0; p < 8; ++p) {
                int k = wk0 + p * 4;
                float v = W[(size_t)(k0 + k) * N + col0 + wn];
                short h = f2bf(v);
                WsH[wn][k] = h;
                WsL[wn][k] = f2bf(v - bf2f(h));
            }
        } else {
            #pragma unroll
            for (int p = 0; p < 8; ++p) {
                int n2 = wn2 + p * 8;
                float v = W[(size_t)(col0 + n2) * K + k0 + wk2];
                short h = f2bf(v);
                WsH[n2][wk2] = h;
                WsL[n2][wk2] = f2bf(v - bf2f(h));
            }
        }
        __syncthreads();
        bf16x8 afH[2], afL[2], bfH[4], bfL[4];
        #pragma unroll
        for (int rt = 0; rt < 2; ++rt) {
            afH[rt] = *(const bf16x8*)&AsH[wv * 32 + rt * 16 + l16][quad * 8];
            afL[rt] = *(const bf16x8*)&AsL[wv * 32 + rt * 16 + l16][quad * 8];
        }
        #pragma unroll
        for (int ct = 0; ct < 4; ++ct) {
            bfH[ct] = *(const bf16x8*)&WsH[ct * 16 + l16][quad * 8];
            bfL[ct] = *(const bf16x8*)&WsL[ct * 16 + l16][quad * 8];
        }
        #pragma unroll
        for (int rt = 0; rt < 2; ++rt)
            #pragma unroll
            for (int ct = 0; ct < 4; ++ct) {
                accv[rt][ct] = __builtin_amdgcn_mfma_f32_16x16x32_bf16(
                    afL[rt], bfH[ct], accv[rt][ct], 0, 0, 0);
                accv[rt][ct] = __builtin_amdgcn_mfma_f32_16x16x32_bf16(
                    afH[rt], bfL[ct], accv[rt][ct], 0, 0, 0);
                accv[rt][ct] = __builtin_amdgcn_mfma_f32_16x16x32_bf16(
                    afH[rt], bfH[ct], accv[rt][ct], 0, 0, 0);
            }
        __syncthreads();
    }
    #pragma unroll
    for (int rt = 0; rt < 2; ++rt) {
        #pragma unroll
        for (int ct = 0; ct < 4; ++ct) {
            int colv = col0 + ct * 16 + l16;
            float bv = bias ? bias[colv] : 0.f;
            #pragma unroll
            for (int r = 0; r < 4; ++r) {
                int rowv = row0 + wv * 32 + rt * 16 + quad * 4 + r;
                float v = accv[rt][ct][r] + bv;
                size_t idx = (size_t)rowv * N + colv;
                if (dsil) { float pz = dsil[idx]; float s = 1.f / (1.f + expf(-pz)); v *= s * (1.f + pz * (1.f - s)); }
                if (addbuf) v += addbuf[idx];
                if (acc) C[idx] += v; else C[idx] = v;
            }
        }
    }
}

// ---------------- 64-row tile variant (2x grid for M=8192/N<=128 GEMMs) -------------
__global__ __launch_bounds__(256) void mfma_gemm64_kernel(
    const float* __restrict__ A, const float* __restrict__ W,
    const float* __restrict__ bias, const float* __restrict__ dsil,
    const float* __restrict__ addbuf, float* __restrict__ C,
    int M, int N, int K, int asilu, int acc, int wtrans)
{
    __shared__ short AsH[64][40];
    __shared__ short AsL[64][40];
    __shared__ short WsH[64][40];
    __shared__ short WsL[64][40];
    int tid = threadIdx.x;
    int row0 = blockIdx.y * 64, col0 = blockIdx.x * 64;
    int wv = tid >> 6, lane = tid & 63;
    int quad = lane >> 4, l16 = lane & 15;

    f32x4 accv[4];
    #pragma unroll
    for (int j = 0; j < 4; ++j) { f32x4 z = {0.f, 0.f, 0.f, 0.f}; accv[j] = z; }

    int am = tid >> 2;            // 0..63
    int ak = (tid & 3) * 8;       // 0,8,16,24
    const float* abase = A + (size_t)(row0 + am) * K + ak;
    int wn = tid & 63, wk0 = tid >> 6;
    int wk2 = tid & 31, wn2 = tid >> 5;

    for (int k0 = 0; k0 < K; k0 += 32) {
        {
            const float* ap = abase + k0;
            #pragma unroll
            for (int i = 0; i < 2; ++i) {
                float4 v = *(const float4*)(ap + 4 * i);
                if (asilu) {
                    v.x = silu_f(v.x); v.y = silu_f(v.y);
                    v.z = silu_f(v.z); v.w = silu_f(v.w);
                }
                float vv[4] = {v.x, v.y, v.z, v.w};
                #pragma unroll
                for (int q = 0; q < 4; ++q) {
                    short h = f2bf(vv[q]);
                    AsH[am][ak + 4 * i + q] = h;
                    AsL[am][ak + 4 * i + q] = f2bf(vv[q] - bf2f(h));
                }
            }
        }
        if (!wtrans) {
            #pragma unroll
            for (int p = 0; p < 8; ++p) {
                int k = wk0 + p * 4;
                float v = W[(size_t)(k0 + k) * N + col0 + wn];
                short h = f2bf(v);
                WsH[wn][k] = h;
                WsL[wn][k] = f2bf(v - bf2f(h));
            }
        } else {
            #pragma unroll
            for (int p = 0; p < 8; ++p) {
                int n2 = wn2 + p * 8;
                float v = W[(size_t)(col0 + n2) * K + k0 + wk2];
                short h = f2bf(v);
                WsH[n2][wk2] = h;
                WsL[n2][wk2] = f2bf(v - bf2f(h));
            }
        }
        __syncthreads();
        bf16x8 afH, afL, bfH[4], bfL[4];
        afH = *(const bf16x8*)&AsH[wv * 16 + l16][quad * 8];
        afL = *(const bf16x8*)&AsL[wv * 16 + l16][quad * 8];
        #pragma unroll
        for (int ct = 0; ct < 4; ++ct) {
            bfH[ct] = *(const bf16x8*)&WsH[ct * 16 + l16][quad * 8];
            bfL[ct] = *(const bf16x8*)&WsL[ct * 16 + l16][quad * 8];
        }
        #pragma unroll
        for (int ct = 0; ct < 4; ++ct) {
            accv[ct] = __builtin_amdgcn_mfma_f32_16x16x32_bf16(afL, bfH[ct], accv[ct], 0, 0, 0);
            accv[ct] = __builtin_amdgcn_mfma_f32_16x16x32_bf16(afH, bfL[ct], accv[ct], 0, 0, 0);
            accv[ct] = __builtin_amdgcn_mfma_f32_16x16x32_bf16(afH, bfH[ct], accv[ct], 0, 0, 0);
        }
        __syncthreads();
    }
    #pragma unroll
    for (int ct = 0; ct < 4; ++ct) {
        int colv = col0 + ct * 16 + l16;
        if (colv >= N) continue;
        float bv = bias ? bias[colv] : 0.f;
        #pragma unroll
        for (int r = 0; r < 4; ++r) {
            int rowv = row0 + wv * 16 + quad * 4 + r;
            float v = accv[ct][r] + bv;
            size_t idx = (size_t)rowv * N + colv;
            if (dsil) { float pz = dsil[idx]; float s = 1.f / (1.f + expf(-pz)); v *= s * (1.f + pz * (1.f - s)); }
            if (addbuf) v += addbuf[idx];
            if (acc) C[idx] += v; else C[idx] = v;
        }
    }
}

// ---------------- small helpers ----------------
__global__ void embed_kernel(const int* at_no, const float* emb, float* x) {
    int i = blockIdx.x * blockDim.x + threadIdx.x;   // NA*FD threads
    int n = i >> 7, f = i & 127;
    x[i] = emb[(size_t)at_no[n] * FD + f];
}

// builds UVcomb [128][256] = [u | v] and Tcomb [256][128] = [u^T ; v^T]
__global__ void combo_prep_kernel(const float* u, const float* v, float* UVcomb, float* Tcomb) {
    int i = blockIdx.x * blockDim.x + threadIdx.x;   // 32768 threads
    {
        int k = i >> 8, j = i & 255;
        UVcomb[i] = (j < 128) ? u[k * 128 + j] : v[k * 128 + (j - 128)];
    }
    {
        int k = i >> 7, j = i & 127;
        Tcomb[i] = (k < 128) ? u[j * 128 + k] : v[j * 128 + (k - 128)];
    }
}

// packs Wr (NBASE x FD3 f32) into f16 pairs along k: out[k2*384 + s*128 + f]
__global__ void wpack_kernel(const float* __restrict__ Wr, unsigned int* __restrict__ out) {
    int i = blockIdx.x * blockDim.x + threadIdx.x;   // 3840 threads
    if (i >= 3840) return;
    int k2 = i / 384, r = i - k2 * 384;
    out[i] = packf16(Wr[(2 * k2) * FD3 + r], Wr[(2 * k2 + 1) * FD3 + r]);
}

// ---------------- edge geometry forward (+ CSR histogram + packing) ----------------
// geo4[e] = (u0, u1, u2, fcut); dfc separate; rbf/drbf only as packed f16.
__global__ void geom_fwd_kernel(const float* coord, const int* ei,
    float* d_e, float4* geo4, float* dfc_e,
    unsigned int* rbfh_e, unsigned int* drbfh_e,
    int* cnt_dst, int* cnt_src)
{
    int e = blockIdx.x * blockDim.x + threadIdx.x;
    if (e >= NE) return;
    int s = ei[e], t = ei[NE + e];
    atomicAdd(&cnt_src[s], 1);
    atomicAdd(&cnt_dst[t], 1);
    float rx = coord[t * 3 + 0] - coord[s * 3 + 0];
    float ry = coord[t * 3 + 1] - coord[s * 3 + 1];
    float rz = coord[t * 3 + 2] - coord[s * 3 + 2];
    float r2 = rx * rx + ry * ry + rz * rz;
    float dd = sqrtf(r2 + 1e-12f);
    float inv = 1.f / dd;
    d_e[e] = dd;
    const float c0 = 0.6324555320336759f;   // sqrt(2/5)
    float rb[NBASE], db[NBASE];
    for (int k = 0; k < NBASE; ++k) {
        float nk = (k + 1) * (PIF / RCUT);
        float sn, cs; sincosf(nk * dd, &sn, &cs);
        rb[k] = c0 * sn * inv;
        db[k] = c0 * (nk * cs * inv - sn * inv * inv);
    }
    #pragma unroll
    for (int k2 = 0; k2 < 10; ++k2) {
        rbfh_e[(size_t)e * 10 + k2] = packf16(rb[2 * k2], rb[2 * k2 + 1]);
        drbfh_e[(size_t)e * 10 + k2] = packf16(db[2 * k2], db[2 * k2 + 1]);
    }
    float fc = 0.f, dfc = 0.f;
    if (dd < RCUT) {
        float sn, cs; sincosf(PIF * dd / RCUT, &sn, &cs);
        fc = 0.5f * (cs + 1.f);
        dfc = -0.5f * (PIF / RCUT) * sn;
    }
    float4 g; g.x = rx * inv; g.y = ry * inv; g.z = rz * inv; g.w = fc;
    geo4[e] = g;
    dfc_e[e] = dfc;
}

// ---------------- CSR build ----------------
__global__ __launch_bounds__(1024) void scan_kernel(
    const int* cnt_dst, const int* cnt_src,
    int* off_dst, int* off_src, int* cur_dst, int* cur_src)
{
    __shared__ int part[1024];
    const int* cnt = (blockIdx.x == 0) ? cnt_dst : cnt_src;
    int* off = (blockIdx.x == 0) ? off_dst : off_src;
    int* cur = (blockIdx.x == 0) ? cur_dst : cur_src;
    int t = threadIdx.x;
    int base = t * 8;
    int loc[8]; int s = 0;
    #pragma unroll
    for (int i = 0; i < 8; ++i) { loc[i] = s; s += cnt[base + i]; }
    part[t] = s;
    __syncthreads();
    for (int d = 1; d < 1024; d <<= 1) {
        int v = part[t];
        int w = (t >= d) ? part[t - d] : 0;
        __syncthreads();
        part[t] = v + w;
        __syncthreads();
    }
    int pre = (t == 0) ? 0 : part[t - 1];
    #pragma unroll
    for (int i = 0; i < 8; ++i) { int o = pre + loc[i]; off[base + i] = o; cur[base + i] = o; }
    if (t == 1023) off[NA] = part[1023];
}

__global__ void scatter_kernel(const int* ei, int* cur_dst, int* cur_src,
                               int* perm_dst, int* perm_src, int* srcp, int* dstp) {
    int e = blockIdx.x * blockDim.x + threadIdx.x;
    if (e >= NE) return;
    int s = ei[e], t = ei[NE + e];
    int pd = atomicAdd(&cur_dst[t], 1); perm_dst[pd] = e; srcp[pd] = s;
    int ps = atomicAdd(&cur_src[s], 1); perm_src[ps] = e; dstp[ps] = t;
}

// ---------------- message forward (per-dst-atom, 2 atoms/block, packed loads) --------
__global__ __launch_bounds__(256) void msg_fwd_kernel(
    const int* __restrict__ row_off_dst, const int* __restrict__ perm_dst, const int* __restrict__ srcp,
    const unsigned int* __restrict__ rbfh_e, const float4* __restrict__ geo4,
    const float* __restrict__ phi, const unsigned int* __restrict__ Wrp, const float* __restrict__ br,
    const float* __restrict__ x_in, const float* __restrict__ v_in,   // v_in may be null (block 0)
    float* __restrict__ x_mid, float* __restrict__ v_mid)
{
    int tid = threadIdx.x;
    int n = blockIdx.x * 2 + (tid >> 7);
    int f = tid & 127;
    f16x2 w0[10], w1[10], w2[10];
    #pragma unroll
    for (int k2 = 0; k2 < 10; ++k2) {
        unsigned int a = Wrp[k2 * 384 + f];
        unsigned int b = Wrp[k2 * 384 + 128 + f];
        unsigned int c = Wrp[k2 * 384 + 256 + f];
        w0[k2] = *(const f16x2*)&a;
        w1[k2] = *(const f16x2*)&b;
        w2[k2] = *(const f16x2*)&c;
    }
    float b0 = br[f], b1 = br[FD + f], b2 = br[2 * FD + f];
    float xa = 0.f, va0 = 0.f, va1 = 0.f, va2 = 0.f;
    int e0 = row_off_dst[n], e1 = row_off_dst[n + 1];
    for (int ii = e0; ii < e1; ++ii) {
        int e = perm_dst[ii];
        int s = srcp[ii];
        float4 g = geo4[e];
        float fc = g.w;
        float raw0 = b0, raw1 = b1, raw2 = b2;
        #pragma unroll
        for (int k2 = 0; k2 < 10; ++k2) {
            unsigned int ra = rbfh_e[(size_t)e * 10 + k2];
            f16x2 r = *(const f16x2*)&ra;
            raw0 = dot2f(r, w0[k2], raw0);
            raw1 = dot2f(r, w1[k2], raw1);
            raw2 = dot2f(r, w2[k2], raw2);
        }
        float f0 = raw0 * fc, f1 = raw1 * fc, f2 = raw2 * fc;
        const float* ph = phi + (size_t)s * FD3;
        float m0 = ph[f] * f0, m1 = ph[FD + f] * f1, m2 = ph[2 * FD + f] * f2;
        xa += m0;
        float vs0 = 0.f, vs1 = 0.f, vs2 = 0.f;
        if (v_in) {
            const float* vp = v_in + (size_t)s * 3 * FD;
            vs0 = vp[f]; vs1 = vp[FD + f]; vs2 = vp[2 * FD + f];
        }
        va0 += m1 * vs0 + m2 * g.x;
        va1 += m1 * vs1 + m2 * g.y;
        va2 += m1 * vs2 + m2 * g.z;
    }
    size_t xb = (size_t)n * FD + f;
    x_mid[xb] = x_in[xb] + xa;
    size_t vb = (size_t)n * 3 * FD + f;
    float p0 = 0.f, p1 = 0.f, p2 = 0.f;
    if (v_in) { p0 = v_in[vb]; p1 = v_in[vb + FD]; p2 = v_in[vb + 2 * FD]; }
    v_mid[vb] = p0 + va0; v_mid[vb + FD] = p1 + va1; v_mid[vb + 2 * FD] = p2 + va2;
}

// ---------------- update-block pointwise kernels (uvvv interleaved layout) ------------
__global__ void vnorm_cat_kernel(const float* xmid, const float* uvvv, float* vnorm, float* cat) {
    int i = blockIdx.x * blockDim.x + threadIdx.x;  // NA*FD
    int n = i >> 7, g = i & 127;
    size_t ub = (size_t)n * 3 * 256 + 128 + g;
    float a = uvvv[ub], b = uvvv[ub + 256], c = uvvv[ub + 512];
    float vn = sqrtf(a * a + b * b + c * c + 1e-12f);
    vnorm[i] = vn;
    cat[(size_t)n * 2 * FD + g] = xmid[i];
    cat[(size_t)n * 2 * FD + FD + g] = vn;
}

__global__ void combine_kernel(const float* xmid, const float* vmid,
    const float* uvvv, const float* a_,
    float* x_out, float* v_out /* nullable */)
{
    int i = blockIdx.x * blockDim.x + threadIdx.x;  // NA*FD
    int n = i >> 7, g = i & 127;
    size_t vb = (size_t)n * 3 * FD + g;
    size_t ub = (size_t)n * 3 * 256 + g;
    float uv0 = uvvv[ub], uv1 = uvvv[ub + 256], uv2 = uvvv[ub + 512];
    float vv0 = uvvv[ub + 128], vv1 = uvvv[ub + 384], vv2 = uvvv[ub + 640];
    float S = uv0 * vv0 + uv1 * vv1 + uv2 * vv2;
    const float* ar = a_ + (size_t)n * FD3;
    x_out[i] = xmid[i] + ar[FD + g] * S + ar[2 * FD + g];
    if (v_out) {
        float avv = ar[g];
        v_out[vb] = vmid[vb] + avv * uv0;
        v_out[vb + FD] = vmid[vb + FD] + avv * uv1;
        v_out[vb + 2 * FD] = vmid[vb + 2 * FD] + avv * uv2;
    }
}

// ---------------- output head ----------------
__global__ __launch_bounds__(256) void energy_kernel(
    const float* tout, const float* ow2, const float* ob2,
    const float* atom_sp, const int* at_no, float* out)
{
    int n = blockIdx.x * 256 + threadIdx.x;   // NA exact
    float e = ob2[0] + atom_sp[at_no[n]];
    for (int h = 0; h < HD; ++h) {
        float t = tout[(size_t)n * HD + h];
        e = fmaf(silu_f(t), ow2[h], e);
    }
    #pragma unroll
    for (int off = 32; off > 0; off >>= 1) e += __shfl_down(e, off);
    __shared__ float s[4];
    int lane = threadIdx.x & 63, wv = threadIdx.x >> 6;
    if (lane == 0) s[wv] = e;
    __syncthreads();
    if (threadIdx.x == 0) atomicAdd(out, s[0] + s[1] + s[2] + s[3]);
}

__global__ __launch_bounds__(128) void head_bwd_kernel(
    const float* tout, const float* ow1, const float* ow2, float* gx)
{
    __shared__ float sh[HD];
    int n = blockIdx.x, f = threadIdx.x;
    if (f < HD) {
        float p = tout[(size_t)n * HD + f];
        sh[f] = dsilu_f(p) * ow2[f];
    }
    __syncthreads();
    float g = 0.f;
    #pragma unroll
    for (int h = 0; h < HD; ++h) g = fmaf(sh[h], ow1[f * HD + h], g);
    gx[(size_t)n * FD + f] = g;
}

// ---------------- update-block backward pointwise ----------------
__global__ void ubwd1_kernel(const float* gx, const float* gv,
    const float* uvvv, float* g_a)
{
    int i = blockIdx.x * blockDim.x + threadIdx.x;  // NA*FD
    int n = i >> 7, g = i & 127;
    size_t vb = (size_t)n * 3 * FD + g;
    size_t ub = (size_t)n * 3 * 256 + g;
    float uv0 = uvvv[ub], uv1 = uvvv[ub + 256], uv2 = uvvv[ub + 512];
    float vv0 = uvvv[ub + 128], vv1 = uvvv[ub + 384], vv2 = uvvv[ub + 640];
    float gv0 = gv[vb], gv1 = gv[vb + FD], gv2 = gv[vb + 2 * FD];
    float gxv = gx[i];
    float S = uv0 * vv0 + uv1 * vv1 + uv2 * vv2;
    size_t ab = (size_t)n * FD3;
    g_a[ab + g]           = gv0 * uv0 + gv1 * uv1 + gv2 * uv2;
    g_a[ab + FD + g]      = gxv * S;
    g_a[ab + 2 * FD + g]  = gxv;
}

// NOTE: uvvv is read then overwritten in place (g_uv/g_vv); no __restrict__ on it.
__global__ void ubwd2_kernel(const float* gx_in, const float* gv_in,
    const float* a_, const float* vnorm, const float* g_cat,
    float* uvvv, float* gx_mid, float* gv_tmp)
{
    int i = blockIdx.x * blockDim.x + threadIdx.x;  // NA*FD
    int n = i >> 7, g = i & 127;
    size_t vb = (size_t)n * 3 * FD + g, ab = (size_t)n * FD3;
    size_t ub = (size_t)n * 3 * 256 + g;
    float gxv = gx_in[i];
    float gS = gxv * a_[ab + FD + g];
    float avv = a_[ab + g];
    float gvn = g_cat[(size_t)n * 2 * FD + FD + g];
    float c = gvn / vnorm[i];
    float uv0 = uvvv[ub], uv1 = uvvv[ub + 256], uv2 = uvvv[ub + 512];
    float vv0 = uvvv[ub + 128], vv1 = uvvv[ub + 384], vv2 = uvvv[ub + 640];
    float gv0 = gv_in[vb], gv1 = gv_in[vb + FD], gv2 = gv_in[vb + 2 * FD];
    uvvv[ub]       = gv0 * avv + gS * vv0;
    uvvv[ub + 256] = gv1 * avv + gS * vv1;
    uvvv[ub + 512] = gv2 * avv + gS * vv2;
    uvvv[ub + 128] = gS * uv0 + c * vv0;
    uvvv[ub + 384] = gS * uv1 + c * vv1;
    uvvv[ub + 640] = gS * uv2 + c * vv2;
    gv_tmp[vb] = gv0; gv_tmp[vb + FD] = gv1; gv_tmp[vb + 2 * FD] = gv2;
    gx_mid[i] = gxv + g_cat[(size_t)n * 2 * FD + g];
}

// ---------------- merged message backward: one BLOCK (4 waves) per src atom --------
__global__ __launch_bounds__(256) void msg_bwd_merged_kernel(
    const int* __restrict__ row_off_src, const int* __restrict__ perm_src, const int* __restrict__ dstp,
    const unsigned int* __restrict__ rbfh_e, const unsigned int* __restrict__ drbfh_e,
    const float4* __restrict__ geo4, const float* __restrict__ dfc_e,
    const float* phi, const unsigned int* __restrict__ Wrp, const float* __restrict__ br,
    const float* __restrict__ v_in,              // nullable (block 0)
    const float* __restrict__ gx_mid, const float* __restrict__ gv_mid,
    float* gphi_out,                // aliases phi (own-atom read-then-write, barrier-protected)
    float* __restrict__ gv_out,
    float* __restrict__ gd_e, float* __restrict__ gu_e)
{
    __shared__ float red[12][4][64];
    int tid = threadIdx.x;
    int wv = tid >> 6, lane = tid & 63;
    int n = blockIdx.x;
    f16x2 w[2][3][10];
    float brv[2][3], ph[2][3], vs[2][3];
    #pragma unroll
    for (int h = 0; h < 2; ++h) {
        int f = lane + h * 64;
        #pragma unroll
        for (int s = 0; s < 3; ++s) {
            #pragma unroll
            for (int k2 = 0; k2 < 10; ++k2) {
                unsigned int u = Wrp[k2 * 384 + s * 128 + f];
                w[h][s][k2] = *(const f16x2*)&u;
            }
            brv[h][s] = br[s * FD + f];
            ph[h][s] = phi[(size_t)n * FD3 + s * FD + f];
            vs[h][s] = v_in ? v_in[(size_t)n * 3 * FD + s * FD + f] : 0.f;
        }
    }
    float gp[2][3] = {{0.f, 0.f, 0.f}, {0.f, 0.f, 0.f}};
    float ga[2][3] = {{0.f, 0.f, 0.f}, {0.f, 0.f, 0.f}};
    int e0 = row_off_src[n], e1 = row_off_src[n + 1];
    for (int ii = e0 + wv; ii < e1; ii += 4) {
        int e = perm_src[ii], dd = dstp[ii];
        float4 g = geo4[e];
        float fc = g.w, dfc = dfc_e[e];
        f16x2 rb2[10], db2[10];
        #pragma unroll
        for (int k2 = 0; k2 < 10; ++k2) {
            unsigned int ra = rbfh_e[(size_t)e * 10 + k2];
            unsigned int db = drbfh_e[(size_t)e * 10 + k2];
            rb2[k2] = *(const f16x2*)&ra;
            db2[k2] = *(const f16x2*)&db;
        }
        float r0 = 0.f, r1 = 0.f, r2 = 0.f, r3 = 0.f;
        #pragma unroll
        for (int h = 0; h < 2; ++h) {
            int f = lane + h * 64;
            float raw0 = brv[h][0], raw1 = brv[h][1], raw2 = brv[h][2];
            float A0 = 0.f, A1 = 0.f, A2 = 0.f;
            #pragma unroll
            for (int k2 = 0; k2 < 10; ++k2) {
                raw0 = dot2f(rb2[k2], w[h][0][k2], raw0);
                raw1 = dot2f(rb2[k2], w[h][1][k2], raw1);
                raw2 = dot2f(rb2[k2], w[h][2][k2], raw2);
                A0 = dot2f(db2[k2], w[h][0][k2], A0);
                A1 = dot2f(db2[k2], w[h][1][k2], A1);
                A2 = dot2f(db2[k2], w[h][2][k2], A2);
            }
            float f0 = raw0 * fc, f1 = raw1 * fc, f2 = raw2 * fc;
            float gds = gx_mid[(size_t)dd * FD + f];
            const float* gvp = gv_mid + (size_t)dd * 3 * FD;
            float gd0 = gvp[f], gd1 = gvp[FD + f], gd2 = gvp[2 * FD + f];
            float gdv1 = gd0 * vs[h][0] + gd1 * vs[h][1] + gd2 * vs[h][2];
            float gdv2 = gd0 * g.x + gd1 * g.y + gd2 * g.z;
            float dv1 = ph[h][1] * f1;
            ga[h][0] += gd0 * dv1; ga[h][1] += gd1 * dv1; ga[h][2] += gd2 * dv1;
            gp[h][0] += gds * f0; gp[h][1] += gdv1 * f1; gp[h][2] += gdv2 * f2;
            float dv2 = ph[h][2] * f2;
            r1 += gd0 * dv2; r2 += gd1 * dv2; r3 += gd2 * dv2;
            float gf0 = gds * ph[h][0], gf1 = gdv1 * ph[h][1], gf2 = gdv2 * ph[h][2];
            r0 += fc * (gf0 * A0 + gf1 * A1 + gf2 * A2)
                + dfc * (gf0 * raw0 + gf1 * raw1 + gf2 * raw2);
        }
        #pragma unroll
        for (int off = 32; off > 0; off >>= 1) {
            r0 += __shfl_down(r0, off);
            r1 += __shfl_down(r1, off);
            r2 += __shfl_down(r2, off);
            r3 += __shfl_down(r3, off);
        }
        if (lane == 0) {
            gd_e[e] += r0;
            gu_e[e * 3]     += r1;
            gu_e[e * 3 + 1] += r2;
            gu_e[e * 3 + 2] += r3;
        }
    }
    #pragma unroll
    for (int h = 0; h < 2; ++h)
        #pragma unroll
        for (int s = 0; s < 3; ++s) {
            red[h * 3 + s][wv][lane] = gp[h][s];
            red[6 + h * 3 + s][wv][lane] = ga[h][s];
        }
    __syncthreads();
    int j0 = tid >> 6;   // 0..3
    #pragma unroll
    for (int rep = 0; rep < 3; ++rep) {
        int j = j0 + rep * 4;
        float v = red[j][0][lane] + red[j][1][lane] + red[j][2][lane] + red[j][3][lane];
        int jj = (j < 6) ? j : j - 6;
        int h = jj / 3, s = jj - 3 * h;
        int f = h * 64 + lane;
        if (j < 6) {
            gphi_out[(size_t)n * FD3 + s * FD + f] = v;
        } else {
            size_t vb = (size_t)n * 3 * FD + s * FD + f;
            gv_out[vb] = gv_mid[vb] + v;
        }
    }
}

// ---------------- geometry backward: per-edge grad vector (no atomics) ----------------
// NOTE: gvec aliases gu_e (same-thread read-then-write) — no __restrict__.
__global__ void edge_vec_kernel(const float* coord, const int* ei,
    const float* d_e, const float* gd_e, const float* gu_e, float* gvec)
{
    int e = blockIdx.x * blockDim.x + threadIdx.x;
    if (e >= NE) return;
    int s = ei[e], t = ei[NE + e];
    float rx = coord[t * 3 + 0] - coord[s * 3 + 0];
    float ry = coord[t * 3 + 1] - coord[s * 3 + 1];
    float rz = coord[t * 3 + 2] - coord[s * 3 + 2];
    float dd = d_e[e];
    float inv = 1.f / dd;
    float gu0 = gu_e[e * 3], gu1 = gu_e[e * 3 + 1], gu2 = gu_e[e * 3 + 2];
    float gd = gd_e[e];
    float dot = gu0 * rx + gu1 * ry + gu2 * rz;
    float coef = gd * inv - dot * inv * inv * inv;
    gvec[e * 3 + 0] = gu0 * inv + coef * rx;
    gvec[e * 3 + 1] = gu1 * inv + coef * ry;
    gvec[e * 3 + 2] = gu2 * inv + coef * rz;
}

// one wave per atom: gcoord[n] = sum_{dst edges} gvec - sum_{src edges} gvec
__global__ __launch_bounds__(256) void coord_gather_kernel(
    const int* __restrict__ off_dst, const int* __restrict__ perm_dst,
    const int* __restrict__ off_src, const int* __restrict__ perm_src,
    const float* __restrict__ gvec, float* __restrict__ gcoord)
{
    int n = blockIdx.x * 4 + (threadIdx.x >> 6);
    int lane = threadIdx.x & 63;
    float a0 = 0.f, a1 = 0.f, a2 = 0.f;
    int d0 = off_dst[n], d1 = off_dst[n + 1];
    for (int ii = d0 + lane; ii < d1; ii += 64) {
        int e = perm_dst[ii];
        a0 += gvec[e * 3]; a1 += gvec[e * 3 + 1]; a2 += gvec[e * 3 + 2];
    }
    int s0 = off_src[n], s1 = off_src[n + 1];
    for (int ii = s0 + lane; ii < s1; ii += 64) {
        int e = perm_src[ii];
        a0 -= gvec[e * 3]; a1 -= gvec[e * 3 + 1]; a2 -= gvec[e * 3 + 2];
    }
    #pragma unroll
    for (int off = 32; off > 0; off >>= 1) {
        a0 += __shfl_down(a0, off);
        a1 += __shfl_down(a1, off);
        a2 += __shfl_down(a2, off);
    }
    if (lane == 0) {
        gcoord[n * 3 + 0] = a0; gcoord[n * 3 + 1] = a1; gcoord[n * 3 + 2] = a2;
    }
}

// ======================================================================
extern "C" void kernel_launch(void* const* d_in, const int* in_sizes, int n_in,
                              void* d_out, int out_size, void* d_ws, size_t ws_size,
                              hipStream_t stream)
{
    (void)in_sizes; (void)n_in; (void)out_size; (void)ws_size;
    const int*   at_no   = (const int*)  d_in[0];
    const float* coord   = (const float*)d_in[1];
    const int*   eidx    = (const int*)  d_in[2];
    const float* emb     = (const float*)d_in[5];
    const float* atom_sp = (const float*)d_in[6];
    const float* msg_w1  = (const float*)d_in[7];
    const float* msg_b1  = (const float*)d_in[8];
    const float* msg_w2  = (const float*)d_in[9];
    const float* msg_b2  = (const float*)d_in[10];
    const float* msg_wr  = (const float*)d_in[11];
    const float* msg_br  = (const float*)d_in[12];
    const float* upd_u   = (const float*)d_in[13];
    const float* upd_v   = (const float*)d_in[14];
    const float* upd_w1  = (const float*)d_in[15];
    const float* upd_b1  = (const float*)d_in[16];
    const float* upd_w2  = (const float*)d_in[17];
    const float* upd_b2  = (const float*)d_in[18];
    const float* out_w1  = (const float*)d_in[19];
    const float* out_b1  = (const float*)d_in[20];
    const float* out_w2  = (const float*)d_in[21];
    const float* out_b2  = (const float*)d_in[22];
    float* out = (float*)d_out;
    float* gcoord = out + 1;

    char* wp = (char*)d_ws;
    auto alloc = [&](size_t nelem) -> float* {
        float* r = (float*)wp; wp += ((nelem * 4 + 255) & ~(size_t)255); return r;
    };
    auto alloci = [&](size_t nelem) -> int* {
        int* r = (int*)wp; wp += ((nelem * 4 + 255) & ~(size_t)255); return r;
    };
    auto allocu = [&](size_t nelem) -> unsigned int* {
        unsigned int* r = (unsigned int*)wp; wp += ((nelem * 4 + 255) & ~(size_t)255); return r;
    };
    const size_t NF = (size_t)NA * FD;

    float* d_e    = alloc(NE);
    float4* geo4  = (float4*)alloc(4 * (size_t)NE);
    float* dfc_e  = alloc(NE);
    float* gd_e   = alloc(NE);
    float* gu_e   = alloc(3 * (size_t)NE);
    unsigned int* rbfh_e  = allocu((size_t)10 * NE);
    unsigned int* drbfh_e = allocu((size_t)10 * NE);
    int* cnt_dst = alloci(NA); int* cnt_src = alloci(NA);
    int* off_dst = alloci(NA + 1); int* off_src = alloci(NA + 1);
    int* cur_dst = alloci(NA); int* cur_src = alloci(NA);
    int* perm_dst = alloci(NE); int* perm_src = alloci(NE);
    int* srcp = alloci(NE); int* dstp = alloci(NE);
    float* xin_all = alloc(3 * NF);
    float* xin0 = xin_all; float* xin1 = xin_all + NF; float* xfin = xin_all + 2 * NF;
    float* vout0 = alloc(3 * NF);
    float* xmid = alloc(NF);
    float* vmid = alloc(3 * NF);            // reused as gv_tmp in backward
    float* catb = alloc(2 * NF);
    float* toutb = alloc((size_t)NA * HD);
    float *s1b[2], *phib[2], *uvvv[2], *vnb[2], *t1b[2], *ab[2];
    for (int b = 0; b < 2; ++b) {
        s1b[b] = alloc(NF); phib[b] = alloc(3 * NF); uvvv[b] = alloc(6 * NF);
        vnb[b] = alloc(NF); t1b[b] = alloc(NF); ab[b] = alloc(3 * NF);
    }
    float* gxA = alloc(NF); float* gxB = alloc(NF);
    float* gvA = alloc(3 * NF);
    // backward aliases of dead forward buffers:
    float* g_a   = xin_all;   // 3*NF
    float* g_cat = catb;      // 2*NF
    float* g_t1  = xmid;      // NF
    float* g_s1  = s1b[0];    // NF (only used in b==1 path)
    float* gvec_e = gu_e;     // in-place transform in edge_vec
    float *UVcomb[2], *Tcomb[2];
    for (int b = 0; b < 2; ++b) { UVcomb[b] = alloc(FD * 256); Tcomb[b] = alloc(256 * FD); }
    unsigned int* Wrp[2];
    for (int b = 0; b < 2; ++b) Wrp[b] = allocu(3840);

    // zero-init (harness poisons d_out/d_ws with 0xAA before every call)
    hipMemsetAsync(d_out, 0, (size_t)(1 + NA * 3) * 4, stream);
    hipMemsetAsync(cnt_dst, 0, (size_t)NA * 4, stream);
    hipMemsetAsync(cnt_src, 0, (size_t)NA * 4, stream);
    hipMemsetAsync(gd_e, 0, (size_t)NE * 4, stream);
    hipMemsetAsync(gu_e, 0, 3ull * NE * 4, stream);
    hipMemsetAsync(gvA, 0, 3 * NF * 4, stream);

    geom_fwd_kernel<<<NE / 256, 256, 0, stream>>>(coord, eidx, d_e, geo4, dfc_e,
                                                  rbfh_e, drbfh_e, cnt_dst, cnt_src);
    scan_kernel<<<2, 1024, 0, stream>>>(cnt_dst, cnt_src, off_dst, off_src, cur_dst, cur_src);
    scatter_kernel<<<NE / 256, 256, 0, stream>>>(eidx, cur_dst, cur_src, perm_dst, perm_src, srcp, dstp);
    embed_kernel<<<NF / 256, 256, 0, stream>>>(at_no, emb, xin0);
    for (int b = 0; b < 2; ++b) {
        combo_prep_kernel<<<128, 256, 0, stream>>>(upd_u + (size_t)b * FD * FD,
                                                   upd_v + (size_t)b * FD * FD, UVcomb[b], Tcomb[b]);
        wpack_kernel<<<15, 256, 0, stream>>>(msg_wr + (size_t)b * NBASE * FD3, Wrp[b]);
    }

    auto gemm = [&](const float* A, const float* W, const float* bias, const float* dsil,
                    const float* addb, float* C, int M, int Nn, int K, int asilu, int acc, int wtrans) {
        if (M == NA && Nn <= 128) {
            dim3 g((Nn + 63) / 64, M / 64);
            mfma_gemm64_kernel<<<g, 256, 0, stream>>>(A, W, bias, dsil, addb, C, M, Nn, K, asilu, acc, wtrans);
        } else {
            dim3 g(Nn / 64, M / 128);
            mfma_gemm_kernel<<<g, 256, 0, stream>>>(A, W, bias, dsil, addb, C, M, Nn, K, asilu, acc, wtrans);
        }
    };

    // ---------------- forward ----------------
    for (int b = 0; b < 2; ++b) {
        const float* xinb = b ? xin1 : xin0;
        const float* vin  = b ? vout0 : nullptr;
        gemm(xinb, msg_w1 + (size_t)b * FD * FD, msg_b1 + b * FD, nullptr, nullptr, s1b[b], NA, FD, FD, 0, 0, 0);
        gemm(s1b[b], msg_w2 + (size_t)b * FD * FD3, msg_b2 + b * FD3, nullptr, nullptr, phib[b], NA, FD3, FD, 1, 0, 0);
        msg_fwd_kernel<<<NA / 2, 256, 0, stream>>>(off_dst, perm_dst, srcp, rbfh_e, geo4,
                                              phib[b], Wrp[b], msg_br + (size_t)b * FD3,
                                              xinb, vin, xmid, vmid);
        gemm(vmid, UVcomb[b], nullptr, nullptr, nullptr, uvvv[b], 3 * NA, 256, FD, 0, 0, 0);
        vnorm_cat_kernel<<<NF / 256, 256, 0, stream>>>(xmid, uvvv[b], vnb[b], catb);
        gemm(catb, upd_w1 + (size_t)b * 2 * FD * FD, upd_b1 + b * FD, nullptr, nullptr, t1b[b], NA, FD, 2 * FD, 0, 0, 0);
        gemm(t1b[b], upd_w2 + (size_t)b * FD * FD3, upd_b2 + b * FD3, nullptr, nullptr, ab[b], NA, FD3, FD, 1, 0, 0);
        combine_kernel<<<NF / 256, 256, 0, stream>>>(xmid, vmid, uvvv[b], ab[b],
                                                     b ? xfin : xin1, b ? nullptr : vout0);
    }
    gemm(xfin, out_w1, out_b1, nullptr, nullptr, toutb, NA, HD, FD, 0, 0, 0);
    energy_kernel<<<NA / 256, 256, 0, stream>>>(toutb, out_w2, out_b2, atom_sp, at_no, out);

    // ---------------- backward ----------------
    head_bwd_kernel<<<NA, FD, 0, stream>>>(toutb, out_w1, out_w2, gxA);
    for (int b = 1; b >= 0; --b) {
        ubwd1_kernel<<<NF / 256, 256, 0, stream>>>(gxA, gvA, uvvv[b], g_a);
        gemm(g_a, upd_w2 + (size_t)b * FD * FD3, nullptr, t1b[b], nullptr, g_t1, NA, FD, FD3, 0, 0, 1);
        gemm(g_t1, upd_w1 + (size_t)b * 2 * FD * FD, nullptr, nullptr, nullptr, g_cat, NA, 2 * FD, FD, 0, 0, 1);
        ubwd2_kernel<<<NF / 256, 256, 0, stream>>>(gxA, gvA, ab[b], vnb[b], g_cat,
                                                   uvvv[b], gxB, vmid);
        gemm(uvvv[b], Tcomb[b], nullptr, nullptr, nullptr, vmid, 3 * NA, FD, 256, 0, 1, 0);
        msg_bwd_merged_kernel<<<NA, 256, 0, stream>>>(off_src, perm_src, dstp,
                                              rbfh_e, drbfh_e, geo4, dfc_e,
                                              phib[b], Wrp[b], msg_br + (size_t)b * FD3,
                                              b ? vout0 : nullptr, gxB, vmid,
                                              phib[b], gvA, gd_e, gu_e);
        if (b == 1) {
            gemm(phib[b], msg_w2 + (size_t)b * FD * FD3, nullptr, s1b[b], nullptr, g_s1, NA, FD, FD3, 0, 0, 1);
            gemm(g_s1, msg_w1 + (size_t)b * FD * FD, nullptr, nullptr, gxB, gxA, NA, FD, FD, 0, 0, 1);
        }
    }
    edge_vec_kernel<<<NE / 256, 256, 0, stream>>>(coord, eidx, d_e, gd_e, gu_e, gvec_e);
    coord_gather_kernel<<<NA / 4, 256, 0, stream>>>(off_dst, perm_dst, off_src, perm_src, gvec_e, gcoord);
}